// Round 2
// baseline (1336.966 us; speedup 1.0000x reference)
//
#include <hip/hip_runtime.h>

#define Bn 8
#define Hn 128
#define Wn 128
#define Cn 192
#define Ln (Hn*Wn)          // 16384
#define Mn (Bn*Ln)          // 131072
#define FUn ((size_t)Mn*Cn) // 25,165,824 floats
#define BN_RSQ 0.9999950000374997f   // 1/sqrt(1+1e-5)

static __device__ __forceinline__ float gelu_f(float x) {
    return 0.5f * x * (1.0f + erff(x * 0.7071067811865475f));
}
static __device__ __forceinline__ float gate1p(float x) {  // 1 + sigmoid(x)
    return 1.0f + 1.0f / (1.0f + __expf(-x));
}
static __device__ __forceinline__ unsigned short f2bf(float f) {  // RNE
    unsigned u = __float_as_uint(f);
    return (unsigned short)((u + 0x7FFFu + ((u >> 16) & 1u)) >> 16);
}

// ---------------- qkv GEMM (one branch): C[m][0:288] = x @ w_qkv cols, bf16 out
// col n: part=n/96 (q,k,v), off=n%96 -> global col part*192 + BRANCH*96 + off
template<int BRANCH>
__global__ __launch_bounds__(256) void qkv_gemm(const float* __restrict__ A,
        const float* __restrict__ Bw, const float* __restrict__ bias,
        unsigned short* __restrict__ Q)
{
    __shared__ float aT[32][68];
    __shared__ float bs[32][68];
    const int m0 = blockIdx.x * 64;
    const int n0 = blockIdx.y * 64;          // 0,64,128,192,256
    const int tid = threadIdx.x;
    const int ty = tid >> 4, tx = tid & 15;
    float acc[4][4] = {};
    for (int k0 = 0; k0 < 192; k0 += 32) {
        #pragma unroll
        for (int r = 0; r < 2; ++r) {
            int ff = tid + r * 256;
            int mm = ff >> 3;
            int kk4 = (ff & 7) << 2;
            float4 v = *(const float4*)(A + (size_t)(m0 + mm) * 192 + k0 + kk4);
            aT[kk4 + 0][mm] = v.x; aT[kk4 + 1][mm] = v.y;
            aT[kk4 + 2][mm] = v.z; aT[kk4 + 3][mm] = v.w;
            int kk = ff >> 4;
            int nn4 = (ff & 15) << 2;
            int nn = n0 + nn4;
            if (nn > 284) nn = 284;          // clamp tail (cols>=288 unused)
            int part = nn / 96;
            int gc = part * 192 + BRANCH * 96 + (nn - part * 96);
            *(float4*)&bs[kk][nn4] = *(const float4*)(Bw + (size_t)(k0 + kk) * 576 + gc);
        }
        __syncthreads();
        #pragma unroll 8
        for (int kk = 0; kk < 32; ++kk) {
            float4 a4 = *(const float4*)&aT[kk][ty * 4];
            float4 b4 = *(const float4*)&bs[kk][tx * 4];
            float av[4] = {a4.x, a4.y, a4.z, a4.w};
            float bv[4] = {b4.x, b4.y, b4.z, b4.w};
            #pragma unroll
            for (int i = 0; i < 4; ++i)
                #pragma unroll
                for (int j = 0; j < 4; ++j)
                    acc[i][j] = fmaf(av[i], bv[j], acc[i][j]);
        }
        __syncthreads();
    }
    int col = n0 + tx * 4;
    if (col < 288) {
        int part = col / 96;
        int gc = part * 192 + BRANCH * 96 + (col - part * 96);
        float4 bb = *(const float4*)(bias + gc);
        #pragma unroll
        for (int i = 0; i < 4; ++i) {
            size_t m = (size_t)m0 + ty * 4 + i;
            ushort4 o;
            o.x = f2bf(acc[i][0] + bb.x);
            o.y = f2bf(acc[i][1] + bb.y);
            o.z = f2bf(acc[i][2] + bb.z);
            o.w = f2bf(acc[i][3] + bb.w);
            *(ushort4*)(Q + m * 288 + col) = o;
        }
    }
}

// ---------------- Window attention (one branch), bf16 in, f32 out -----------
template<int BRANCH>
__global__ __launch_bounds__(128) void attn_kernel(const unsigned short* __restrict__ Q,
                                                   float* __restrict__ fu)
{
    int idx = blockIdx.x;                  // 3072 = 3 heads * 8 b * 128 win
    int head = idx >> 10;
    int rem = idx & 1023;
    int b = rem >> 7;
    int win = rem & 127;
    int t = threadIdx.x;                   // query token in window
    int h, w;
    if (BRANCH == 0) {                     // Hs=8, Ws=16 ; win grid 16x8
        int wy = win >> 3, wx = win & 7;
        h = wy * 8 + (t >> 4);
        w = wx * 16 + (t & 15);
    } else {                               // Hs=16, Ws=8 ; win grid 8x16
        int wy = win >> 4, wx = win & 15;
        h = wy * 16 + (t >> 3);
        w = wx * 8 + (t & 7);
    }
    int l = h * Wn + w;
    const unsigned short* row = Q + (size_t)(b * Ln + l) * 288 + head * 32;

    __shared__ float kb[128][32];
    __shared__ float vb[128][32];
    float q[32];
    #pragma unroll
    for (int c8 = 0; c8 < 4; ++c8) {
        uint4 uq = *(const uint4*)(row + c8 * 8);
        uint4 uk = *(const uint4*)(row + 96 + c8 * 8);
        uint4 uv = *(const uint4*)(row + 192 + c8 * 8);
        q[c8*8+0] = __uint_as_float(uq.x << 16); q[c8*8+1] = __uint_as_float(uq.x & 0xffff0000u);
        q[c8*8+2] = __uint_as_float(uq.y << 16); q[c8*8+3] = __uint_as_float(uq.y & 0xffff0000u);
        q[c8*8+4] = __uint_as_float(uq.z << 16); q[c8*8+5] = __uint_as_float(uq.z & 0xffff0000u);
        q[c8*8+6] = __uint_as_float(uq.w << 16); q[c8*8+7] = __uint_as_float(uq.w & 0xffff0000u);
        kb[t][c8*8+0] = __uint_as_float(uk.x << 16); kb[t][c8*8+1] = __uint_as_float(uk.x & 0xffff0000u);
        kb[t][c8*8+2] = __uint_as_float(uk.y << 16); kb[t][c8*8+3] = __uint_as_float(uk.y & 0xffff0000u);
        kb[t][c8*8+4] = __uint_as_float(uk.z << 16); kb[t][c8*8+5] = __uint_as_float(uk.z & 0xffff0000u);
        kb[t][c8*8+6] = __uint_as_float(uk.w << 16); kb[t][c8*8+7] = __uint_as_float(uk.w & 0xffff0000u);
        vb[t][c8*8+0] = __uint_as_float(uv.x << 16); vb[t][c8*8+1] = __uint_as_float(uv.x & 0xffff0000u);
        vb[t][c8*8+2] = __uint_as_float(uv.y << 16); vb[t][c8*8+3] = __uint_as_float(uv.y & 0xffff0000u);
        vb[t][c8*8+4] = __uint_as_float(uv.z << 16); vb[t][c8*8+5] = __uint_as_float(uv.z & 0xffff0000u);
        vb[t][c8*8+6] = __uint_as_float(uv.w << 16); vb[t][c8*8+7] = __uint_as_float(uv.w & 0xffff0000u);
    }
    __syncthreads();

    float mx = -1e30f, ssum = 0.0f;
    float acc[32] = {};
    for (int s = 0; s < 128; ++s) {
        float dot = 0.0f;
        #pragma unroll
        for (int d4 = 0; d4 < 8; ++d4) {
            float4 kk4 = *(const float4*)&kb[s][d4 * 4];
            dot = fmaf(q[d4*4+0], kk4.x, dot);
            dot = fmaf(q[d4*4+1], kk4.y, dot);
            dot = fmaf(q[d4*4+2], kk4.z, dot);
            dot = fmaf(q[d4*4+3], kk4.w, dot);
        }
        float logit = dot * 0.5303300858899106f;   // 3 / sqrt(32)
        float p;
        if (logit > mx) {
            float corr = __expf(mx - logit);
            ssum *= corr;
            #pragma unroll
            for (int d = 0; d < 32; ++d) acc[d] *= corr;
            mx = logit;
            p = 1.0f;
        } else {
            p = __expf(logit - mx);
        }
        ssum += p;
        #pragma unroll
        for (int d4 = 0; d4 < 8; ++d4) {
            float4 vv = *(const float4*)&vb[s][d4 * 4];
            acc[d4*4+0] = fmaf(p, vv.x, acc[d4*4+0]);
            acc[d4*4+1] = fmaf(p, vv.y, acc[d4*4+1]);
            acc[d4*4+2] = fmaf(p, vv.z, acc[d4*4+2]);
            acc[d4*4+3] = fmaf(p, vv.w, acc[d4*4+3]);
        }
    }
    float inv = 3.0f / ssum;
    float* orow = fu + (size_t)(b * Ln + l) * 192 + BRANCH * 96 + head * 32;
    #pragma unroll
    for (int d4 = 0; d4 < 8; ++d4) {
        float4 o;
        o.x = acc[d4*4+0] * inv;
        o.y = acc[d4*4+1] * inv;
        o.z = acc[d4*4+2] * inv;
        o.w = acc[d4*4+3] * inv;
        *(float4*)(orow + d4 * 4) = o;
    }
}

// -------- dwconv1+BN+GELU fused with spatial-gate MLP and pool partials -----
__global__ __launch_bounds__(128) void dwconv1_gates(const float* __restrict__ x,
        const float* __restrict__ wdw, const float* __restrict__ bdw,
        const float* __restrict__ g1, const float* __restrict__ be1,
        const float* __restrict__ ws1g, const float* __restrict__ bs1,
        const float* __restrict__ gsi, const float* __restrict__ besi,
        const float* __restrict__ ws2, const float* __restrict__ bs2,
        float* __restrict__ gate_s, float* __restrict__ partial)
{
    int bh = blockIdx.x;               // b*128 + h
    int b = bh >> 7, h = bh & 127;
    int w = threadIdx.x;               // 0..127
    __shared__ float ws1T[24 * 192];   // [c][o] transposed
    __shared__ float pacc[192][2];
    for (int i = w; i < 24 * 192; i += 128) {
        int c = i / 24, o = i - c * 24;
        ws1T[i] = ws1g[o * 192 + c];
    }
    __syncthreads();
    float acc24[24] = {};
    int wave = w >> 6, lane = w & 63;
    for (int c = 0; c < 192; ++c) {
        const float* bp = x + (size_t)(b * 192 + c) * Ln;
        float s = 0.0f;
        #pragma unroll
        for (int dy = -1; dy <= 1; ++dy) {
            int hh = h + dy;
            if (hh < 0 || hh >= Hn) continue;
            const float* rp = bp + hh * Wn;
            float w0 = wdw[c*9 + (dy+1)*3 + 0];
            float w1 = wdw[c*9 + (dy+1)*3 + 1];
            float w2 = wdw[c*9 + (dy+1)*3 + 2];
            if (w > 0)   s = fmaf(w0, rp[w-1], s);
            s = fmaf(w1, rp[w], s);
            if (w < 127) s = fmaf(w2, rp[w+1], s);
        }
        float y = gelu_f((s + bdw[c]) * (g1[c] * BN_RSQ) + be1[c]);
        const float4* wp = (const float4*)&ws1T[c * 24];
        #pragma unroll
        for (int o4 = 0; o4 < 6; ++o4) {
            float4 wv = wp[o4];
            acc24[o4*4+0] = fmaf(y, wv.x, acc24[o4*4+0]);
            acc24[o4*4+1] = fmaf(y, wv.y, acc24[o4*4+1]);
            acc24[o4*4+2] = fmaf(y, wv.z, acc24[o4*4+2]);
            acc24[o4*4+3] = fmaf(y, wv.w, acc24[o4*4+3]);
        }
        float r = y;
        for (int off = 32; off; off >>= 1) r += __shfl_down(r, off);
        if (lane == 0) pacc[c][wave] = r;
    }
    __syncthreads();
    for (int c = w; c < 192; c += 128)
        partial[(size_t)bh * 192 + c] = pacc[c][0] + pacc[c][1];
    float s2 = bs2[0];
    #pragma unroll
    for (int o = 0; o < 24; ++o)
        s2 = fmaf(gelu_f((acc24[o] + bs1[o]) * (gsi[o] * BN_RSQ) + besi[o]), ws2[o], s2);
    gate_s[(size_t)bh * 128 + w] = gate1p(s2);
}

// ---------------- channel gate: pool-finalize + 192->24->192, 1+sigmoid -----
__global__ __launch_bounds__(192) void channel_gate_k(const float* __restrict__ partial,
        const float* __restrict__ w1, const float* __restrict__ b1,
        const float* __restrict__ g, const float* __restrict__ be,
        const float* __restrict__ w2, const float* __restrict__ b2,
        float* __restrict__ gate_c)
{
    int b = blockIdx.x, t = threadIdx.x;
    __shared__ float pl[192];
    __shared__ float h1[24];
    float s = 0.0f;
    for (int hh = 0; hh < 128; ++hh)
        s += partial[((size_t)b * 128 + hh) * 192 + t];
    pl[t] = s * (1.0f / Ln);
    __syncthreads();
    if (t < 24) {
        float a = b1[t];
        for (int c = 0; c < 192; ++c) a = fmaf(pl[c], w1[t * 192 + c], a);
        a = a * (g[t] * BN_RSQ) + be[t];
        h1[t] = gelu_f(a);
    }
    __syncthreads();
    float a = b2[t];
    #pragma unroll
    for (int o = 0; o < 24; ++o) a = fmaf(h1[o], w2[t * 24 + o], a);
    gate_c[b * 192 + t] = gate1p(a);
}

// ---- spatial-gated fu -> dwconv2 -> BN -> GELU -> channel gate, NCHW out ---
// block: (wt, h, b); stages 3 rows x 34 px x 96 ch (half) of gated fu via LDS
__global__ __launch_bounds__(256) void dwconv2_k(const float* __restrict__ fu,
        const float* __restrict__ gate_s, const float* __restrict__ gate_c,
        const float* __restrict__ wdw, const float* __restrict__ bdw,
        const float* __restrict__ g2, const float* __restrict__ be2,
        float* __restrict__ out2)
{
    int w0 = blockIdx.x * 32;
    int h  = blockIdx.y;
    int b  = blockIdx.z;
    int tid = threadIdx.x;
    __shared__ float ls[3][34][97];
    int ww = tid & 31, co = tid >> 5;       // co in 0..7
    for (int half = 0; half < 2; ++half) {
        if (half) __syncthreads();
        for (int f = tid; f < 3 * 34 * 24; f += 256) {   // 24 float4 per pixel-row
            int c4 = f % 24;
            int pp = f / 24;
            int wl = pp % 34;
            int r  = pp / 34;
            int hr = h - 1 + r;
            int wp = w0 - 1 + wl;
            float4 v = make_float4(0.f, 0.f, 0.f, 0.f);
            if (hr >= 0 && hr < Hn && wp >= 0 && wp < Wn) {
                int l = hr * Wn + wp;
                v = *(const float4*)(fu + ((size_t)b * Ln + l) * 192 + half * 96 + c4 * 4);
                float gs = gate_s[(size_t)b * Ln + l];
                v.x *= gs; v.y *= gs; v.z *= gs; v.w *= gs;
            }
            float* d = &ls[r][wl][c4 * 4];
            d[0] = v.x; d[1] = v.y; d[2] = v.z; d[3] = v.w;
        }
        __syncthreads();
        #pragma unroll
        for (int j = 0; j < 12; ++j) {
            int cl = co * 12 + j;          // 0..95
            int c = half * 96 + cl;
            const float* wk = wdw + c * 9;
            float s = 0.0f;
            #pragma unroll
            for (int r = 0; r < 3; ++r) {
                s = fmaf(wk[r*3+0], ls[r][ww+0][cl], s);
                s = fmaf(wk[r*3+1], ls[r][ww+1][cl], s);
                s = fmaf(wk[r*3+2], ls[r][ww+2][cl], s);
            }
            float y = gelu_f((s + bdw[c]) * (g2[c] * BN_RSQ) + be2[c]) * gate_c[b * 192 + c];
            out2[((size_t)(b * 192 + c) * Hn + h) * Wn + w0 + ww] = y;
        }
    }
}

// ---- proj GEMM, A sourced K-major from NCHW out2: A[(b,l)][k]=At[(b*192+k)*Ln+l]
__global__ __launch_bounds__(256) void gemm_projT(const float* __restrict__ At,
                                                  const float* __restrict__ Bw,
                                                  const float* __restrict__ bias,
                                                  float* __restrict__ Cout)
{
    __shared__ float aT[32][68];
    __shared__ float bs[32][68];
    const int m0 = blockIdx.x * 64;
    const int n0 = blockIdx.y * 64;
    const int b = m0 >> 14;
    const int l0 = m0 & 16383;
    const int tid = threadIdx.x;
    const int ty = tid >> 4, tx = tid & 15;
    float acc[4][4] = {};
    for (int k0 = 0; k0 < 192; k0 += 32) {
        #pragma unroll
        for (int r = 0; r < 2; ++r) {
            int ff = tid + r * 256;
            int kk = ff >> 4;
            int mm4 = (ff & 15) << 2;
            *(float4*)&aT[kk][mm4] =
                *(const float4*)(At + ((size_t)b * 192 + k0 + kk) * Ln + l0 + mm4);
            *(float4*)&bs[kk][mm4] =
                *(const float4*)(Bw + (size_t)(k0 + kk) * 192 + n0 + mm4);
        }
        __syncthreads();
        #pragma unroll 8
        for (int kk = 0; kk < 32; ++kk) {
            float4 a4 = *(const float4*)&aT[kk][ty * 4];
            float4 b4 = *(const float4*)&bs[kk][tx * 4];
            float av[4] = {a4.x, a4.y, a4.z, a4.w};
            float bv[4] = {b4.x, b4.y, b4.z, b4.w};
            #pragma unroll
            for (int i = 0; i < 4; ++i)
                #pragma unroll
                for (int j = 0; j < 4; ++j)
                    acc[i][j] = fmaf(av[i], bv[j], acc[i][j]);
        }
        __syncthreads();
    }
    #pragma unroll
    for (int i = 0; i < 4; ++i) {
        size_t m = (size_t)m0 + ty * 4 + i;
        float4 o;
        o.x = acc[i][0] + bias[n0 + tx * 4 + 0];
        o.y = acc[i][1] + bias[n0 + tx * 4 + 1];
        o.z = acc[i][2] + bias[n0 + tx * 4 + 2];
        o.w = acc[i][3] + bias[n0 + tx * 4 + 3];
        *(float4*)(Cout + m * 192 + n0 + tx * 4) = o;
    }
}

extern "C" void kernel_launch(void* const* d_in, const int* in_sizes, int n_in,
                              void* d_out, int out_size, void* d_ws, size_t ws_size,
                              hipStream_t stream) {
    (void)in_sizes; (void)n_in; (void)out_size; (void)ws_size;
    const float* x      = (const float*)d_in[0];
    const float* w_qkv  = (const float*)d_in[1];
    const float* b_qkv  = (const float*)d_in[2];
    const float* w_dw1  = (const float*)d_in[3];
    const float* b_dw1  = (const float*)d_in[4];
    const float* g_bn1  = (const float*)d_in[5];
    const float* be_bn1 = (const float*)d_in[6];
    const float* w_si1  = (const float*)d_in[7];
    const float* b_si1  = (const float*)d_in[8];
    const float* g_si   = (const float*)d_in[9];
    const float* be_si  = (const float*)d_in[10];
    const float* w_si2  = (const float*)d_in[11];
    const float* b_si2  = (const float*)d_in[12];
    const float* w_ci1  = (const float*)d_in[13];
    const float* b_ci1  = (const float*)d_in[14];
    const float* g_ci   = (const float*)d_in[15];
    const float* be_ci  = (const float*)d_in[16];
    const float* w_ci2  = (const float*)d_in[17];
    const float* b_ci2  = (const float*)d_in[18];
    const float* w_dw2  = (const float*)d_in[19];
    const float* b_dw2  = (const float*)d_in[20];
    const float* g_bn2  = (const float*)d_in[21];
    const float* be_bn2 = (const float*)d_in[22];
    const float* w_proj = (const float*)d_in[23];
    const float* b_proj = (const float*)d_in[24];

    // ws layout (floats): [0, FUn) out2 / (alias) bf16 qkvb; then smalls.
    float* ws = (float*)d_ws;
    float* out2 = ws;
    unsigned short* qkvb = (unsigned short*)ws;        // 288*Mn bf16 = 75.5 MB, dies before out2
    float* gate_s  = ws + FUn;                         // B*L
    float* partial = gate_s + (size_t)Bn * Ln;         // B*H*192
    float* gate_c  = partial + (size_t)Bn * Hn * 192;  // B*192
    float* fu = (float*)d_out;                         // fu staged in d_out until proj

    qkv_gemm<0><<<dim3(Mn / 64, 5), 256, 0, stream>>>(x, w_qkv, b_qkv, qkvb);
    attn_kernel<0><<<3072, 128, 0, stream>>>(qkvb, fu);
    qkv_gemm<1><<<dim3(Mn / 64, 5), 256, 0, stream>>>(x, w_qkv, b_qkv, qkvb);
    attn_kernel<1><<<3072, 128, 0, stream>>>(qkvb, fu);
    dwconv1_gates<<<Bn * Hn, 128, 0, stream>>>(x, w_dw1, b_dw1, g_bn1, be_bn1,
                                               w_si1, b_si1, g_si, be_si, w_si2, b_si2,
                                               gate_s, partial);
    channel_gate_k<<<Bn, 192, 0, stream>>>(partial, w_ci1, b_ci1, g_ci, be_ci,
                                           w_ci2, b_ci2, gate_c);
    dwconv2_k<<<dim3(4, Hn, Bn), 256, 0, stream>>>(fu, gate_s, gate_c,
                                                   w_dw2, b_dw2, g_bn2, be_bn2, out2);
    gemm_projT<<<dim3(Mn / 64, 3), 256, 0, stream>>>(out2, w_proj, b_proj, (float*)d_out);
}

// Round 3
// 914.023 us; speedup vs baseline: 1.4627x; 1.4627x over previous
//
#include <hip/hip_runtime.h>

#define Bn 8
#define Hn 128
#define Wn 128
#define Cn 192
#define Ln (Hn*Wn)          // 16384
#define Mn (Bn*Ln)          // 131072
#define FUn ((size_t)Mn*Cn) // 25,165,824 floats
#define BN_RSQ 0.9999950000374997f   // 1/sqrt(1+1e-5)

typedef unsigned short ushort_t;
typedef __attribute__((ext_vector_type(8))) short short8;
typedef __attribute__((ext_vector_type(4))) float f32x4;

static __device__ __forceinline__ float gelu_f(float x) {
    return 0.5f * x * (1.0f + erff(x * 0.7071067811865475f));
}
static __device__ __forceinline__ float gate1p(float x) {  // 1 + sigmoid(x)
    return 1.0f + 1.0f / (1.0f + __expf(-x));
}
static __device__ __forceinline__ unsigned short f2bf(float f) {  // RNE
    unsigned u = __float_as_uint(f);
    return (unsigned short)((u + 0x7FFFu + ((u >> 16) & 1u)) >> 16);
}
static __device__ __forceinline__ unsigned int pk2(float lo, float hi) {
    return (unsigned int)f2bf(lo) | ((unsigned int)f2bf(hi) << 16);
}

// =================== qkv GEMM, bf16 MFMA 16x16x32 ===========================
// per branch: C[m][0:288] bf16; col layout part*96+off, part=q/k/v.
// grid (Mn/128, 3 parts), 256 thr. BM=128 BN=96 BK=64, K=192 (3 steps).
// LDS XOR swizzle: 16B slot s of row r stored at slot s^(r&7).  [G4/T2]
template<int BRANCH>
__global__ __launch_bounds__(256) void qkv_mfma(const float* __restrict__ A,
        const float* __restrict__ Bw, const float* __restrict__ bias,
        ushort_t* __restrict__ Q)
{
    __shared__ __align__(16) ushort_t As[128 * 64];   // [row][64k] swizzled, 16KB
    __shared__ __align__(16) ushort_t Bs[96 * 64];    // [col][64k] swizzled, 12KB
    const int m0 = blockIdx.x * 128;
    const int part = blockIdx.y;                      // 0..2
    const int bcol = part * 192 + BRANCH * 96;        // w_qkv global col base
    const int tid = threadIdx.x;
    const int lane = tid & 63;
    const int wrow = (tid >> 6) * 32;                 // wave's 32-row strip
    const int r0 = lane >> 4, cl = lane & 15;
    f32x4 acc[2][6] = {};

    for (int ks = 0; ks < 3; ++ks) {
        const int k0 = ks * 64;
        if (ks) __syncthreads();
        // ---- stage A: 128 rows x 64 k (f32 -> bf16) ----
        #pragma unroll
        for (int i = 0; i < 2; ++i) {
            int s = tid + i * 256;                    // 0..511
            int row = s >> 2, q = s & 3;
            const float* src = A + (size_t)(m0 + row) * 192 + k0 + q * 16;
            float4 v0 = *(const float4*)(src);
            float4 v1 = *(const float4*)(src + 4);
            float4 v2 = *(const float4*)(src + 8);
            float4 v3 = *(const float4*)(src + 12);
            uint4 w0 = make_uint4(pk2(v0.x, v0.y), pk2(v0.z, v0.w),
                                  pk2(v1.x, v1.y), pk2(v1.z, v1.w));
            uint4 w1 = make_uint4(pk2(v2.x, v2.y), pk2(v2.z, v2.w),
                                  pk2(v3.x, v3.y), pk2(v3.z, v3.w));
            int r7 = row & 7;
            *(uint4*)&As[row * 64 + (((q * 2) ^ r7) * 8)] = w0;
            *(uint4*)&As[row * 64 + (((q * 2 + 1) ^ r7) * 8)] = w1;
        }
        // ---- stage B: 96 cols x 64 k, col-major-k ----
        #pragma unroll
        for (int i = 0; i < 6; ++i) {
            int f = tid + i * 256;                    // 0..1535
            int k = f / 24, c4 = (f % 24) * 4;
            float4 v = *(const float4*)(Bw + (size_t)(k0 + k) * 576 + bcol + c4);
            int kw = k >> 3, ke = k & 7;
            Bs[(c4 + 0) * 64 + ((kw ^ ((c4 + 0) & 7)) * 8) + ke] = f2bf(v.x);
            Bs[(c4 + 1) * 64 + ((kw ^ ((c4 + 1) & 7)) * 8) + ke] = f2bf(v.y);
            Bs[(c4 + 2) * 64 + ((kw ^ ((c4 + 2) & 7)) * 8) + ke] = f2bf(v.z);
            Bs[(c4 + 3) * 64 + ((kw ^ ((c4 + 3) & 7)) * 8) + ke] = f2bf(v.w);
        }
        __syncthreads();
        // ---- MFMA ----
        #pragma unroll
        for (int kk = 0; kk < 2; ++kk) {
            int kslot = kk * 4 + r0;
            int ra0 = wrow + cl, ra1 = wrow + 16 + cl;
            short8 a0 = *(const short8*)&As[ra0 * 64 + ((kslot ^ (ra0 & 7)) * 8)];
            short8 a1 = *(const short8*)&As[ra1 * 64 + ((kslot ^ (ra1 & 7)) * 8)];
            #pragma unroll
            for (int n = 0; n < 6; ++n) {
                int col = n * 16 + cl;
                short8 bn = *(const short8*)&Bs[col * 64 + ((kslot ^ (col & 7)) * 8)];
                acc[0][n] = __builtin_amdgcn_mfma_f32_16x16x32_bf16(a0, bn, acc[0][n], 0, 0, 0);
                acc[1][n] = __builtin_amdgcn_mfma_f32_16x16x32_bf16(a1, bn, acc[1][n], 0, 0, 0);
            }
        }
    }
    // ---- epilogue: + bias, bf16 store into 288-col layout ----
    #pragma unroll
    for (int m = 0; m < 2; ++m) {
        #pragma unroll
        for (int n = 0; n < 6; ++n) {
            int col = n * 16 + cl;
            float bv = bias[bcol + col];
            #pragma unroll
            for (int j = 0; j < 4; ++j) {
                int row = m0 + wrow + m * 16 + r0 * 4 + j;
                Q[(size_t)row * 288 + part * 96 + col] = f2bf(acc[m][n][j] + bv);
            }
        }
    }
}

// =================== proj GEMM: bf16 A (row-major) x f32 Bw -> f32 out ======
__global__ __launch_bounds__(256) void proj_mfma(const ushort_t* __restrict__ Ab,
        const float* __restrict__ Bw, const float* __restrict__ bias,
        float* __restrict__ Cout)
{
    __shared__ __align__(16) ushort_t As[128 * 64];
    __shared__ __align__(16) ushort_t Bs[96 * 64];
    const int m0 = blockIdx.x * 128;
    const int n0 = blockIdx.y * 96;
    const int tid = threadIdx.x;
    const int lane = tid & 63;
    const int wrow = (tid >> 6) * 32;
    const int r0 = lane >> 4, cl = lane & 15;
    f32x4 acc[2][6] = {};

    for (int ks = 0; ks < 3; ++ks) {
        const int k0 = ks * 64;
        if (ks) __syncthreads();
        #pragma unroll
        for (int i = 0; i < 2; ++i) {
            int s = tid + i * 256;
            int row = s >> 2, q = s & 3;
            const ushort_t* src = Ab + (size_t)(m0 + row) * 192 + k0 + q * 16;
            uint4 u0 = *(const uint4*)(src);
            uint4 u1 = *(const uint4*)(src + 8);
            int r7 = row & 7;
            *(uint4*)&As[row * 64 + (((q * 2) ^ r7) * 8)] = u0;
            *(uint4*)&As[row * 64 + (((q * 2 + 1) ^ r7) * 8)] = u1;
        }
        #pragma unroll
        for (int i = 0; i < 6; ++i) {
            int f = tid + i * 256;
            int k = f / 24, c4 = (f % 24) * 4;
            float4 v = *(const float4*)(Bw + (size_t)(k0 + k) * 192 + n0 + c4);
            int kw = k >> 3, ke = k & 7;
            Bs[(c4 + 0) * 64 + ((kw ^ ((c4 + 0) & 7)) * 8) + ke] = f2bf(v.x);
            Bs[(c4 + 1) * 64 + ((kw ^ ((c4 + 1) & 7)) * 8) + ke] = f2bf(v.y);
            Bs[(c4 + 2) * 64 + ((kw ^ ((c4 + 2) & 7)) * 8) + ke] = f2bf(v.z);
            Bs[(c4 + 3) * 64 + ((kw ^ ((c4 + 3) & 7)) * 8) + ke] = f2bf(v.w);
        }
        __syncthreads();
        #pragma unroll
        for (int kk = 0; kk < 2; ++kk) {
            int kslot = kk * 4 + r0;
            int ra0 = wrow + cl, ra1 = wrow + 16 + cl;
            short8 a0 = *(const short8*)&As[ra0 * 64 + ((kslot ^ (ra0 & 7)) * 8)];
            short8 a1 = *(const short8*)&As[ra1 * 64 + ((kslot ^ (ra1 & 7)) * 8)];
            #pragma unroll
            for (int n = 0; n < 6; ++n) {
                int col = n * 16 + cl;
                short8 bn = *(const short8*)&Bs[col * 64 + ((kslot ^ (col & 7)) * 8)];
                acc[0][n] = __builtin_amdgcn_mfma_f32_16x16x32_bf16(a0, bn, acc[0][n], 0, 0, 0);
                acc[1][n] = __builtin_amdgcn_mfma_f32_16x16x32_bf16(a1, bn, acc[1][n], 0, 0, 0);
            }
        }
    }
    #pragma unroll
    for (int m = 0; m < 2; ++m) {
        #pragma unroll
        for (int n = 0; n < 6; ++n) {
            int col = n0 + n * 16 + cl;
            float bv = bias[col];
            #pragma unroll
            for (int j = 0; j < 4; ++j) {
                int row = m0 + wrow + m * 16 + r0 * 4 + j;
                Cout[(size_t)row * 192 + col] = acc[m][n][j] + bv;
            }
        }
    }
}

// ---------------- Window attention (one branch), bf16 in, f32 out -----------
template<int BRANCH>
__global__ __launch_bounds__(128) void attn_kernel(const ushort_t* __restrict__ Q,
                                                   float* __restrict__ fu)
{
    int idx = blockIdx.x;                  // 3072 = 3 heads * 8 b * 128 win
    int head = idx >> 10;
    int rem = idx & 1023;
    int b = rem >> 7;
    int win = rem & 127;
    int t = threadIdx.x;
    int h, w;
    if (BRANCH == 0) {                     // Hs=8, Ws=16
        int wy = win >> 3, wx = win & 7;
        h = wy * 8 + (t >> 4);
        w = wx * 16 + (t & 15);
    } else {                               // Hs=16, Ws=8
        int wy = win >> 4, wx = win & 15;
        h = wy * 16 + (t >> 3);
        w = wx * 8 + (t & 7);
    }
    int l = h * Wn + w;
    const ushort_t* row = Q + (size_t)(b * Ln + l) * 288 + head * 32;

    __shared__ float kb[128][32];
    __shared__ float vb[128][32];
    float q[32];
    #pragma unroll
    for (int c8 = 0; c8 < 4; ++c8) {
        uint4 uq = *(const uint4*)(row + c8 * 8);
        uint4 uk = *(const uint4*)(row + 96 + c8 * 8);
        uint4 uv = *(const uint4*)(row + 192 + c8 * 8);
        q[c8*8+0] = __uint_as_float(uq.x << 16); q[c8*8+1] = __uint_as_float(uq.x & 0xffff0000u);
        q[c8*8+2] = __uint_as_float(uq.y << 16); q[c8*8+3] = __uint_as_float(uq.y & 0xffff0000u);
        q[c8*8+4] = __uint_as_float(uq.z << 16); q[c8*8+5] = __uint_as_float(uq.z & 0xffff0000u);
        q[c8*8+6] = __uint_as_float(uq.w << 16); q[c8*8+7] = __uint_as_float(uq.w & 0xffff0000u);
        kb[t][c8*8+0] = __uint_as_float(uk.x << 16); kb[t][c8*8+1] = __uint_as_float(uk.x & 0xffff0000u);
        kb[t][c8*8+2] = __uint_as_float(uk.y << 16); kb[t][c8*8+3] = __uint_as_float(uk.y & 0xffff0000u);
        kb[t][c8*8+4] = __uint_as_float(uk.z << 16); kb[t][c8*8+5] = __uint_as_float(uk.z & 0xffff0000u);
        kb[t][c8*8+6] = __uint_as_float(uk.w << 16); kb[t][c8*8+7] = __uint_as_float(uk.w & 0xffff0000u);
        vb[t][c8*8+0] = __uint_as_float(uv.x << 16); vb[t][c8*8+1] = __uint_as_float(uv.x & 0xffff0000u);
        vb[t][c8*8+2] = __uint_as_float(uv.y << 16); vb[t][c8*8+3] = __uint_as_float(uv.y & 0xffff0000u);
        vb[t][c8*8+4] = __uint_as_float(uv.z << 16); vb[t][c8*8+5] = __uint_as_float(uv.z & 0xffff0000u);
        vb[t][c8*8+6] = __uint_as_float(uv.w << 16); vb[t][c8*8+7] = __uint_as_float(uv.w & 0xffff0000u);
    }
    __syncthreads();

    float mx = -1e30f, ssum = 0.0f;
    float acc[32] = {};
    for (int s = 0; s < 128; ++s) {
        float dot = 0.0f;
        #pragma unroll
        for (int d4 = 0; d4 < 8; ++d4) {
            float4 kk4 = *(const float4*)&kb[s][d4 * 4];
            dot = fmaf(q[d4*4+0], kk4.x, dot);
            dot = fmaf(q[d4*4+1], kk4.y, dot);
            dot = fmaf(q[d4*4+2], kk4.z, dot);
            dot = fmaf(q[d4*4+3], kk4.w, dot);
        }
        float logit = dot * 0.5303300858899106f;   // 3 / sqrt(32)
        float p;
        if (logit > mx) {
            float corr = __expf(mx - logit);
            ssum *= corr;
            #pragma unroll
            for (int d = 0; d < 32; ++d) acc[d] *= corr;
            mx = logit;
            p = 1.0f;
        } else {
            p = __expf(logit - mx);
        }
        ssum += p;
        #pragma unroll
        for (int d4 = 0; d4 < 8; ++d4) {
            float4 vv = *(const float4*)&vb[s][d4 * 4];
            acc[d4*4+0] = fmaf(p, vv.x, acc[d4*4+0]);
            acc[d4*4+1] = fmaf(p, vv.y, acc[d4*4+1]);
            acc[d4*4+2] = fmaf(p, vv.z, acc[d4*4+2]);
            acc[d4*4+3] = fmaf(p, vv.w, acc[d4*4+3]);
        }
    }
    float inv = 3.0f / ssum;
    float* orow = fu + (size_t)(b * Ln + l) * 192 + BRANCH * 96 + head * 32;
    #pragma unroll
    for (int d4 = 0; d4 < 8; ++d4) {
        float4 o;
        o.x = acc[d4*4+0] * inv;
        o.y = acc[d4*4+1] * inv;
        o.z = acc[d4*4+2] * inv;
        o.w = acc[d4*4+3] * inv;
        *(float4*)(orow + d4 * 4) = o;
    }
}

// ------ dwconv1 part A: conv+BN+GELU for 96 ch, partial gate acc + pool -----
__global__ __launch_bounds__(128) void dwconv1A(const float* __restrict__ x,
        const float* __restrict__ wdw, const float* __restrict__ bdw,
        const float* __restrict__ g1, const float* __restrict__ be1,
        const float* __restrict__ ws1g,
        float* __restrict__ partial24, float* __restrict__ pool_part)
{
    int bh = blockIdx.x;               // b*128 + h
    int g = blockIdx.y;                // channel group 0/1
    int b = bh >> 7, h = bh & 127;
    int w = threadIdx.x;
    __shared__ float ws1T[96 * 24];    // [cc][o]
    __shared__ float pacc[96][2];
    for (int i = w; i < 96 * 24; i += 128) {
        int cc = i / 24, o = i - cc * 24;
        ws1T[i] = ws1g[o * 192 + g * 96 + cc];
    }
    __syncthreads();
    float acc24[24] = {};
    int wave = w >> 6, lane = w & 63;
    for (int cc = 0; cc < 96; ++cc) {
        int c = g * 96 + cc;
        const float* bp = x + (size_t)(b * 192 + c) * Ln;
        float s = 0.0f;
        #pragma unroll
        for (int dy = -1; dy <= 1; ++dy) {
            int hh = h + dy;
            if (hh < 0 || hh >= Hn) continue;
            const float* rp = bp + hh * Wn;
            float w0c = wdw[c*9 + (dy+1)*3 + 0];
            float w1c = wdw[c*9 + (dy+1)*3 + 1];
            float w2c = wdw[c*9 + (dy+1)*3 + 2];
            if (w > 0)   s = fmaf(w0c, rp[w-1], s);
            s = fmaf(w1c, rp[w], s);
            if (w < 127) s = fmaf(w2c, rp[w+1], s);
        }
        float y = gelu_f((s + bdw[c]) * (g1[c] * BN_RSQ) + be1[c]);
        const float4* wp = (const float4*)&ws1T[cc * 24];
        #pragma unroll
        for (int o4 = 0; o4 < 6; ++o4) {
            float4 wv = wp[o4];
            acc24[o4*4+0] = fmaf(y, wv.x, acc24[o4*4+0]);
            acc24[o4*4+1] = fmaf(y, wv.y, acc24[o4*4+1]);
            acc24[o4*4+2] = fmaf(y, wv.z, acc24[o4*4+2]);
            acc24[o4*4+3] = fmaf(y, wv.w, acc24[o4*4+3]);
        }
        float r = y;
        for (int off = 32; off; off >>= 1) r += __shfl_down(r, off);
        if (lane == 0) pacc[cc][wave] = r;
    }
    __syncthreads();
    for (int cc = w; cc < 96; cc += 128)
        pool_part[(size_t)bh * 192 + g * 96 + cc] = pacc[cc][0] + pacc[cc][1];
    #pragma unroll
    for (int o = 0; o < 24; ++o)
        partial24[((size_t)(bh * 2 + g) * 24 + o) * 128 + w] = acc24[o];
}

// ------ dwconv1 part B: combine groups, gate MLP -> gate_s ------------------
__global__ __launch_bounds__(128) void dwconv1B(const float* __restrict__ partial24,
        const float* __restrict__ bs1, const float* __restrict__ gsi,
        const float* __restrict__ besi, const float* __restrict__ ws2,
        const float* __restrict__ bs2, float* __restrict__ gate_s)
{
    int bh = blockIdx.x;
    int w = threadIdx.x;
    const float* p0 = partial24 + (size_t)(bh * 2) * 24 * 128;
    float s2 = bs2[0];
    #pragma unroll
    for (int o = 0; o < 24; ++o) {
        float a = p0[o * 128 + w] + p0[(24 + o) * 128 + w] + bs1[o];
        s2 = fmaf(gelu_f(a * (gsi[o] * BN_RSQ) + besi[o]), ws2[o], s2);
    }
    gate_s[(size_t)bh * 128 + w] = gate1p(s2);
}

// ---------------- channel gate: pool-finalize + 192->24->192, 1+sigmoid -----
__global__ __launch_bounds__(192) void channel_gate_k(const float* __restrict__ partial,
        const float* __restrict__ w1, const float* __restrict__ b1,
        const float* __restrict__ g, const float* __restrict__ be,
        const float* __restrict__ w2, const float* __restrict__ b2,
        float* __restrict__ gate_c)
{
    int b = blockIdx.x, t = threadIdx.x;
    __shared__ float pl[192];
    __shared__ float h1[24];
    float s = 0.0f;
    for (int hh = 0; hh < 128; ++hh)
        s += partial[((size_t)b * 128 + hh) * 192 + t];
    pl[t] = s * (1.0f / Ln);
    __syncthreads();
    if (t < 24) {
        float a = b1[t];
        for (int c = 0; c < 192; ++c) a = fmaf(pl[c], w1[t * 192 + c], a);
        a = a * (g[t] * BN_RSQ) + be[t];
        h1[t] = gelu_f(a);
    }
    __syncthreads();
    float a = b2[t];
    #pragma unroll
    for (int o = 0; o < 24; ++o) a = fmaf(h1[o], w2[t * 24 + o], a);
    gate_c[b * 192 + t] = gate1p(a);
}

// ---- spatial-gated fu -> dwconv2 -> BN -> GELU -> ch gate, bf16 (B,L,C) out
__global__ __launch_bounds__(256) void dwconv2_k(const float* __restrict__ fu,
        const float* __restrict__ gate_s, const float* __restrict__ gate_c,
        const float* __restrict__ wdw, const float* __restrict__ bdw,
        const float* __restrict__ g2, const float* __restrict__ be2,
        ushort_t* __restrict__ out2b)
{
    int w0 = blockIdx.x * 32;
    int h  = blockIdx.y;
    int b  = blockIdx.z;
    int tid = threadIdx.x;
    __shared__ float ls[3][34][97];
    __shared__ float ybuf[32][97];
    int ww = tid & 31, co = tid >> 5;       // co in 0..7
    for (int half = 0; half < 2; ++half) {
        if (half) __syncthreads();
        for (int f = tid; f < 3 * 34 * 24; f += 256) {
            int c4 = f % 24;
            int pp = f / 24;
            int wl = pp % 34;
            int r  = pp / 34;
            int hr = h - 1 + r;
            int wp = w0 - 1 + wl;
            float4 v = make_float4(0.f, 0.f, 0.f, 0.f);
            if (hr >= 0 && hr < Hn && wp >= 0 && wp < Wn) {
                int l = hr * Wn + wp;
                v = *(const float4*)(fu + ((size_t)b * Ln + l) * 192 + half * 96 + c4 * 4);
                float gs = gate_s[(size_t)b * Ln + l];
                v.x *= gs; v.y *= gs; v.z *= gs; v.w *= gs;
            }
            float* d = &ls[r][wl][c4 * 4];
            d[0] = v.x; d[1] = v.y; d[2] = v.z; d[3] = v.w;
        }
        __syncthreads();
        #pragma unroll
        for (int j = 0; j < 12; ++j) {
            int cll = co * 12 + j;         // 0..95
            int c = half * 96 + cll;
            const float* wk = wdw + c * 9;
            float s = 0.0f;
            #pragma unroll
            for (int r = 0; r < 3; ++r) {
                s = fmaf(wk[r*3+0], ls[r][ww+0][cll], s);
                s = fmaf(wk[r*3+1], ls[r][ww+1][cll], s);
                s = fmaf(wk[r*3+2], ls[r][ww+2][cll], s);
            }
            float y = gelu_f((s + bdw[c]) * (g2[c] * BN_RSQ) + be2[c]) * gate_c[b * 192 + c];
            ybuf[ww][cll] = y;
        }
        __syncthreads();
        for (int f = tid; f < 32 * 12; f += 256) {
            int px = f / 12, c8 = f % 12;
            int l = h * Wn + w0 + px;
            float* yb = &ybuf[px][c8 * 8];
            uint4 o = make_uint4(pk2(yb[0], yb[1]), pk2(yb[2], yb[3]),
                                 pk2(yb[4], yb[5]), pk2(yb[6], yb[7]));
            *(uint4*)(out2b + ((size_t)b * Ln + l) * 192 + half * 96 + c8 * 8) = o;
        }
    }
}

extern "C" void kernel_launch(void* const* d_in, const int* in_sizes, int n_in,
                              void* d_out, int out_size, void* d_ws, size_t ws_size,
                              hipStream_t stream) {
    (void)in_sizes; (void)n_in; (void)out_size; (void)ws_size;
    const float* x      = (const float*)d_in[0];
    const float* w_qkv  = (const float*)d_in[1];
    const float* b_qkv  = (const float*)d_in[2];
    const float* w_dw1  = (const float*)d_in[3];
    const float* b_dw1  = (const float*)d_in[4];
    const float* g_bn1  = (const float*)d_in[5];
    const float* be_bn1 = (const float*)d_in[6];
    const float* w_si1  = (const float*)d_in[7];
    const float* b_si1  = (const float*)d_in[8];
    const float* g_si   = (const float*)d_in[9];
    const float* be_si  = (const float*)d_in[10];
    const float* w_si2  = (const float*)d_in[11];
    const float* b_si2  = (const float*)d_in[12];
    const float* w_ci1  = (const float*)d_in[13];
    const float* b_ci1  = (const float*)d_in[14];
    const float* g_ci   = (const float*)d_in[15];
    const float* be_ci  = (const float*)d_in[16];
    const float* w_ci2  = (const float*)d_in[17];
    const float* b_ci2  = (const float*)d_in[18];
    const float* w_dw2  = (const float*)d_in[19];
    const float* b_dw2  = (const float*)d_in[20];
    const float* g_bn2  = (const float*)d_in[21];
    const float* be_bn2 = (const float*)d_in[22];
    const float* w_proj = (const float*)d_in[23];
    const float* b_proj = (const float*)d_in[24];

    // ws layout (f32 units). Region A = [0, 18.87M f32):
    //   phase 1: qkvb bf16 (Mn*288 shorts = 18.87M f32)          [qkv+attn]
    //   phase 2: partial24 f32 [0, 6.29M) + pool_part [6.3M..)   [dwconv1]
    //   phase 3: out2b bf16 at f32-offset 8M (12.58M f32)        [dwconv2+proj]
    // gate_s/gate_c above FUn (proven in round 2).
    float* ws = (float*)d_ws;
    ushort_t* qkvb   = (ushort_t*)ws;
    float* partial24 = ws;                               // 6,291,456 f32
    float* pool_part = ws + 6400000;                     // 196,608 f32
    ushort_t* out2b  = (ushort_t*)(ws + 8000000);        // 25,165,824 shorts
    float* gate_s    = ws + FUn;                         // B*L
    float* gate_c    = gate_s + (size_t)Bn * Ln;         // B*192
    float* fu = (float*)d_out;                           // fu staged in d_out

    qkv_mfma<0><<<dim3(Mn / 128, 3), 256, 0, stream>>>(x, w_qkv, b_qkv, qkvb);
    attn_kernel<0><<<3072, 128, 0, stream>>>(qkvb, fu);
    qkv_mfma<1><<<dim3(Mn / 128, 3), 256, 0, stream>>>(x, w_qkv, b_qkv, qkvb);
    attn_kernel<1><<<3072, 128, 0, stream>>>(qkvb, fu);
    dwconv1A<<<dim3(Bn * Hn, 2), 128, 0, stream>>>(x, w_dw1, b_dw1, g_bn1, be_bn1,
                                                   w_si1, partial24, pool_part);
    dwconv1B<<<Bn * Hn, 128, 0, stream>>>(partial24, b_si1, g_si, be_si,
                                          w_si2, b_si2, gate_s);
    channel_gate_k<<<Bn, 192, 0, stream>>>(pool_part, w_ci1, b_ci1, g_ci, be_ci,
                                           w_ci2, b_ci2, gate_c);
    dwconv2_k<<<dim3(4, Hn, Bn), 256, 0, stream>>>(fu, gate_s, gate_c,
                                                   w_dw2, b_dw2, g_bn2, be_bn2, out2b);
    proj_mfma<<<dim3(Mn / 128, 2), 256, 0, stream>>>(out2b, w_proj, b_proj, (float*)d_out);
}

// Round 4
// 668.609 us; speedup vs baseline: 1.9996x; 1.3671x over previous
//
#include <hip/hip_runtime.h>

#define Bn 8
#define Hn 128
#define Wn 128
#define Cn 192
#define Ln (Hn*Wn)          // 16384
#define Mn (Bn*Ln)          // 131072
#define FUn ((size_t)Mn*Cn) // 25,165,824 floats
#define BN_RSQ 0.9999950000374997f   // 1/sqrt(1+1e-5)

typedef unsigned short ushort_t;
typedef __attribute__((ext_vector_type(8))) short short8;
typedef __attribute__((ext_vector_type(4))) float f32x4;

static __device__ __forceinline__ float gelu_f(float x) {
    return 0.5f * x * (1.0f + erff(x * 0.7071067811865475f));
}
static __device__ __forceinline__ float gate1p(float x) {  // 1 + sigmoid(x)
    return 1.0f + 1.0f / (1.0f + __expf(-x));
}
static __device__ __forceinline__ unsigned short f2bf(float f) {  // RNE
    unsigned u = __float_as_uint(f);
    return (unsigned short)((u + 0x7FFFu + ((u >> 16) & 1u)) >> 16);
}
static __device__ __forceinline__ unsigned int pk2(float lo, float hi) {
    return (unsigned int)f2bf(lo) | ((unsigned int)f2bf(hi) << 16);
}
static __device__ __forceinline__ float bf2f(ushort_t u) {
    return __uint_as_float((unsigned)u << 16);
}

// =================== qkv GEMM, bf16 MFMA 16x16x32 ===========================
template<int BRANCH>
__global__ __launch_bounds__(256) void qkv_mfma(const float* __restrict__ A,
        const float* __restrict__ Bw, const float* __restrict__ bias,
        ushort_t* __restrict__ Q)
{
    __shared__ __align__(16) ushort_t As[128 * 64];
    __shared__ __align__(16) ushort_t Bs[96 * 64];
    const int m0 = blockIdx.x * 128;
    const int part = blockIdx.y;                      // 0..2
    const int bcol = part * 192 + BRANCH * 96;
    const int tid = threadIdx.x;
    const int lane = tid & 63;
    const int wrow = (tid >> 6) * 32;
    const int r0 = lane >> 4, cl = lane & 15;
    f32x4 acc[2][6] = {};

    for (int ks = 0; ks < 3; ++ks) {
        const int k0 = ks * 64;
        if (ks) __syncthreads();
        #pragma unroll
        for (int i = 0; i < 2; ++i) {
            int s = tid + i * 256;
            int row = s >> 2, q = s & 3;
            const float* src = A + (size_t)(m0 + row) * 192 + k0 + q * 16;
            float4 v0 = *(const float4*)(src);
            float4 v1 = *(const float4*)(src + 4);
            float4 v2 = *(const float4*)(src + 8);
            float4 v3 = *(const float4*)(src + 12);
            uint4 w0 = make_uint4(pk2(v0.x, v0.y), pk2(v0.z, v0.w),
                                  pk2(v1.x, v1.y), pk2(v1.z, v1.w));
            uint4 w1 = make_uint4(pk2(v2.x, v2.y), pk2(v2.z, v2.w),
                                  pk2(v3.x, v3.y), pk2(v3.z, v3.w));
            int r7 = row & 7;
            *(uint4*)&As[row * 64 + (((q * 2) ^ r7) * 8)] = w0;
            *(uint4*)&As[row * 64 + (((q * 2 + 1) ^ r7) * 8)] = w1;
        }
        #pragma unroll
        for (int i = 0; i < 6; ++i) {
            int f = tid + i * 256;
            int k = f / 24, c4 = (f % 24) * 4;
            float4 v = *(const float4*)(Bw + (size_t)(k0 + k) * 576 + bcol + c4);
            int kw = k >> 3, ke = k & 7;
            Bs[(c4 + 0) * 64 + ((kw ^ ((c4 + 0) & 7)) * 8) + ke] = f2bf(v.x);
            Bs[(c4 + 1) * 64 + ((kw ^ ((c4 + 1) & 7)) * 8) + ke] = f2bf(v.y);
            Bs[(c4 + 2) * 64 + ((kw ^ ((c4 + 2) & 7)) * 8) + ke] = f2bf(v.z);
            Bs[(c4 + 3) * 64 + ((kw ^ ((c4 + 3) & 7)) * 8) + ke] = f2bf(v.w);
        }
        __syncthreads();
        #pragma unroll
        for (int kk = 0; kk < 2; ++kk) {
            int kslot = kk * 4 + r0;
            int ra0 = wrow + cl, ra1 = wrow + 16 + cl;
            short8 a0 = *(const short8*)&As[ra0 * 64 + ((kslot ^ (ra0 & 7)) * 8)];
            short8 a1 = *(const short8*)&As[ra1 * 64 + ((kslot ^ (ra1 & 7)) * 8)];
            #pragma unroll
            for (int n = 0; n < 6; ++n) {
                int col = n * 16 + cl;
                short8 bn = *(const short8*)&Bs[col * 64 + ((kslot ^ (col & 7)) * 8)];
                acc[0][n] = __builtin_amdgcn_mfma_f32_16x16x32_bf16(a0, bn, acc[0][n], 0, 0, 0);
                acc[1][n] = __builtin_amdgcn_mfma_f32_16x16x32_bf16(a1, bn, acc[1][n], 0, 0, 0);
            }
        }
    }
    #pragma unroll
    for (int m = 0; m < 2; ++m) {
        #pragma unroll
        for (int n = 0; n < 6; ++n) {
            int col = n * 16 + cl;
            float bv = bias[bcol + col];
            #pragma unroll
            for (int j = 0; j < 4; ++j) {
                int row = m0 + wrow + m * 16 + r0 * 4 + j;
                Q[(size_t)row * 288 + part * 96 + col] = f2bf(acc[m][n][j] + bv);
            }
        }
    }
}

// =================== proj GEMM: bf16 A (row-major) x f32 Bw -> f32 out ======
__global__ __launch_bounds__(256) void proj_mfma(const ushort_t* __restrict__ Ab,
        const float* __restrict__ Bw, const float* __restrict__ bias,
        float* __restrict__ Cout)
{
    __shared__ __align__(16) ushort_t As[128 * 64];
    __shared__ __align__(16) ushort_t Bs[96 * 64];
    const int m0 = blockIdx.x * 128;
    const int n0 = blockIdx.y * 96;
    const int tid = threadIdx.x;
    const int lane = tid & 63;
    const int wrow = (tid >> 6) * 32;
    const int r0 = lane >> 4, cl = lane & 15;
    f32x4 acc[2][6] = {};

    for (int ks = 0; ks < 3; ++ks) {
        const int k0 = ks * 64;
        if (ks) __syncthreads();
        #pragma unroll
        for (int i = 0; i < 2; ++i) {
            int s = tid + i * 256;
            int row = s >> 2, q = s & 3;
            const ushort_t* src = Ab + (size_t)(m0 + row) * 192 + k0 + q * 16;
            uint4 u0 = *(const uint4*)(src);
            uint4 u1 = *(const uint4*)(src + 8);
            int r7 = row & 7;
            *(uint4*)&As[row * 64 + (((q * 2) ^ r7) * 8)] = u0;
            *(uint4*)&As[row * 64 + (((q * 2 + 1) ^ r7) * 8)] = u1;
        }
        #pragma unroll
        for (int i = 0; i < 6; ++i) {
            int f = tid + i * 256;
            int k = f / 24, c4 = (f % 24) * 4;
            float4 v = *(const float4*)(Bw + (size_t)(k0 + k) * 192 + n0 + c4);
            int kw = k >> 3, ke = k & 7;
            Bs[(c4 + 0) * 64 + ((kw ^ ((c4 + 0) & 7)) * 8) + ke] = f2bf(v.x);
            Bs[(c4 + 1) * 64 + ((kw ^ ((c4 + 1) & 7)) * 8) + ke] = f2bf(v.y);
            Bs[(c4 + 2) * 64 + ((kw ^ ((c4 + 2) & 7)) * 8) + ke] = f2bf(v.z);
            Bs[(c4 + 3) * 64 + ((kw ^ ((c4 + 3) & 7)) * 8) + ke] = f2bf(v.w);
        }
        __syncthreads();
        #pragma unroll
        for (int kk = 0; kk < 2; ++kk) {
            int kslot = kk * 4 + r0;
            int ra0 = wrow + cl, ra1 = wrow + 16 + cl;
            short8 a0 = *(const short8*)&As[ra0 * 64 + ((kslot ^ (ra0 & 7)) * 8)];
            short8 a1 = *(const short8*)&As[ra1 * 64 + ((kslot ^ (ra1 & 7)) * 8)];
            #pragma unroll
            for (int n = 0; n < 6; ++n) {
                int col = n * 16 + cl;
                short8 bn = *(const short8*)&Bs[col * 64 + ((kslot ^ (col & 7)) * 8)];
                acc[0][n] = __builtin_amdgcn_mfma_f32_16x16x32_bf16(a0, bn, acc[0][n], 0, 0, 0);
                acc[1][n] = __builtin_amdgcn_mfma_f32_16x16x32_bf16(a1, bn, acc[1][n], 0, 0, 0);
            }
        }
    }
    #pragma unroll
    for (int m = 0; m < 2; ++m) {
        #pragma unroll
        for (int n = 0; n < 6; ++n) {
            int col = n0 + n * 16 + cl;
            float bv = bias[col];
            #pragma unroll
            for (int j = 0; j < 4; ++j) {
                int row = m0 + wrow + m * 16 + r0 * 4 + j;
                Cout[(size_t)row * 192 + col] = acc[m][n][j] + bv;
            }
        }
    }
}

// ------- Window attention, bf16 in, f32 out. No online-max (logits bounded) -
template<int BRANCH>
__global__ __launch_bounds__(128) void attn_kernel(const ushort_t* __restrict__ Q,
                                                   float* __restrict__ fu)
{
    int idx = blockIdx.x;                  // 3072 = 3 heads * 8 b * 128 win
    int head = idx >> 10;
    int rem = idx & 1023;
    int b = rem >> 7;
    int win = rem & 127;
    int t = threadIdx.x;
    int h, w;
    if (BRANCH == 0) {                     // Hs=8, Ws=16
        int wy = win >> 3, wx = win & 7;
        h = wy * 8 + (t >> 4);
        w = wx * 16 + (t & 15);
    } else {                               // Hs=16, Ws=8
        int wy = win >> 4, wx = win & 15;
        h = wy * 16 + (t >> 3);
        w = wx * 8 + (t & 7);
    }
    int l = h * Wn + w;
    const ushort_t* row = Q + (size_t)(b * Ln + l) * 288 + head * 32;

    __shared__ float kb[128][32];
    __shared__ float vb[128][32];
    float q[32];
    #pragma unroll
    for (int c8 = 0; c8 < 4; ++c8) {
        uint4 uq = *(const uint4*)(row + c8 * 8);
        uint4 uk = *(const uint4*)(row + 96 + c8 * 8);
        uint4 uv = *(const uint4*)(row + 192 + c8 * 8);
        q[c8*8+0] = __uint_as_float(uq.x << 16); q[c8*8+1] = __uint_as_float(uq.x & 0xffff0000u);
        q[c8*8+2] = __uint_as_float(uq.y << 16); q[c8*8+3] = __uint_as_float(uq.y & 0xffff0000u);
        q[c8*8+4] = __uint_as_float(uq.z << 16); q[c8*8+5] = __uint_as_float(uq.z & 0xffff0000u);
        q[c8*8+6] = __uint_as_float(uq.w << 16); q[c8*8+7] = __uint_as_float(uq.w & 0xffff0000u);
        kb[t][c8*8+0] = __uint_as_float(uk.x << 16); kb[t][c8*8+1] = __uint_as_float(uk.x & 0xffff0000u);
        kb[t][c8*8+2] = __uint_as_float(uk.y << 16); kb[t][c8*8+3] = __uint_as_float(uk.y & 0xffff0000u);
        kb[t][c8*8+4] = __uint_as_float(uk.z << 16); kb[t][c8*8+5] = __uint_as_float(uk.z & 0xffff0000u);
        kb[t][c8*8+6] = __uint_as_float(uk.w << 16); kb[t][c8*8+7] = __uint_as_float(uk.w & 0xffff0000u);
        vb[t][c8*8+0] = __uint_as_float(uv.x << 16); vb[t][c8*8+1] = __uint_as_float(uv.x & 0xffff0000u);
        vb[t][c8*8+2] = __uint_as_float(uv.y << 16); vb[t][c8*8+3] = __uint_as_float(uv.y & 0xffff0000u);
        vb[t][c8*8+4] = __uint_as_float(uv.z << 16); vb[t][c8*8+5] = __uint_as_float(uv.z & 0xffff0000u);
        vb[t][c8*8+6] = __uint_as_float(uv.w << 16); vb[t][c8*8+7] = __uint_as_float(uv.w & 0xffff0000u);
    }
    __syncthreads();

    float ssum = 0.0f;
    float acc[32] = {};
    #pragma unroll 2
    for (int s = 0; s < 128; ++s) {
        float dot = 0.0f;
        #pragma unroll
        for (int d4 = 0; d4 < 8; ++d4) {
            float4 kk4 = *(const float4*)&kb[s][d4 * 4];
            dot = fmaf(q[d4*4+0], kk4.x, dot);
            dot = fmaf(q[d4*4+1], kk4.y, dot);
            dot = fmaf(q[d4*4+2], kk4.z, dot);
            dot = fmaf(q[d4*4+3], kk4.w, dot);
        }
        float p = __expf(dot * 0.5303300858899106f);   // 3 / sqrt(32); |logit|<~5
        ssum += p;
        #pragma unroll
        for (int d4 = 0; d4 < 8; ++d4) {
            float4 vv = *(const float4*)&vb[s][d4 * 4];
            acc[d4*4+0] = fmaf(p, vv.x, acc[d4*4+0]);
            acc[d4*4+1] = fmaf(p, vv.y, acc[d4*4+1]);
            acc[d4*4+2] = fmaf(p, vv.z, acc[d4*4+2]);
            acc[d4*4+3] = fmaf(p, vv.w, acc[d4*4+3]);
        }
    }
    float inv = 3.0f / ssum;
    float* orow = fu + (size_t)(b * Ln + l) * 192 + BRANCH * 96 + head * 32;
    #pragma unroll
    for (int d4 = 0; d4 < 8; ++d4) {
        float4 o;
        o.x = acc[d4*4+0] * inv;
        o.y = acc[d4*4+1] * inv;
        o.z = acc[d4*4+2] * inv;
        o.w = acc[d4*4+3] * inv;
        *(float4*)(orow + d4 * 4) = o;
    }
}

// ------- conv1: dwconv3x3+BN+GELU per (b,c) plane -> bf16, + pooled mean ----
__global__ __launch_bounds__(256) void conv1_k(const float* __restrict__ x,
        const float* __restrict__ wdw, const float* __restrict__ bdw,
        const float* __restrict__ g1, const float* __restrict__ be1,
        ushort_t* __restrict__ conv1b, float* __restrict__ pooled)
{
    int bc = blockIdx.x;                   // b*192 + c
    int c = bc % 192;
    const float* plane = x + (size_t)bc * Ln;
    ushort_t* oplane = conv1b + (size_t)bc * Ln;
    int t = threadIdx.x;
    int wp = (t & 63) * 2;                 // even pixel pair
    int hr = t >> 6;                       // 0..3
    float wk[9];
    #pragma unroll
    for (int i = 0; i < 9; ++i) wk[i] = wdw[c * 9 + i];
    float gb = g1[c] * BN_RSQ, bb = be1[c], bd = bdw[c];
    float psum = 0.0f;
    for (int hi = 0; hi < 32; ++hi) {
        int h = hi * 4 + hr;
        float a0 = 0.0f, a1 = 0.0f;
        #pragma unroll
        for (int r = 0; r < 3; ++r) {
            int hh = h - 1 + r;
            if (hh < 0 || hh >= Hn) continue;
            const float* rp = plane + hh * Wn;
            float xm = (wp > 0) ? rp[wp - 1] : 0.0f;
            float2 x01 = *(const float2*)(rp + wp);
            float xp = (wp < 126) ? rp[wp + 2] : 0.0f;
            a0 = fmaf(wk[r*3+0], xm, a0);
            a0 = fmaf(wk[r*3+1], x01.x, a0);
            a0 = fmaf(wk[r*3+2], x01.y, a0);
            a1 = fmaf(wk[r*3+0], x01.x, a1);
            a1 = fmaf(wk[r*3+1], x01.y, a1);
            a1 = fmaf(wk[r*3+2], xp, a1);
        }
        float y0 = gelu_f((a0 + bd) * gb + bb);
        float y1 = gelu_f((a1 + bd) * gb + bb);
        psum += y0 + y1;
        *(unsigned int*)(oplane + h * Wn + wp) = pk2(y0, y1);
    }
    // block reduce psum (256 threads)
    __shared__ float red[4];
    for (int off = 32; off; off >>= 1) psum += __shfl_down(psum, off);
    if ((t & 63) == 0) red[t >> 6] = psum;
    __syncthreads();
    if (t == 0)
        pooled[bc] = (red[0] + red[1] + red[2] + red[3]) * (1.0f / Ln);
}

// ------- spatial gate: per-pixel 192->24->1 MLP on bf16 conv1 ---------------
__global__ __launch_bounds__(128) void spatial_gate_k(const ushort_t* __restrict__ conv1b,
        const float* __restrict__ ws1g, const float* __restrict__ bs1,
        const float* __restrict__ gsi, const float* __restrict__ besi,
        const float* __restrict__ ws2, const float* __restrict__ bs2,
        float* __restrict__ gate_s)
{
    int bh = blockIdx.x;                   // b*128 + h
    int b = bh >> 7, h = bh & 127;
    int w = threadIdx.x;
    __shared__ float ws1T[192 * 24];       // [c][o]
    for (int i = w; i < 192 * 24; i += 128) {
        int c = i / 24, o = i - c * 24;
        ws1T[i] = ws1g[o * 192 + c];
    }
    __syncthreads();
    float acc24[24] = {};
    const ushort_t* base = conv1b + (size_t)b * 192 * Ln + h * Wn + w;
    #pragma unroll 4
    for (int c = 0; c < 192; ++c) {
        float v = bf2f(base[(size_t)c * Ln]);
        const float4* wp = (const float4*)&ws1T[c * 24];
        #pragma unroll
        for (int o4 = 0; o4 < 6; ++o4) {
            float4 wv = wp[o4];
            acc24[o4*4+0] = fmaf(v, wv.x, acc24[o4*4+0]);
            acc24[o4*4+1] = fmaf(v, wv.y, acc24[o4*4+1]);
            acc24[o4*4+2] = fmaf(v, wv.z, acc24[o4*4+2]);
            acc24[o4*4+3] = fmaf(v, wv.w, acc24[o4*4+3]);
        }
    }
    float s2 = bs2[0];
    #pragma unroll
    for (int o = 0; o < 24; ++o)
        s2 = fmaf(gelu_f((acc24[o] + bs1[o]) * (gsi[o] * BN_RSQ) + besi[o]), ws2[o], s2);
    gate_s[(size_t)bh * 128 + w] = gate1p(s2);
}

// ---------------- channel gate: 192->24->192 MLP on pooled ------------------
__global__ __launch_bounds__(192) void channel_gate_k(const float* __restrict__ pooled,
        const float* __restrict__ w1, const float* __restrict__ b1,
        const float* __restrict__ g, const float* __restrict__ be,
        const float* __restrict__ w2, const float* __restrict__ b2,
        float* __restrict__ gate_c)
{
    int b = blockIdx.x, t = threadIdx.x;
    __shared__ float pl[192];
    __shared__ float h1[24];
    pl[t] = pooled[b * 192 + t];
    __syncthreads();
    if (t < 24) {
        float a = b1[t];
        for (int c = 0; c < 192; ++c) a = fmaf(pl[c], w1[t * 192 + c], a);
        a = a * (g[t] * BN_RSQ) + be[t];
        h1[t] = gelu_f(a);
    }
    __syncthreads();
    float a = b2[t];
    #pragma unroll
    for (int o = 0; o < 24; ++o) a = fmaf(h1[o], w2[t * 24 + o], a);
    gate_c[b * 192 + t] = gate1p(a);
}

// ---- spatial-gated fu -> dwconv2 -> BN -> GELU -> ch gate, bf16 (B,L,C) out
__global__ __launch_bounds__(256) void dwconv2_k(const float* __restrict__ fu,
        const float* __restrict__ gate_s, const float* __restrict__ gate_c,
        const float* __restrict__ wdw, const float* __restrict__ bdw,
        const float* __restrict__ g2, const float* __restrict__ be2,
        ushort_t* __restrict__ out2b)
{
    int w0 = blockIdx.x * 32;
    int h  = blockIdx.y;
    int b  = blockIdx.z;
    int tid = threadIdx.x;
    __shared__ float ls[3][34][97];
    __shared__ float ybuf[32][97];
    int ww = tid & 31, co = tid >> 5;
    for (int half = 0; half < 2; ++half) {
        if (half) __syncthreads();
        for (int f = tid; f < 3 * 34 * 24; f += 256) {
            int c4 = f % 24;
            int pp = f / 24;
            int wl = pp % 34;
            int r  = pp / 34;
            int hr = h - 1 + r;
            int wp = w0 - 1 + wl;
            float4 v = make_float4(0.f, 0.f, 0.f, 0.f);
            if (hr >= 0 && hr < Hn && wp >= 0 && wp < Wn) {
                int l = hr * Wn + wp;
                v = *(const float4*)(fu + ((size_t)b * Ln + l) * 192 + half * 96 + c4 * 4);
                float gs = gate_s[(size_t)b * Ln + l];
                v.x *= gs; v.y *= gs; v.z *= gs; v.w *= gs;
            }
            float* d = &ls[r][wl][c4 * 4];
            d[0] = v.x; d[1] = v.y; d[2] = v.z; d[3] = v.w;
        }
        __syncthreads();
        #pragma unroll
        for (int j = 0; j < 12; ++j) {
            int cll = co * 12 + j;
            int c = half * 96 + cll;
            const float* wk = wdw + c * 9;
            float s = 0.0f;
            #pragma unroll
            for (int r = 0; r < 3; ++r) {
                s = fmaf(wk[r*3+0], ls[r][ww+0][cll], s);
                s = fmaf(wk[r*3+1], ls[r][ww+1][cll], s);
                s = fmaf(wk[r*3+2], ls[r][ww+2][cll], s);
            }
            float y = gelu_f((s + bdw[c]) * (g2[c] * BN_RSQ) + be2[c]) * gate_c[b * 192 + c];
            ybuf[ww][cll] = y;
        }
        __syncthreads();
        for (int f = tid; f < 32 * 12; f += 256) {
            int px = f / 12, c8 = f % 12;
            int l = h * Wn + w0 + px;
            float* yb = &ybuf[px][c8 * 8];
            uint4 o = make_uint4(pk2(yb[0], yb[1]), pk2(yb[2], yb[3]),
                                 pk2(yb[4], yb[5]), pk2(yb[6], yb[7]));
            *(uint4*)(out2b + ((size_t)b * Ln + l) * 192 + half * 96 + c8 * 8) = o;
        }
    }
}

extern "C" void kernel_launch(void* const* d_in, const int* in_sizes, int n_in,
                              void* d_out, int out_size, void* d_ws, size_t ws_size,
                              hipStream_t stream) {
    (void)in_sizes; (void)n_in; (void)out_size; (void)ws_size;
    const float* x      = (const float*)d_in[0];
    const float* w_qkv  = (const float*)d_in[1];
    const float* b_qkv  = (const float*)d_in[2];
    const float* w_dw1  = (const float*)d_in[3];
    const float* b_dw1  = (const float*)d_in[4];
    const float* g_bn1  = (const float*)d_in[5];
    const float* be_bn1 = (const float*)d_in[6];
    const float* w_si1  = (const float*)d_in[7];
    const float* b_si1  = (const float*)d_in[8];
    const float* g_si   = (const float*)d_in[9];
    const float* be_si  = (const float*)d_in[10];
    const float* w_si2  = (const float*)d_in[11];
    const float* b_si2  = (const float*)d_in[12];
    const float* w_ci1  = (const float*)d_in[13];
    const float* b_ci1  = (const float*)d_in[14];
    const float* g_ci   = (const float*)d_in[15];
    const float* be_ci  = (const float*)d_in[16];
    const float* w_ci2  = (const float*)d_in[17];
    const float* b_ci2  = (const float*)d_in[18];
    const float* w_dw2  = (const float*)d_in[19];
    const float* b_dw2  = (const float*)d_in[20];
    const float* g_bn2  = (const float*)d_in[21];
    const float* be_bn2 = (const float*)d_in[22];
    const float* w_proj = (const float*)d_in[23];
    const float* b_proj = (const float*)d_in[24];

    // ws (f32 units):
    //   phase 1: qkvb bf16 [0, 18.87M f32)           [qkv+attn]
    //   phase 2: conv1b bf16 [0, 12.58M f32)         [conv1 -> spatial gate]
    //   phase 3: out2b bf16 at 8M..20.58M            [dwconv2 -> proj]
    //   smalls above FUn: gate_s, gate_c, pooled
    float* ws = (float*)d_ws;
    ushort_t* qkvb   = (ushort_t*)ws;
    ushort_t* conv1b = (ushort_t*)ws;
    ushort_t* out2b  = (ushort_t*)(ws + 8000000);
    float* gate_s    = ws + FUn;                       // B*L
    float* gate_c    = gate_s + (size_t)Bn * Ln;       // B*192
    float* pooled    = gate_c + Bn * 192;              // B*192
    float* fu = (float*)d_out;

    qkv_mfma<0><<<dim3(Mn / 128, 3), 256, 0, stream>>>(x, w_qkv, b_qkv, qkvb);
    attn_kernel<0><<<3072, 128, 0, stream>>>(qkvb, fu);
    qkv_mfma<1><<<dim3(Mn / 128, 3), 256, 0, stream>>>(x, w_qkv, b_qkv, qkvb);
    attn_kernel<1><<<3072, 128, 0, stream>>>(qkvb, fu);
    conv1_k<<<Bn * 192, 256, 0, stream>>>(x, w_dw1, b_dw1, g_bn1, be_bn1, conv1b, pooled);
    spatial_gate_k<<<Bn * Hn, 128, 0, stream>>>(conv1b, w_si1, b_si1, g_si, be_si,
                                                w_si2, b_si2, gate_s);
    channel_gate_k<<<Bn, 192, 0, stream>>>(pooled, w_ci1, b_ci1, g_ci, be_ci,
                                           w_ci2, b_ci2, gate_c);
    dwconv2_k<<<dim3(4, Hn, Bn), 256, 0, stream>>>(fu, gate_s, gate_c,
                                                   w_dw2, b_dw2, g_bn2, be_bn2, out2b);
    proj_mfma<<<dim3(Mn / 128, 2), 256, 0, stream>>>(out2b, w_proj, b_proj, (float*)d_out);
}

// Round 5
// 617.707 us; speedup vs baseline: 2.1644x; 1.0824x over previous
//
#include <hip/hip_runtime.h>

#define Bn 8
#define Hn 128
#define Wn 128
#define Cn 192
#define Ln (Hn*Wn)          // 16384
#define Mn (Bn*Ln)          // 131072
#define FUn ((size_t)Mn*Cn) // 25,165,824 floats
#define BN_RSQ 0.9999950000374997f   // 1/sqrt(1+1e-5)

typedef unsigned short ushort_t;
typedef __attribute__((ext_vector_type(8))) short short8;
typedef __attribute__((ext_vector_type(4))) float f32x4;
typedef __attribute__((ext_vector_type(4))) unsigned int uint4v;

static __device__ __forceinline__ float gelu_f(float x) {
    return 0.5f * x * (1.0f + erff(x * 0.7071067811865475f));
}
static __device__ __forceinline__ float gate1p(float x) {  // 1 + sigmoid(x)
    return 1.0f + 1.0f / (1.0f + __expf(-x));
}
static __device__ __forceinline__ unsigned short f2bf(float f) {  // RNE
    unsigned u = __float_as_uint(f);
    return (unsigned short)((u + 0x7FFFu + ((u >> 16) & 1u)) >> 16);
}
static __device__ __forceinline__ unsigned int pk2(float lo, float hi) {
    return (unsigned int)f2bf(lo) | ((unsigned int)f2bf(hi) << 16);
}
static __device__ __forceinline__ float bf2f(ushort_t u) {
    return __uint_as_float((unsigned)u << 16);
}

// =================== qkv GEMM, bf16 MFMA 16x16x32 ===========================
template<int BRANCH>
__global__ __launch_bounds__(256) void qkv_mfma(const float* __restrict__ A,
        const float* __restrict__ Bw, const float* __restrict__ bias,
        ushort_t* __restrict__ Q)
{
    __shared__ __align__(16) ushort_t As[128 * 64];
    __shared__ __align__(16) ushort_t Bs[96 * 64];
    const int m0 = blockIdx.x * 128;
    const int part = blockIdx.y;                      // 0..2
    const int bcol = part * 192 + BRANCH * 96;
    const int tid = threadIdx.x;
    const int lane = tid & 63;
    const int wrow = (tid >> 6) * 32;
    const int r0 = lane >> 4, cl = lane & 15;
    f32x4 acc[2][6] = {};

    for (int ks = 0; ks < 3; ++ks) {
        const int k0 = ks * 64;
        if (ks) __syncthreads();
        #pragma unroll
        for (int i = 0; i < 2; ++i) {
            int s = tid + i * 256;
            int row = s >> 2, q = s & 3;
            const float* src = A + (size_t)(m0 + row) * 192 + k0 + q * 16;
            float4 v0 = *(const float4*)(src);
            float4 v1 = *(const float4*)(src + 4);
            float4 v2 = *(const float4*)(src + 8);
            float4 v3 = *(const float4*)(src + 12);
            uint4 w0 = make_uint4(pk2(v0.x, v0.y), pk2(v0.z, v0.w),
                                  pk2(v1.x, v1.y), pk2(v1.z, v1.w));
            uint4 w1 = make_uint4(pk2(v2.x, v2.y), pk2(v2.z, v2.w),
                                  pk2(v3.x, v3.y), pk2(v3.z, v3.w));
            int r7 = row & 7;
            *(uint4*)&As[row * 64 + (((q * 2) ^ r7) * 8)] = w0;
            *(uint4*)&As[row * 64 + (((q * 2 + 1) ^ r7) * 8)] = w1;
        }
        #pragma unroll
        for (int i = 0; i < 6; ++i) {
            int f = tid + i * 256;
            int k = f / 24, c4 = (f % 24) * 4;
            float4 v = *(const float4*)(Bw + (size_t)(k0 + k) * 576 + bcol + c4);
            int kw = k >> 3, ke = k & 7;
            Bs[(c4 + 0) * 64 + ((kw ^ ((c4 + 0) & 7)) * 8) + ke] = f2bf(v.x);
            Bs[(c4 + 1) * 64 + ((kw ^ ((c4 + 1) & 7)) * 8) + ke] = f2bf(v.y);
            Bs[(c4 + 2) * 64 + ((kw ^ ((c4 + 2) & 7)) * 8) + ke] = f2bf(v.z);
            Bs[(c4 + 3) * 64 + ((kw ^ ((c4 + 3) & 7)) * 8) + ke] = f2bf(v.w);
        }
        __syncthreads();
        #pragma unroll
        for (int kk = 0; kk < 2; ++kk) {
            int kslot = kk * 4 + r0;
            int ra0 = wrow + cl, ra1 = wrow + 16 + cl;
            short8 a0 = *(const short8*)&As[ra0 * 64 + ((kslot ^ (ra0 & 7)) * 8)];
            short8 a1 = *(const short8*)&As[ra1 * 64 + ((kslot ^ (ra1 & 7)) * 8)];
            #pragma unroll
            for (int n = 0; n < 6; ++n) {
                int col = n * 16 + cl;
                short8 bn = *(const short8*)&Bs[col * 64 + ((kslot ^ (col & 7)) * 8)];
                acc[0][n] = __builtin_amdgcn_mfma_f32_16x16x32_bf16(a0, bn, acc[0][n], 0, 0, 0);
                acc[1][n] = __builtin_amdgcn_mfma_f32_16x16x32_bf16(a1, bn, acc[1][n], 0, 0, 0);
            }
        }
    }
    #pragma unroll
    for (int m = 0; m < 2; ++m) {
        #pragma unroll
        for (int n = 0; n < 6; ++n) {
            int col = n * 16 + cl;
            float bv = bias[bcol + col];
            #pragma unroll
            for (int j = 0; j < 4; ++j) {
                int row = m0 + wrow + m * 16 + r0 * 4 + j;
                Q[(size_t)row * 288 + part * 96 + col] = f2bf(acc[m][n][j] + bv);
            }
        }
    }
}

// =================== proj GEMM: bf16 A (row-major) x f32 Bw -> f32 out ======
__global__ __launch_bounds__(256) void proj_mfma(const ushort_t* __restrict__ Ab,
        const float* __restrict__ Bw, const float* __restrict__ bias,
        float* __restrict__ Cout)
{
    __shared__ __align__(16) ushort_t As[128 * 64];
    __shared__ __align__(16) ushort_t Bs[96 * 64];
    const int m0 = blockIdx.x * 128;
    const int n0 = blockIdx.y * 96;
    const int tid = threadIdx.x;
    const int lane = tid & 63;
    const int wrow = (tid >> 6) * 32;
    const int r0 = lane >> 4, cl = lane & 15;
    f32x4 acc[2][6] = {};

    for (int ks = 0; ks < 3; ++ks) {
        const int k0 = ks * 64;
        if (ks) __syncthreads();
        #pragma unroll
        for (int i = 0; i < 2; ++i) {
            int s = tid + i * 256;
            int row = s >> 2, q = s & 3;
            const ushort_t* src = Ab + (size_t)(m0 + row) * 192 + k0 + q * 16;
            uint4 u0 = *(const uint4*)(src);
            uint4 u1 = *(const uint4*)(src + 8);
            int r7 = row & 7;
            *(uint4*)&As[row * 64 + (((q * 2) ^ r7) * 8)] = u0;
            *(uint4*)&As[row * 64 + (((q * 2 + 1) ^ r7) * 8)] = u1;
        }
        #pragma unroll
        for (int i = 0; i < 6; ++i) {
            int f = tid + i * 256;
            int k = f / 24, c4 = (f % 24) * 4;
            float4 v = *(const float4*)(Bw + (size_t)(k0 + k) * 192 + n0 + c4);
            int kw = k >> 3, ke = k & 7;
            Bs[(c4 + 0) * 64 + ((kw ^ ((c4 + 0) & 7)) * 8) + ke] = f2bf(v.x);
            Bs[(c4 + 1) * 64 + ((kw ^ ((c4 + 1) & 7)) * 8) + ke] = f2bf(v.y);
            Bs[(c4 + 2) * 64 + ((kw ^ ((c4 + 2) & 7)) * 8) + ke] = f2bf(v.z);
            Bs[(c4 + 3) * 64 + ((kw ^ ((c4 + 3) & 7)) * 8) + ke] = f2bf(v.w);
        }
        __syncthreads();
        #pragma unroll
        for (int kk = 0; kk < 2; ++kk) {
            int kslot = kk * 4 + r0;
            int ra0 = wrow + cl, ra1 = wrow + 16 + cl;
            short8 a0 = *(const short8*)&As[ra0 * 64 + ((kslot ^ (ra0 & 7)) * 8)];
            short8 a1 = *(const short8*)&As[ra1 * 64 + ((kslot ^ (ra1 & 7)) * 8)];
            #pragma unroll
            for (int n = 0; n < 6; ++n) {
                int col = n * 16 + cl;
                short8 bn = *(const short8*)&Bs[col * 64 + ((kslot ^ (col & 7)) * 8)];
                acc[0][n] = __builtin_amdgcn_mfma_f32_16x16x32_bf16(a0, bn, acc[0][n], 0, 0, 0);
                acc[1][n] = __builtin_amdgcn_mfma_f32_16x16x32_bf16(a1, bn, acc[1][n], 0, 0, 0);
            }
        }
    }
    #pragma unroll
    for (int m = 0; m < 2; ++m) {
        #pragma unroll
        for (int n = 0; n < 6; ++n) {
            int col = n0 + n * 16 + cl;
            float bv = bias[col];
            #pragma unroll
            for (int j = 0; j < 4; ++j) {
                int row = m0 + wrow + m * 16 + r0 * 4 + j;
                Cout[(size_t)row * 192 + col] = acc[m][n][j] + bv;
            }
        }
    }
}

// =================== MFMA window attention ==================================
// wave = one (win, head). S^T tiles via mfma(K_i, Q_j) (16x16x32, layouts
// verified by the working GEMM). Softmax rows are lane-local + 2 shfl_xor.
// PV: O^T += mfma(V^T_frag, P^T_frag); P^T rebuilt in-register via pack+shfl.
template<int BRANCH>
__global__ __launch_bounds__(256) void attn_mfma(const ushort_t* __restrict__ Qk,
                                                 float* __restrict__ fu)
{
    __shared__ float Of[4][16][33];
    const int widx = threadIdx.x >> 6;
    const int idx = blockIdx.x * 4 + widx;          // 0..3071
    const int head = idx >> 10;
    const int b = (idx >> 7) & 7;
    const int win = idx & 127;
    const int L = threadIdx.x & 63;
    const int g = L >> 4, q = L & 15;
    int hb, wb;
    if (BRANCH == 0) { hb = (win >> 3) * 8;  wb = (win & 7) * 16; }
    else             { hb = (win >> 4) * 16; wb = (win & 15) * 8; }
    const int cb = head * 32;

    // token t -> qkv row offset (ushort units)
    #define ROWOFF(t) ((size_t)(b * Ln + (BRANCH == 0 \
        ? (hb + ((t) >> 4)) * Wn + wb + ((t) & 15)   \
        : (hb + ((t) >> 3)) * Wn + wb + ((t) & 7))) * 288)

    // ---- K (A-frags) and Q (B-frags): lane holds row 16i+q, k = 8g+e ----
    short8 kf[8], qf[8];
    #pragma unroll
    for (int i = 0; i < 8; ++i) {
        size_t rb = ROWOFF(16 * i + q);
        qf[i] = *(const short8*)(Qk + rb + cb + 8 * g);
        kf[i] = *(const short8*)(Qk + rb + 96 + cb + 8 * g);
    }
    // ---- V (A2-frags): vf[dblk][s] = V[32s+8g+e][16dblk+q], e=0..7 ----
    short8 vf[2][4];
    {
        size_t vrb[8];
        #pragma unroll
        for (int e = 0; e < 8; ++e)
            vrb[e] = ROWOFF(8 * g + e) + 192 + cb + q;
        const size_t sstep = (size_t)(BRANCH == 0 ? 256 : 512) * 288;
        #pragma unroll
        for (int s = 0; s < 4; ++s) {
            #pragma unroll
            for (int dblk = 0; dblk < 2; ++dblk) {
                uint4v wv;
                #pragma unroll
                for (int e2 = 0; e2 < 4; ++e2) {
                    unsigned lo = Qk[vrb[2 * e2]     + s * sstep + 16 * dblk];
                    unsigned hi = Qk[vrb[2 * e2 + 1] + s * sstep + 16 * dblk];
                    wv[e2] = lo | (hi << 16);
                }
                vf[dblk][s] = *(short8*)&wv;
            }
        }
    }

    const float SC = 0.5303300858899106f;   // 3/sqrt(32)
    const int src0 = q + ((g & 1) << 5);
    const bool thi = (g >> 1) != 0;
    #pragma unroll
    for (int j = 0; j < 8; ++j) {
        unsigned wA[8], wB[8];
        float ss = 0.0f;
        #pragma unroll
        for (int i = 0; i < 8; ++i) {
            f32x4 z = {};
            f32x4 S = __builtin_amdgcn_mfma_f32_16x16x32_bf16(kf[i], qf[j], z, 0, 0, 0);
            float p0 = __expf(S[0] * SC), p1 = __expf(S[1] * SC);
            float p2 = __expf(S[2] * SC), p3 = __expf(S[3] * SC);
            ss += (p0 + p1) + (p2 + p3);
            wA[i] = pk2(p0, p1);
            wB[i] = pk2(p2, p3);
        }
        ss += __shfl_xor(ss, 16);
        ss += __shfl_xor(ss, 32);
        float inv = 3.0f / ss;

        f32x4 O0 = {}, O1 = {};
        #pragma unroll
        for (int s = 0; s < 4; ++s) {
            unsigned a0  = (unsigned)__shfl((int)wA[2*s],     src0);
            unsigned b0  = (unsigned)__shfl((int)wB[2*s],     src0);
            unsigned a0h = (unsigned)__shfl((int)wA[2*s],     src0 + 16);
            unsigned b0h = (unsigned)__shfl((int)wB[2*s],     src0 + 16);
            unsigned a1  = (unsigned)__shfl((int)wA[2*s+1],   src0);
            unsigned b1  = (unsigned)__shfl((int)wB[2*s+1],   src0);
            unsigned a1h = (unsigned)__shfl((int)wA[2*s+1],   src0 + 16);
            unsigned b1h = (unsigned)__shfl((int)wB[2*s+1],   src0 + 16);
            uint4v B2u;
            B2u[0] = thi ? a1  : a0;
            B2u[1] = thi ? b1  : b0;
            B2u[2] = thi ? a1h : a0h;
            B2u[3] = thi ? b1h : b0h;
            short8 B2 = *(short8*)&B2u;
            O0 = __builtin_amdgcn_mfma_f32_16x16x32_bf16(vf[0][s], B2, O0, 0, 0, 0);
            O1 = __builtin_amdgcn_mfma_f32_16x16x32_bf16(vf[1][s], B2, O1, 0, 0, 0);
        }
        // O^T frag: col=q (lane-uniform row q'), row d = 16dblk + 4g + r
        #pragma unroll
        for (int r = 0; r < 4; ++r) {
            Of[widx][q][4 * g + r]      = O0[r] * inv;
            Of[widx][q][16 + 4 * g + r] = O1[r] * inv;
        }
        __syncthreads();
        {
            int rr = L >> 2, c = L & 3;
            int t2 = 16 * j + rr;
            int l;
            if (BRANCH == 0) l = (hb + j) * Wn + wb + rr;
            else             l = (hb + 2 * j + (rr >> 3)) * Wn + wb + (rr & 7);
            (void)t2;
            float* dst = fu + (size_t)(b * Ln + l) * 192 + BRANCH * 96 + cb + c * 8;
            float4 v0 = *(float4*)&Of[widx][rr][c * 8];
            float4 v1 = *(float4*)&Of[widx][rr][c * 8 + 4];
            *(float4*)dst = v0;
            *(float4*)(dst + 4) = v1;
        }
        __syncthreads();
    }
    #undef ROWOFF
}

// ------- conv1: dwconv3x3+BN+GELU per (b,c) plane -> bf16, + pooled mean ----
__global__ __launch_bounds__(256) void conv1_k(const float* __restrict__ x,
        const float* __restrict__ wdw, const float* __restrict__ bdw,
        const float* __restrict__ g1, const float* __restrict__ be1,
        ushort_t* __restrict__ conv1b, float* __restrict__ pooled)
{
    int bc = blockIdx.x;                   // b*192 + c
    int c = bc % 192;
    const float* plane = x + (size_t)bc * Ln;
    ushort_t* oplane = conv1b + (size_t)bc * Ln;
    int t = threadIdx.x;
    int wp = (t & 63) * 2;                 // even pixel pair
    int hr = t >> 6;                       // 0..3
    float wk[9];
    #pragma unroll
    for (int i = 0; i < 9; ++i) wk[i] = wdw[c * 9 + i];
    float gb = g1[c] * BN_RSQ, bb = be1[c], bd = bdw[c];
    float psum = 0.0f;
    for (int hi = 0; hi < 32; ++hi) {
        int h = hi * 4 + hr;
        float a0 = 0.0f, a1 = 0.0f;
        #pragma unroll
        for (int r = 0; r < 3; ++r) {
            int hh = h - 1 + r;
            if (hh < 0 || hh >= Hn) continue;
            const float* rp = plane + hh * Wn;
            float xm = (wp > 0) ? rp[wp - 1] : 0.0f;
            float2 x01 = *(const float2*)(rp + wp);
            float xp = (wp < 126) ? rp[wp + 2] : 0.0f;
            a0 = fmaf(wk[r*3+0], xm, a0);
            a0 = fmaf(wk[r*3+1], x01.x, a0);
            a0 = fmaf(wk[r*3+2], x01.y, a0);
            a1 = fmaf(wk[r*3+0], x01.x, a1);
            a1 = fmaf(wk[r*3+1], x01.y, a1);
            a1 = fmaf(wk[r*3+2], xp, a1);
        }
        float y0 = gelu_f((a0 + bd) * gb + bb);
        float y1 = gelu_f((a1 + bd) * gb + bb);
        psum += y0 + y1;
        *(unsigned int*)(oplane + h * Wn + wp) = pk2(y0, y1);
    }
    __shared__ float red[4];
    for (int off = 32; off; off >>= 1) psum += __shfl_down(psum, off);
    if ((t & 63) == 0) red[t >> 6] = psum;
    __syncthreads();
    if (t == 0)
        pooled[bc] = (red[0] + red[1] + red[2] + red[3]) * (1.0f / Ln);
}

// ------- spatial gate: per-pixel 192->24->1 MLP on bf16 conv1 ---------------
__global__ __launch_bounds__(128) void spatial_gate_k(const ushort_t* __restrict__ conv1b,
        const float* __restrict__ ws1g, const float* __restrict__ bs1,
        const float* __restrict__ gsi, const float* __restrict__ besi,
        const float* __restrict__ ws2, const float* __restrict__ bs2,
        float* __restrict__ gate_s)
{
    int bh = blockIdx.x;                   // b*128 + h
    int b = bh >> 7, h = bh & 127;
    int w = threadIdx.x;
    __shared__ float ws1T[192 * 24];       // [c][o]
    for (int i = w; i < 192 * 24; i += 128) {
        int c = i / 24, o = i - c * 24;
        ws1T[i] = ws1g[o * 192 + c];
    }
    __syncthreads();
    float acc24[24] = {};
    const ushort_t* base = conv1b + (size_t)b * 192 * Ln + h * Wn + w;
    #pragma unroll 4
    for (int c = 0; c < 192; ++c) {
        float v = bf2f(base[(size_t)c * Ln]);
        const float4* wp = (const float4*)&ws1T[c * 24];
        #pragma unroll
        for (int o4 = 0; o4 < 6; ++o4) {
            float4 wv = wp[o4];
            acc24[o4*4+0] = fmaf(v, wv.x, acc24[o4*4+0]);
            acc24[o4*4+1] = fmaf(v, wv.y, acc24[o4*4+1]);
            acc24[o4*4+2] = fmaf(v, wv.z, acc24[o4*4+2]);
            acc24[o4*4+3] = fmaf(v, wv.w, acc24[o4*4+3]);
        }
    }
    float s2 = bs2[0];
    #pragma unroll
    for (int o = 0; o < 24; ++o)
        s2 = fmaf(gelu_f((acc24[o] + bs1[o]) * (gsi[o] * BN_RSQ) + besi[o]), ws2[o], s2);
    gate_s[(size_t)bh * 128 + w] = gate1p(s2);
}

// ---------------- channel gate: 192->24->192 MLP on pooled ------------------
__global__ __launch_bounds__(192) void channel_gate_k(const float* __restrict__ pooled,
        const float* __restrict__ w1, const float* __restrict__ b1,
        const float* __restrict__ g, const float* __restrict__ be,
        const float* __restrict__ w2, const float* __restrict__ b2,
        float* __restrict__ gate_c)
{
    int b = blockIdx.x, t = threadIdx.x;
    __shared__ float pl[192];
    __shared__ float h1[24];
    pl[t] = pooled[b * 192 + t];
    __syncthreads();
    if (t < 24) {
        float a = b1[t];
        for (int c = 0; c < 192; ++c) a = fmaf(pl[c], w1[t * 192 + c], a);
        a = a * (g[t] * BN_RSQ) + be[t];
        h1[t] = gelu_f(a);
    }
    __syncthreads();
    float a = b2[t];
    #pragma unroll
    for (int o = 0; o < 24; ++o) a = fmaf(h1[o], w2[t * 24 + o], a);
    gate_c[b * 192 + t] = gate1p(a);
}

// ---- spatial-gated fu -> dwconv2 -> BN -> GELU -> ch gate, bf16 (B,L,C) out
__global__ __launch_bounds__(256) void dwconv2_k(const float* __restrict__ fu,
        const float* __restrict__ gate_s, const float* __restrict__ gate_c,
        const float* __restrict__ wdw, const float* __restrict__ bdw,
        const float* __restrict__ g2, const float* __restrict__ be2,
        ushort_t* __restrict__ out2b)
{
    int w0 = blockIdx.x * 32;
    int h  = blockIdx.y;
    int b  = blockIdx.z;
    int tid = threadIdx.x;
    __shared__ float ls[3][34][97];
    __shared__ float ybuf[32][97];
    int ww = tid & 31, co = tid >> 5;
    for (int half = 0; half < 2; ++half) {
        if (half) __syncthreads();
        for (int f = tid; f < 3 * 34 * 24; f += 256) {
            int c4 = f % 24;
            int pp = f / 24;
            int wl = pp % 34;
            int r  = pp / 34;
            int hr = h - 1 + r;
            int wp = w0 - 1 + wl;
            float4 v = make_float4(0.f, 0.f, 0.f, 0.f);
            if (hr >= 0 && hr < Hn && wp >= 0 && wp < Wn) {
                int l = hr * Wn + wp;
                v = *(const float4*)(fu + ((size_t)b * Ln + l) * 192 + half * 96 + c4 * 4);
                float gs = gate_s[(size_t)b * Ln + l];
                v.x *= gs; v.y *= gs; v.z *= gs; v.w *= gs;
            }
            float* d = &ls[r][wl][c4 * 4];
            d[0] = v.x; d[1] = v.y; d[2] = v.z; d[3] = v.w;
        }
        __syncthreads();
        #pragma unroll
        for (int j = 0; j < 12; ++j) {
            int cll = co * 12 + j;
            int c = half * 96 + cll;
            const float* wk = wdw + c * 9;
            float s = 0.0f;
            #pragma unroll
            for (int r = 0; r < 3; ++r) {
                s = fmaf(wk[r*3+0], ls[r][ww+0][cll], s);
                s = fmaf(wk[r*3+1], ls[r][ww+1][cll], s);
                s = fmaf(wk[r*3+2], ls[r][ww+2][cll], s);
            }
            float y = gelu_f((s + bdw[c]) * (g2[c] * BN_RSQ) + be2[c]) * gate_c[b * 192 + c];
            ybuf[ww][cll] = y;
        }
        __syncthreads();
        for (int f = tid; f < 32 * 12; f += 256) {
            int px = f / 12, c8 = f % 12;
            int l = h * Wn + w0 + px;
            float* yb = &ybuf[px][c8 * 8];
            uint4 o = make_uint4(pk2(yb[0], yb[1]), pk2(yb[2], yb[3]),
                                 pk2(yb[4], yb[5]), pk2(yb[6], yb[7]));
            *(uint4*)(out2b + ((size_t)b * Ln + l) * 192 + half * 96 + c8 * 8) = o;
        }
    }
}

extern "C" void kernel_launch(void* const* d_in, const int* in_sizes, int n_in,
                              void* d_out, int out_size, void* d_ws, size_t ws_size,
                              hipStream_t stream) {
    (void)in_sizes; (void)n_in; (void)out_size; (void)ws_size;
    const float* x      = (const float*)d_in[0];
    const float* w_qkv  = (const float*)d_in[1];
    const float* b_qkv  = (const float*)d_in[2];
    const float* w_dw1  = (const float*)d_in[3];
    const float* b_dw1  = (const float*)d_in[4];
    const float* g_bn1  = (const float*)d_in[5];
    const float* be_bn1 = (const float*)d_in[6];
    const float* w_si1  = (const float*)d_in[7];
    const float* b_si1  = (const float*)d_in[8];
    const float* g_si   = (const float*)d_in[9];
    const float* be_si  = (const float*)d_in[10];
    const float* w_si2  = (const float*)d_in[11];
    const float* b_si2  = (const float*)d_in[12];
    const float* w_ci1  = (const float*)d_in[13];
    const float* b_ci1  = (const float*)d_in[14];
    const float* g_ci   = (const float*)d_in[15];
    const float* be_ci  = (const float*)d_in[16];
    const float* w_ci2  = (const float*)d_in[17];
    const float* b_ci2  = (const float*)d_in[18];
    const float* w_dw2  = (const float*)d_in[19];
    const float* b_dw2  = (const float*)d_in[20];
    const float* g_bn2  = (const float*)d_in[21];
    const float* be_bn2 = (const float*)d_in[22];
    const float* w_proj = (const float*)d_in[23];
    const float* b_proj = (const float*)d_in[24];

    float* ws = (float*)d_ws;
    ushort_t* qkvb   = (ushort_t*)ws;
    ushort_t* conv1b = (ushort_t*)ws;
    ushort_t* out2b  = (ushort_t*)(ws + 8000000);
    float* gate_s    = ws + FUn;                       // B*L
    float* gate_c    = gate_s + (size_t)Bn * Ln;       // B*192
    float* pooled    = gate_c + Bn * 192;              // B*192
    float* fu = (float*)d_out;

    qkv_mfma<0><<<dim3(Mn / 128, 3), 256, 0, stream>>>(x, w_qkv, b_qkv, qkvb);
    attn_mfma<0><<<768, 256, 0, stream>>>(qkvb, fu);
    qkv_mfma<1><<<dim3(Mn / 128, 3), 256, 0, stream>>>(x, w_qkv, b_qkv, qkvb);
    attn_mfma<1><<<768, 256, 0, stream>>>(qkvb, fu);
    conv1_k<<<Bn * 192, 256, 0, stream>>>(x, w_dw1, b_dw1, g_bn1, be_bn1, conv1b, pooled);
    spatial_gate_k<<<Bn * Hn, 128, 0, stream>>>(conv1b, w_si1, b_si1, g_si, be_si,
                                                w_si2, b_si2, gate_s);
    channel_gate_k<<<Bn, 192, 0, stream>>>(pooled, w_ci1, b_ci1, g_ci, be_ci,
                                           w_ci2, b_ci2, gate_c);
    dwconv2_k<<<dim3(4, Hn, Bn), 256, 0, stream>>>(fu, gate_s, gate_c,
                                                   w_dw2, b_dw2, g_bn2, be_bn2, out2b);
    proj_mfma<<<dim3(Mn / 128, 2), 256, 0, stream>>>(out2b, w_proj, b_proj, (float*)d_out);
}

// Round 6
// 614.998 us; speedup vs baseline: 2.1739x; 1.0044x over previous
//
#include <hip/hip_runtime.h>

#define Bn 8
#define Hn 128
#define Wn 128
#define Cn 192
#define Ln (Hn*Wn)          // 16384
#define Mn (Bn*Ln)          // 131072
#define FUn ((size_t)Mn*Cn) // 25,165,824 floats
#define BN_RSQ 0.9999950000374997f   // 1/sqrt(1+1e-5)

typedef unsigned short ushort_t;
typedef __attribute__((ext_vector_type(8))) short short8;
typedef __attribute__((ext_vector_type(4))) float f32x4;
typedef __attribute__((ext_vector_type(4))) unsigned int uint4v;

static __device__ __forceinline__ float gelu_f(float x) {
    return 0.5f * x * (1.0f + erff(x * 0.7071067811865475f));
}
static __device__ __forceinline__ float gate1p(float x) {  // 1 + sigmoid(x)
    return 1.0f + 1.0f / (1.0f + __expf(-x));
}
static __device__ __forceinline__ unsigned short f2bf(float f) {  // RNE
    unsigned u = __float_as_uint(f);
    return (unsigned short)((u + 0x7FFFu + ((u >> 16) & 1u)) >> 16);
}
static __device__ __forceinline__ unsigned int pk2(float lo, float hi) {
    return (unsigned int)f2bf(lo) | ((unsigned int)f2bf(hi) << 16);
}
static __device__ __forceinline__ float bf2f(ushort_t u) {
    return __uint_as_float((unsigned)u << 16);
}

// =================== qkv GEMM, bf16 MFMA 16x16x32 ===========================
template<int BRANCH>
__global__ __launch_bounds__(256) void qkv_mfma(const float* __restrict__ A,
        const float* __restrict__ Bw, const float* __restrict__ bias,
        ushort_t* __restrict__ Q)
{
    __shared__ __align__(16) ushort_t As[128 * 64];
    __shared__ __align__(16) ushort_t Bs[96 * 64];
    const int m0 = blockIdx.x * 128;
    const int part = blockIdx.y;                      // 0..2
    const int bcol = part * 192 + BRANCH * 96;
    const int tid = threadIdx.x;
    const int lane = tid & 63;
    const int wrow = (tid >> 6) * 32;
    const int r0 = lane >> 4, cl = lane & 15;
    f32x4 acc[2][6] = {};

    for (int ks = 0; ks < 3; ++ks) {
        const int k0 = ks * 64;
        if (ks) __syncthreads();
        #pragma unroll
        for (int i = 0; i < 2; ++i) {
            int s = tid + i * 256;
            int row = s >> 2, q = s & 3;
            const float* src = A + (size_t)(m0 + row) * 192 + k0 + q * 16;
            float4 v0 = *(const float4*)(src);
            float4 v1 = *(const float4*)(src + 4);
            float4 v2 = *(const float4*)(src + 8);
            float4 v3 = *(const float4*)(src + 12);
            uint4 w0 = make_uint4(pk2(v0.x, v0.y), pk2(v0.z, v0.w),
                                  pk2(v1.x, v1.y), pk2(v1.z, v1.w));
            uint4 w1 = make_uint4(pk2(v2.x, v2.y), pk2(v2.z, v2.w),
                                  pk2(v3.x, v3.y), pk2(v3.z, v3.w));
            int r7 = row & 7;
            *(uint4*)&As[row * 64 + (((q * 2) ^ r7) * 8)] = w0;
            *(uint4*)&As[row * 64 + (((q * 2 + 1) ^ r7) * 8)] = w1;
        }
        #pragma unroll
        for (int i = 0; i < 6; ++i) {
            int f = tid + i * 256;
            int k = f / 24, c4 = (f % 24) * 4;
            float4 v = *(const float4*)(Bw + (size_t)(k0 + k) * 576 + bcol + c4);
            int kw = k >> 3, ke = k & 7;
            Bs[(c4 + 0) * 64 + ((kw ^ ((c4 + 0) & 7)) * 8) + ke] = f2bf(v.x);
            Bs[(c4 + 1) * 64 + ((kw ^ ((c4 + 1) & 7)) * 8) + ke] = f2bf(v.y);
            Bs[(c4 + 2) * 64 + ((kw ^ ((c4 + 2) & 7)) * 8) + ke] = f2bf(v.z);
            Bs[(c4 + 3) * 64 + ((kw ^ ((c4 + 3) & 7)) * 8) + ke] = f2bf(v.w);
        }
        __syncthreads();
        #pragma unroll
        for (int kk = 0; kk < 2; ++kk) {
            int kslot = kk * 4 + r0;
            int ra0 = wrow + cl, ra1 = wrow + 16 + cl;
            short8 a0 = *(const short8*)&As[ra0 * 64 + ((kslot ^ (ra0 & 7)) * 8)];
            short8 a1 = *(const short8*)&As[ra1 * 64 + ((kslot ^ (ra1 & 7)) * 8)];
            #pragma unroll
            for (int n = 0; n < 6; ++n) {
                int col = n * 16 + cl;
                short8 bn = *(const short8*)&Bs[col * 64 + ((kslot ^ (col & 7)) * 8)];
                acc[0][n] = __builtin_amdgcn_mfma_f32_16x16x32_bf16(a0, bn, acc[0][n], 0, 0, 0);
                acc[1][n] = __builtin_amdgcn_mfma_f32_16x16x32_bf16(a1, bn, acc[1][n], 0, 0, 0);
            }
        }
    }
    #pragma unroll
    for (int m = 0; m < 2; ++m) {
        #pragma unroll
        for (int n = 0; n < 6; ++n) {
            int col = n * 16 + cl;
            float bv = bias[bcol + col];
            #pragma unroll
            for (int j = 0; j < 4; ++j) {
                int row = m0 + wrow + m * 16 + r0 * 4 + j;
                Q[(size_t)row * 288 + part * 96 + col] = f2bf(acc[m][n][j] + bv);
            }
        }
    }
}

// =================== proj GEMM: bf16 A (row-major) x f32 Bw -> f32 out ======
__global__ __launch_bounds__(256) void proj_mfma(const ushort_t* __restrict__ Ab,
        const float* __restrict__ Bw, const float* __restrict__ bias,
        float* __restrict__ Cout)
{
    __shared__ __align__(16) ushort_t As[128 * 64];
    __shared__ __align__(16) ushort_t Bs[96 * 64];
    const int m0 = blockIdx.x * 128;
    const int n0 = blockIdx.y * 96;
    const int tid = threadIdx.x;
    const int lane = tid & 63;
    const int wrow = (tid >> 6) * 32;
    const int r0 = lane >> 4, cl = lane & 15;
    f32x4 acc[2][6] = {};

    for (int ks = 0; ks < 3; ++ks) {
        const int k0 = ks * 64;
        if (ks) __syncthreads();
        #pragma unroll
        for (int i = 0; i < 2; ++i) {
            int s = tid + i * 256;
            int row = s >> 2, q = s & 3;
            const ushort_t* src = Ab + (size_t)(m0 + row) * 192 + k0 + q * 16;
            uint4 u0 = *(const uint4*)(src);
            uint4 u1 = *(const uint4*)(src + 8);
            int r7 = row & 7;
            *(uint4*)&As[row * 64 + (((q * 2) ^ r7) * 8)] = u0;
            *(uint4*)&As[row * 64 + (((q * 2 + 1) ^ r7) * 8)] = u1;
        }
        #pragma unroll
        for (int i = 0; i < 6; ++i) {
            int f = tid + i * 256;
            int k = f / 24, c4 = (f % 24) * 4;
            float4 v = *(const float4*)(Bw + (size_t)(k0 + k) * 192 + n0 + c4);
            int kw = k >> 3, ke = k & 7;
            Bs[(c4 + 0) * 64 + ((kw ^ ((c4 + 0) & 7)) * 8) + ke] = f2bf(v.x);
            Bs[(c4 + 1) * 64 + ((kw ^ ((c4 + 1) & 7)) * 8) + ke] = f2bf(v.y);
            Bs[(c4 + 2) * 64 + ((kw ^ ((c4 + 2) & 7)) * 8) + ke] = f2bf(v.z);
            Bs[(c4 + 3) * 64 + ((kw ^ ((c4 + 3) & 7)) * 8) + ke] = f2bf(v.w);
        }
        __syncthreads();
        #pragma unroll
        for (int kk = 0; kk < 2; ++kk) {
            int kslot = kk * 4 + r0;
            int ra0 = wrow + cl, ra1 = wrow + 16 + cl;
            short8 a0 = *(const short8*)&As[ra0 * 64 + ((kslot ^ (ra0 & 7)) * 8)];
            short8 a1 = *(const short8*)&As[ra1 * 64 + ((kslot ^ (ra1 & 7)) * 8)];
            #pragma unroll
            for (int n = 0; n < 6; ++n) {
                int col = n * 16 + cl;
                short8 bn = *(const short8*)&Bs[col * 64 + ((kslot ^ (col & 7)) * 8)];
                acc[0][n] = __builtin_amdgcn_mfma_f32_16x16x32_bf16(a0, bn, acc[0][n], 0, 0, 0);
                acc[1][n] = __builtin_amdgcn_mfma_f32_16x16x32_bf16(a1, bn, acc[1][n], 0, 0, 0);
            }
        }
    }
    #pragma unroll
    for (int m = 0; m < 2; ++m) {
        #pragma unroll
        for (int n = 0; n < 6; ++n) {
            int col = n0 + n * 16 + cl;
            float bv = bias[col];
            #pragma unroll
            for (int j = 0; j < 4; ++j) {
                int row = m0 + wrow + m * 16 + r0 * 4 + j;
                Cout[(size_t)row * 192 + col] = acc[m][n][j] + bv;
            }
        }
    }
}

// =================== MFMA window attention ==================================
// wave = one (win, head). Epilogue applies spatial gate and writes bf16 fu.
template<int BRANCH>
__global__ __launch_bounds__(256) void attn_mfma(const ushort_t* __restrict__ Qk,
                                                 const float* __restrict__ gate_s,
                                                 ushort_t* __restrict__ fu_b)
{
    __shared__ float Of[4][16][33];
    const int widx = threadIdx.x >> 6;
    const int idx = blockIdx.x * 4 + widx;          // 0..3071
    const int head = idx >> 10;
    const int b = (idx >> 7) & 7;
    const int win = idx & 127;
    const int L = threadIdx.x & 63;
    const int g = L >> 4, q = L & 15;
    int hb, wb;
    if (BRANCH == 0) { hb = (win >> 3) * 8;  wb = (win & 7) * 16; }
    else             { hb = (win >> 4) * 16; wb = (win & 15) * 8; }
    const int cb = head * 32;

    #define ROWOFF(t) ((size_t)(b * Ln + (BRANCH == 0 \
        ? (hb + ((t) >> 4)) * Wn + wb + ((t) & 15)   \
        : (hb + ((t) >> 3)) * Wn + wb + ((t) & 7))) * 288)

    short8 kf[8], qf[8];
    #pragma unroll
    for (int i = 0; i < 8; ++i) {
        size_t rb = ROWOFF(16 * i + q);
        qf[i] = *(const short8*)(Qk + rb + cb + 8 * g);
        kf[i] = *(const short8*)(Qk + rb + 96 + cb + 8 * g);
    }
    short8 vf[2][4];
    {
        size_t vrb[8];
        #pragma unroll
        for (int e = 0; e < 8; ++e)
            vrb[e] = ROWOFF(8 * g + e) + 192 + cb + q;
        const size_t sstep = (size_t)(BRANCH == 0 ? 256 : 512) * 288;
        #pragma unroll
        for (int s = 0; s < 4; ++s) {
            #pragma unroll
            for (int dblk = 0; dblk < 2; ++dblk) {
                uint4v wv;
                #pragma unroll
                for (int e2 = 0; e2 < 4; ++e2) {
                    unsigned lo = Qk[vrb[2 * e2]     + s * sstep + 16 * dblk];
                    unsigned hi = Qk[vrb[2 * e2 + 1] + s * sstep + 16 * dblk];
                    wv[e2] = lo | (hi << 16);
                }
                vf[dblk][s] = *(short8*)&wv;
            }
        }
    }

    const float SC = 0.5303300858899106f;   // 3/sqrt(32)
    const int src0 = q + ((g & 1) << 5);
    const bool thi = (g >> 1) != 0;
    #pragma unroll
    for (int j = 0; j < 8; ++j) {
        unsigned wA[8], wB[8];
        float ss = 0.0f;
        #pragma unroll
        for (int i = 0; i < 8; ++i) {
            f32x4 z = {};
            f32x4 S = __builtin_amdgcn_mfma_f32_16x16x32_bf16(kf[i], qf[j], z, 0, 0, 0);
            float p0 = __expf(S[0] * SC), p1 = __expf(S[1] * SC);
            float p2 = __expf(S[2] * SC), p3 = __expf(S[3] * SC);
            ss += (p0 + p1) + (p2 + p3);
            wA[i] = pk2(p0, p1);
            wB[i] = pk2(p2, p3);
        }
        ss += __shfl_xor(ss, 16);
        ss += __shfl_xor(ss, 32);
        float inv = 3.0f / ss;

        f32x4 O0 = {}, O1 = {};
        #pragma unroll
        for (int s = 0; s < 4; ++s) {
            unsigned a0  = (unsigned)__shfl((int)wA[2*s],     src0);
            unsigned b0  = (unsigned)__shfl((int)wB[2*s],     src0);
            unsigned a0h = (unsigned)__shfl((int)wA[2*s],     src0 + 16);
            unsigned b0h = (unsigned)__shfl((int)wB[2*s],     src0 + 16);
            unsigned a1  = (unsigned)__shfl((int)wA[2*s+1],   src0);
            unsigned b1  = (unsigned)__shfl((int)wB[2*s+1],   src0);
            unsigned a1h = (unsigned)__shfl((int)wA[2*s+1],   src0 + 16);
            unsigned b1h = (unsigned)__shfl((int)wB[2*s+1],   src0 + 16);
            uint4v B2u;
            B2u[0] = thi ? a1  : a0;
            B2u[1] = thi ? b1  : b0;
            B2u[2] = thi ? a1h : a0h;
            B2u[3] = thi ? b1h : b0h;
            short8 B2 = *(short8*)&B2u;
            O0 = __builtin_amdgcn_mfma_f32_16x16x32_bf16(vf[0][s], B2, O0, 0, 0, 0);
            O1 = __builtin_amdgcn_mfma_f32_16x16x32_bf16(vf[1][s], B2, O1, 0, 0, 0);
        }
        #pragma unroll
        for (int r = 0; r < 4; ++r) {
            Of[widx][q][4 * g + r]      = O0[r] * inv;
            Of[widx][q][16 + 4 * g + r] = O1[r] * inv;
        }
        __syncthreads();
        {
            int rr = L >> 2, c = L & 3;
            int l;
            if (BRANCH == 0) l = (hb + j) * Wn + wb + rr;
            else             l = (hb + 2 * j + (rr >> 3)) * Wn + wb + (rr & 7);
            float gs = gate_s[(size_t)b * Ln + l];
            float* src = &Of[widx][rr][c * 8];
            uint4 o = make_uint4(pk2(src[0] * gs, src[1] * gs),
                                 pk2(src[2] * gs, src[3] * gs),
                                 pk2(src[4] * gs, src[5] * gs),
                                 pk2(src[6] * gs, src[7] * gs));
            *(uint4*)(fu_b + (size_t)(b * Ln + l) * 192 + BRANCH * 96 + cb + c * 8) = o;
        }
        __syncthreads();
    }
    #undef ROWOFF
}

// ------- conv1: dwconv3x3+BN+GELU per (b,c) plane -> bf16, + pooled mean ----
__global__ __launch_bounds__(256) void conv1_k(const float* __restrict__ x,
        const float* __restrict__ wdw, const float* __restrict__ bdw,
        const float* __restrict__ g1, const float* __restrict__ be1,
        ushort_t* __restrict__ conv1b, float* __restrict__ pooled)
{
    int bc = blockIdx.x;                   // b*192 + c
    int c = bc % 192;
    const float* plane = x + (size_t)bc * Ln;
    ushort_t* oplane = conv1b + (size_t)bc * Ln;
    int t = threadIdx.x;
    int wp = (t & 63) * 2;                 // even pixel pair
    int hr = t >> 6;                       // 0..3
    float wk[9];
    #pragma unroll
    for (int i = 0; i < 9; ++i) wk[i] = wdw[c * 9 + i];
    float gb = g1[c] * BN_RSQ, bb = be1[c], bd = bdw[c];
    float psum = 0.0f;
    for (int hi = 0; hi < 32; ++hi) {
        int h = hi * 4 + hr;
        float a0 = 0.0f, a1 = 0.0f;
        #pragma unroll
        for (int r = 0; r < 3; ++r) {
            int hh = h - 1 + r;
            if (hh < 0 || hh >= Hn) continue;
            const float* rp = plane + hh * Wn;
            float xm = (wp > 0) ? rp[wp - 1] : 0.0f;
            float2 x01 = *(const float2*)(rp + wp);
            float xp = (wp < 126) ? rp[wp + 2] : 0.0f;
            a0 = fmaf(wk[r*3+0], xm, a0);
            a0 = fmaf(wk[r*3+1], x01.x, a0);
            a0 = fmaf(wk[r*3+2], x01.y, a0);
            a1 = fmaf(wk[r*3+0], x01.x, a1);
            a1 = fmaf(wk[r*3+1], x01.y, a1);
            a1 = fmaf(wk[r*3+2], xp, a1);
        }
        float y0 = gelu_f((a0 + bd) * gb + bb);
        float y1 = gelu_f((a1 + bd) * gb + bb);
        psum += y0 + y1;
        *(unsigned int*)(oplane + h * Wn + wp) = pk2(y0, y1);
    }
    __shared__ float red[4];
    for (int off = 32; off; off >>= 1) psum += __shfl_down(psum, off);
    if ((t & 63) == 0) red[t >> 6] = psum;
    __syncthreads();
    if (t == 0)
        pooled[bc] = (red[0] + red[1] + red[2] + red[3]) * (1.0f / Ln);
}

// ------- spatial gate: per-pixel 192->24->1 MLP on bf16 conv1 ---------------
__global__ __launch_bounds__(128) void spatial_gate_k(const ushort_t* __restrict__ conv1b,
        const float* __restrict__ ws1g, const float* __restrict__ bs1,
        const float* __restrict__ gsi, const float* __restrict__ besi,
        const float* __restrict__ ws2, const float* __restrict__ bs2,
        float* __restrict__ gate_s)
{
    int bh = blockIdx.x;                   // b*128 + h
    int b = bh >> 7, h = bh & 127;
    int w = threadIdx.x;
    __shared__ float ws1T[192 * 24];       // [c][o]
    for (int i = w; i < 192 * 24; i += 128) {
        int c = i / 24, o = i - c * 24;
        ws1T[i] = ws1g[o * 192 + c];
    }
    __syncthreads();
    float acc24[24] = {};
    const ushort_t* base = conv1b + (size_t)b * 192 * Ln + h * Wn + w;
    #pragma unroll 4
    for (int c = 0; c < 192; ++c) {
        float v = bf2f(base[(size_t)c * Ln]);
        const float4* wp = (const float4*)&ws1T[c * 24];
        #pragma unroll
        for (int o4 = 0; o4 < 6; ++o4) {
            float4 wv = wp[o4];
            acc24[o4*4+0] = fmaf(v, wv.x, acc24[o4*4+0]);
            acc24[o4*4+1] = fmaf(v, wv.y, acc24[o4*4+1]);
            acc24[o4*4+2] = fmaf(v, wv.z, acc24[o4*4+2]);
            acc24[o4*4+3] = fmaf(v, wv.w, acc24[o4*4+3]);
        }
    }
    float s2 = bs2[0];
    #pragma unroll
    for (int o = 0; o < 24; ++o)
        s2 = fmaf(gelu_f((acc24[o] + bs1[o]) * (gsi[o] * BN_RSQ) + besi[o]), ws2[o], s2);
    gate_s[(size_t)bh * 128 + w] = gate1p(s2);
}

// ---------------- channel gate: 192->24->192 MLP on pooled ------------------
__global__ __launch_bounds__(192) void channel_gate_k(const float* __restrict__ pooled,
        const float* __restrict__ w1, const float* __restrict__ b1,
        const float* __restrict__ g, const float* __restrict__ be,
        const float* __restrict__ w2, const float* __restrict__ b2,
        float* __restrict__ gate_c)
{
    int b = blockIdx.x, t = threadIdx.x;
    __shared__ float pl[192];
    __shared__ float h1[24];
    pl[t] = pooled[b * 192 + t];
    __syncthreads();
    if (t < 24) {
        float a = b1[t];
        for (int c = 0; c < 192; ++c) a = fmaf(pl[c], w1[t * 192 + c], a);
        a = a * (g[t] * BN_RSQ) + be[t];
        h1[t] = gelu_f(a);
    }
    __syncthreads();
    float a = b2[t];
    #pragma unroll
    for (int o = 0; o < 24; ++o) a = fmaf(h1[o], w2[t * 24 + o], a);
    gate_c[b * 192 + t] = gate1p(a);
}

// ---- dwconv2: channels-last register 3x3 stencil on gated bf16 fu ----------
// thread item = (pixel w, 8-channel group); 9 uint4 coalesced loads; no halo LDS.
__global__ __launch_bounds__(256) void dwconv2_k(const ushort_t* __restrict__ fu_b,
        const float* __restrict__ gate_c,
        const float* __restrict__ wdw, const float* __restrict__ bdw,
        const float* __restrict__ g2, const float* __restrict__ be2,
        ushort_t* __restrict__ out2b)
{
    int bh = blockIdx.x >> 1;              // b*128 + h
    int whalf = blockIdx.x & 1;
    int b = bh >> 7, h = bh & 127;
    int tid = threadIdx.x;
    __shared__ float cw[192 * 9];
    __shared__ float cbd[192], cgb[192], cbe[192], cgc[192];
    for (int i = tid; i < 192 * 9; i += 256) cw[i] = wdw[i];
    for (int i = tid; i < 192; i += 256) {
        cbd[i] = bdw[i];
        cgb[i] = g2[i] * BN_RSQ;
        cbe[i] = be2[i];
        cgc[i] = gate_c[b * 192 + i];
    }
    __syncthreads();
    const size_t outrow = (size_t)(b * Ln + h * Wn) * 192;
    for (int it = 0; it < 6; ++it) {
        int item = it * 256 + tid;          // 0..1535
        int w = whalf * 64 + item / 24;
        int c8 = item % 24;
        int co = c8 * 8;
        uint4 nb[3][3];
        #pragma unroll
        for (int r = 0; r < 3; ++r)
            #pragma unroll
            for (int d = 0; d < 3; ++d)
                nb[r][d] = make_uint4(0u, 0u, 0u, 0u);
        #pragma unroll
        for (int r = 0; r < 3; ++r) {
            int hh = h - 1 + r;
            if (hh < 0 || hh >= Hn) continue;
            const ushort_t* rp = fu_b + (size_t)(b * Ln + hh * Wn) * 192 + co;
            #pragma unroll
            for (int d = 0; d < 3; ++d) {
                int w2 = w - 1 + d;
                if (w2 < 0 || w2 >= Wn) continue;
                nb[r][d] = *(const uint4*)(rp + (size_t)w2 * 192);
            }
        }
        unsigned ou[4];
        #pragma unroll
        for (int i = 0; i < 8; ++i) {
            int c = co + i;
            float s = 0.0f;
            #pragma unroll
            for (int r = 0; r < 3; ++r) {
                #pragma unroll
                for (int d = 0; d < 3; ++d) {
                    unsigned word = ((const unsigned*)&nb[r][d])[i >> 1];
                    float v = __uint_as_float((i & 1) ? (word & 0xffff0000u)
                                                      : (word << 16));
                    s = fmaf(cw[c * 9 + r * 3 + d], v, s);
                }
            }
            float y = gelu_f((s + cbd[c]) * cgb[c] + cbe[c]) * cgc[c];
            if (i & 1) ou[i >> 1] |= (unsigned)f2bf(y) << 16;
            else       ou[i >> 1] = (unsigned)f2bf(y);
        }
        *(uint4*)(out2b + outrow + (size_t)w * 192 + co) =
            make_uint4(ou[0], ou[1], ou[2], ou[3]);
    }
}

extern "C" void kernel_launch(void* const* d_in, const int* in_sizes, int n_in,
                              void* d_out, int out_size, void* d_ws, size_t ws_size,
                              hipStream_t stream) {
    (void)in_sizes; (void)n_in; (void)out_size; (void)ws_size;
    const float* x      = (const float*)d_in[0];
    const float* w_qkv  = (const float*)d_in[1];
    const float* b_qkv  = (const float*)d_in[2];
    const float* w_dw1  = (const float*)d_in[3];
    const float* b_dw1  = (const float*)d_in[4];
    const float* g_bn1  = (const float*)d_in[5];
    const float* be_bn1 = (const float*)d_in[6];
    const float* w_si1  = (const float*)d_in[7];
    const float* b_si1  = (const float*)d_in[8];
    const float* g_si   = (const float*)d_in[9];
    const float* be_si  = (const float*)d_in[10];
    const float* w_si2  = (const float*)d_in[11];
    const float* b_si2  = (const float*)d_in[12];
    const float* w_ci1  = (const float*)d_in[13];
    const float* b_ci1  = (const float*)d_in[14];
    const float* g_ci   = (const float*)d_in[15];
    const float* be_ci  = (const float*)d_in[16];
    const float* w_ci2  = (const float*)d_in[17];
    const float* b_ci2  = (const float*)d_in[18];
    const float* w_dw2  = (const float*)d_in[19];
    const float* b_dw2  = (const float*)d_in[20];
    const float* g_bn2  = (const float*)d_in[21];
    const float* be_bn2 = (const float*)d_in[22];
    const float* w_proj = (const float*)d_in[23];
    const float* b_proj = (const float*)d_in[24];

    // ws (f32 units):
    //   phase 1: conv1b bf16 [0, 12.58M f32)      [conv1 -> spatial_gate]
    //   phase 2: qkvb bf16 [0, 18.87M f32)        [qkv -> attn]
    //   phase 3: out2b bf16 at 8M..20.58M         [dwconv2 -> proj]
    //   smalls above FUn: gate_s, gate_c, pooled
    float* ws = (float*)d_ws;
    ushort_t* conv1b = (ushort_t*)ws;
    ushort_t* qkvb   = (ushort_t*)ws;
    ushort_t* out2b  = (ushort_t*)(ws + 8000000);
    float* gate_s    = ws + FUn;                       // B*L
    float* gate_c    = gate_s + (size_t)Bn * Ln;       // B*192
    float* pooled    = gate_c + Bn * 192;              // B*192
    ushort_t* fu_b   = (ushort_t*)d_out;               // gated bf16 fu (50MB)

    conv1_k<<<Bn * 192, 256, 0, stream>>>(x, w_dw1, b_dw1, g_bn1, be_bn1, conv1b, pooled);
    spatial_gate_k<<<Bn * Hn, 128, 0, stream>>>(conv1b, w_si1, b_si1, g_si, be_si,
                                                w_si2, b_si2, gate_s);
    channel_gate_k<<<Bn, 192, 0, stream>>>(pooled, w_ci1, b_ci1, g_ci, be_ci,
                                           w_ci2, b_ci2, gate_c);
    qkv_mfma<0><<<dim3(Mn / 128, 3), 256, 0, stream>>>(x, w_qkv, b_qkv, qkvb);
    attn_mfma<0><<<768, 256, 0, stream>>>(qkvb, gate_s, fu_b);
    qkv_mfma<1><<<dim3(Mn / 128, 3), 256, 0, stream>>>(x, w_qkv, b_qkv, qkvb);
    attn_mfma<1><<<768, 256, 0, stream>>>(qkvb, gate_s, fu_b);
    dwconv2_k<<<Bn * Hn * 2, 256, 0, stream>>>(fu_b, gate_c,
                                               w_dw2, b_dw2, g_bn2, be_bn2, out2b);
    proj_mfma<<<dim3(Mn / 128, 2), 256, 0, stream>>>(out2b, w_proj, b_proj, (float*)d_out);
}

// Round 7
// 524.039 us; speedup vs baseline: 2.5513x; 1.1736x over previous
//
#include <hip/hip_runtime.h>

#define Bn 8
#define Hn 128
#define Wn 128
#define Cn 192
#define Ln (Hn*Wn)          // 16384
#define Mn (Bn*Ln)          // 131072
#define FUn ((size_t)Mn*Cn) // 25,165,824 floats
#define BN_RSQ 0.9999950000374997f   // 1/sqrt(1+1e-5)

typedef unsigned short ushort_t;
typedef __attribute__((ext_vector_type(8))) short short8;
typedef __attribute__((ext_vector_type(4))) float f32x4;
typedef __attribute__((ext_vector_type(4))) unsigned int uint4v;

static __device__ __forceinline__ float gelu_f(float x) {
    return 0.5f * x * (1.0f + erff(x * 0.7071067811865475f));
}
static __device__ __forceinline__ float gate1p(float x) {  // 1 + sigmoid(x)
    return 1.0f + 1.0f / (1.0f + __expf(-x));
}
static __device__ __forceinline__ unsigned short f2bf(float f) {  // RNE
    unsigned u = __float_as_uint(f);
    return (unsigned short)((u + 0x7FFFu + ((u >> 16) & 1u)) >> 16);
}
static __device__ __forceinline__ unsigned int pk2(float lo, float hi) {
    return (unsigned int)f2bf(lo) | ((unsigned int)f2bf(hi) << 16);
}
static __device__ __forceinline__ float bf2f(ushort_t u) {
    return __uint_as_float((unsigned)u << 16);
}

// ========== qkv GEMM (all 576 cols), bf16 MFMA; writes Q/K/V parts =========
__global__ __launch_bounds__(256) void qkv_mfma(const float* __restrict__ A,
        const float* __restrict__ Bw, const float* __restrict__ bias,
        ushort_t* __restrict__ Qp, ushort_t* __restrict__ Kp,
        ushort_t* __restrict__ Vp)
{
    __shared__ __align__(16) ushort_t As[128 * 64];
    __shared__ __align__(16) ushort_t Bs[96 * 64];
    const int m0 = blockIdx.x * 128;
    const int n0g = blockIdx.y * 96;                  // 0..480
    const int part = n0g / 192;
    const int coln = n0g - part * 192;
    ushort_t* dst = part == 0 ? Qp : (part == 1 ? Kp : Vp);
    const int tid = threadIdx.x;
    const int lane = tid & 63;
    const int wrow = (tid >> 6) * 32;
    const int r0 = lane >> 4, cl = lane & 15;
    f32x4 acc[2][6] = {};

    for (int ks = 0; ks < 3; ++ks) {
        const int k0 = ks * 64;
        if (ks) __syncthreads();
        #pragma unroll
        for (int i = 0; i < 2; ++i) {
            int s = tid + i * 256;
            int row = s >> 2, q = s & 3;
            const float* src = A + (size_t)(m0 + row) * 192 + k0 + q * 16;
            float4 v0 = *(const float4*)(src);
            float4 v1 = *(const float4*)(src + 4);
            float4 v2 = *(const float4*)(src + 8);
            float4 v3 = *(const float4*)(src + 12);
            uint4 w0 = make_uint4(pk2(v0.x, v0.y), pk2(v0.z, v0.w),
                                  pk2(v1.x, v1.y), pk2(v1.z, v1.w));
            uint4 w1 = make_uint4(pk2(v2.x, v2.y), pk2(v2.z, v2.w),
                                  pk2(v3.x, v3.y), pk2(v3.z, v3.w));
            int r7 = row & 7;
            *(uint4*)&As[row * 64 + (((q * 2) ^ r7) * 8)] = w0;
            *(uint4*)&As[row * 64 + (((q * 2 + 1) ^ r7) * 8)] = w1;
        }
        #pragma unroll
        for (int i = 0; i < 6; ++i) {
            int f = tid + i * 256;
            int k = f / 24, c4 = (f % 24) * 4;
            float4 v = *(const float4*)(Bw + (size_t)(k0 + k) * 576 + n0g + c4);
            int kw = k >> 3, ke = k & 7;
            Bs[(c4 + 0) * 64 + ((kw ^ ((c4 + 0) & 7)) * 8) + ke] = f2bf(v.x);
            Bs[(c4 + 1) * 64 + ((kw ^ ((c4 + 1) & 7)) * 8) + ke] = f2bf(v.y);
            Bs[(c4 + 2) * 64 + ((kw ^ ((c4 + 2) & 7)) * 8) + ke] = f2bf(v.z);
            Bs[(c4 + 3) * 64 + ((kw ^ ((c4 + 3) & 7)) * 8) + ke] = f2bf(v.w);
        }
        __syncthreads();
        #pragma unroll
        for (int kk = 0; kk < 2; ++kk) {
            int kslot = kk * 4 + r0;
            int ra0 = wrow + cl, ra1 = wrow + 16 + cl;
            short8 a0 = *(const short8*)&As[ra0 * 64 + ((kslot ^ (ra0 & 7)) * 8)];
            short8 a1 = *(const short8*)&As[ra1 * 64 + ((kslot ^ (ra1 & 7)) * 8)];
            #pragma unroll
            for (int n = 0; n < 6; ++n) {
                int col = n * 16 + cl;
                short8 bn = *(const short8*)&Bs[col * 64 + ((kslot ^ (col & 7)) * 8)];
                acc[0][n] = __builtin_amdgcn_mfma_f32_16x16x32_bf16(a0, bn, acc[0][n], 0, 0, 0);
                acc[1][n] = __builtin_amdgcn_mfma_f32_16x16x32_bf16(a1, bn, acc[1][n], 0, 0, 0);
            }
        }
    }
    #pragma unroll
    for (int m = 0; m < 2; ++m) {
        #pragma unroll
        for (int n = 0; n < 6; ++n) {
            int col = n * 16 + cl;
            float bv = bias[n0g + col];
            #pragma unroll
            for (int j = 0; j < 4; ++j) {
                int row = m0 + wrow + m * 16 + r0 * 4 + j;
                dst[(size_t)row * 192 + coln + col] = f2bf(acc[m][n][j] + bv);
            }
        }
    }
}

// =================== proj GEMM: bf16 A (row-major) x f32 Bw -> f32 out ======
__global__ __launch_bounds__(256) void proj_mfma(const ushort_t* __restrict__ Ab,
        const float* __restrict__ Bw, const float* __restrict__ bias,
        float* __restrict__ Cout)
{
    __shared__ __align__(16) ushort_t As[128 * 64];
    __shared__ __align__(16) ushort_t Bs[96 * 64];
    const int m0 = blockIdx.x * 128;
    const int n0 = blockIdx.y * 96;
    const int tid = threadIdx.x;
    const int lane = tid & 63;
    const int wrow = (tid >> 6) * 32;
    const int r0 = lane >> 4, cl = lane & 15;
    f32x4 acc[2][6] = {};

    for (int ks = 0; ks < 3; ++ks) {
        const int k0 = ks * 64;
        if (ks) __syncthreads();
        #pragma unroll
        for (int i = 0; i < 2; ++i) {
            int s = tid + i * 256;
            int row = s >> 2, q = s & 3;
            const ushort_t* src = Ab + (size_t)(m0 + row) * 192 + k0 + q * 16;
            uint4 u0 = *(const uint4*)(src);
            uint4 u1 = *(const uint4*)(src + 8);
            int r7 = row & 7;
            *(uint4*)&As[row * 64 + (((q * 2) ^ r7) * 8)] = u0;
            *(uint4*)&As[row * 64 + (((q * 2 + 1) ^ r7) * 8)] = u1;
        }
        #pragma unroll
        for (int i = 0; i < 6; ++i) {
            int f = tid + i * 256;
            int k = f / 24, c4 = (f % 24) * 4;
            float4 v = *(const float4*)(Bw + (size_t)(k0 + k) * 192 + n0 + c4);
            int kw = k >> 3, ke = k & 7;
            Bs[(c4 + 0) * 64 + ((kw ^ ((c4 + 0) & 7)) * 8) + ke] = f2bf(v.x);
            Bs[(c4 + 1) * 64 + ((kw ^ ((c4 + 1) & 7)) * 8) + ke] = f2bf(v.y);
            Bs[(c4 + 2) * 64 + ((kw ^ ((c4 + 2) & 7)) * 8) + ke] = f2bf(v.z);
            Bs[(c4 + 3) * 64 + ((kw ^ ((c4 + 3) & 7)) * 8) + ke] = f2bf(v.w);
        }
        __syncthreads();
        #pragma unroll
        for (int kk = 0; kk < 2; ++kk) {
            int kslot = kk * 4 + r0;
            int ra0 = wrow + cl, ra1 = wrow + 16 + cl;
            short8 a0 = *(const short8*)&As[ra0 * 64 + ((kslot ^ (ra0 & 7)) * 8)];
            short8 a1 = *(const short8*)&As[ra1 * 64 + ((kslot ^ (ra1 & 7)) * 8)];
            #pragma unroll
            for (int n = 0; n < 6; ++n) {
                int col = n * 16 + cl;
                short8 bn = *(const short8*)&Bs[col * 64 + ((kslot ^ (col & 7)) * 8)];
                acc[0][n] = __builtin_amdgcn_mfma_f32_16x16x32_bf16(a0, bn, acc[0][n], 0, 0, 0);
                acc[1][n] = __builtin_amdgcn_mfma_f32_16x16x32_bf16(a1, bn, acc[1][n], 0, 0, 0);
            }
        }
    }
    #pragma unroll
    for (int m = 0; m < 2; ++m) {
        #pragma unroll
        for (int n = 0; n < 6; ++n) {
            int col = n0 + n * 16 + cl;
            float bv = bias[col];
            #pragma unroll
            for (int j = 0; j < 4; ++j) {
                int row = m0 + wrow + m * 16 + r0 * 4 + j;
                Cout[(size_t)row * 192 + col] = acc[m][n][j] + bv;
            }
        }
    }
}

// ============ MFMA window attention, both branches in one launch ============
__global__ __launch_bounds__(256) void attn_mfma(const ushort_t* __restrict__ Qb,
        const ushort_t* __restrict__ Kb, const ushort_t* __restrict__ Vb,
        const float* __restrict__ gate_s, ushort_t* __restrict__ fu_b)
{
    __shared__ float Of[4][16][33];
    const int widx = threadIdx.x >> 6;
    const int idx = blockIdx.x * 4 + widx;          // 0..6143
    const int branch = (idx >= 3072) ? 1 : 0;
    const int sub = idx - branch * 3072;
    const int head = sub >> 10;
    const int b = (sub >> 7) & 7;
    const int win = sub & 127;
    const int L = threadIdx.x & 63;
    const int g = L >> 4, q = L & 15;
    int hb, wb;
    if (branch == 0) { hb = (win >> 3) * 8;  wb = (win & 7) * 16; }
    else             { hb = (win >> 4) * 16; wb = (win & 15) * 8; }
    const int cf = branch * 96 + head * 32;

    auto rowoff = [&](int t) -> size_t {
        int l = (branch == 0) ? (hb + (t >> 4)) * Wn + wb + (t & 15)
                              : (hb + (t >> 3)) * Wn + wb + (t & 7);
        return (size_t)(b * Ln + l) * 192;
    };

    short8 kf[8], qf[8];
    #pragma unroll
    for (int i = 0; i < 8; ++i) {
        size_t rb = rowoff(16 * i + q);
        qf[i] = *(const short8*)(Qb + rb + cf + 8 * g);
        kf[i] = *(const short8*)(Kb + rb + cf + 8 * g);
    }
    short8 vf[2][4];
    {
        size_t vrb[8];
        #pragma unroll
        for (int e = 0; e < 8; ++e)
            vrb[e] = rowoff(8 * g + e) + cf + q;
        const size_t sstep = (size_t)(branch == 0 ? 256 : 512) * 192;
        #pragma unroll
        for (int s = 0; s < 4; ++s) {
            #pragma unroll
            for (int dblk = 0; dblk < 2; ++dblk) {
                uint4v wv;
                #pragma unroll
                for (int e2 = 0; e2 < 4; ++e2) {
                    unsigned lo = Vb[vrb[2 * e2]     + s * sstep + 16 * dblk];
                    unsigned hi = Vb[vrb[2 * e2 + 1] + s * sstep + 16 * dblk];
                    wv[e2] = lo | (hi << 16);
                }
                vf[dblk][s] = *(short8*)&wv;
            }
        }
    }

    const float SC = 0.5303300858899106f;   // 3/sqrt(32)
    const int src0 = q + ((g & 1) << 5);
    const bool thi = (g >> 1) != 0;
    #pragma unroll
    for (int j = 0; j < 8; ++j) {
        unsigned wA[8], wB[8];
        float ss = 0.0f;
        #pragma unroll
        for (int i = 0; i < 8; ++i) {
            f32x4 z = {};
            f32x4 S = __builtin_amdgcn_mfma_f32_16x16x32_bf16(kf[i], qf[j], z, 0, 0, 0);
            float p0 = __expf(S[0] * SC), p1 = __expf(S[1] * SC);
            float p2 = __expf(S[2] * SC), p3 = __expf(S[3] * SC);
            ss += (p0 + p1) + (p2 + p3);
            wA[i] = pk2(p0, p1);
            wB[i] = pk2(p2, p3);
        }
        ss += __shfl_xor(ss, 16);
        ss += __shfl_xor(ss, 32);
        float inv = 3.0f / ss;

        f32x4 O0 = {}, O1 = {};
        #pragma unroll
        for (int s = 0; s < 4; ++s) {
            unsigned a0  = (unsigned)__shfl((int)wA[2*s],     src0);
            unsigned b0  = (unsigned)__shfl((int)wB[2*s],     src0);
            unsigned a0h = (unsigned)__shfl((int)wA[2*s],     src0 + 16);
            unsigned b0h = (unsigned)__shfl((int)wB[2*s],     src0 + 16);
            unsigned a1  = (unsigned)__shfl((int)wA[2*s+1],   src0);
            unsigned b1  = (unsigned)__shfl((int)wB[2*s+1],   src0);
            unsigned a1h = (unsigned)__shfl((int)wA[2*s+1],   src0 + 16);
            unsigned b1h = (unsigned)__shfl((int)wB[2*s+1],   src0 + 16);
            uint4v B2u;
            B2u[0] = thi ? a1  : a0;
            B2u[1] = thi ? b1  : b0;
            B2u[2] = thi ? a1h : a0h;
            B2u[3] = thi ? b1h : b0h;
            short8 B2 = *(short8*)&B2u;
            O0 = __builtin_amdgcn_mfma_f32_16x16x32_bf16(vf[0][s], B2, O0, 0, 0, 0);
            O1 = __builtin_amdgcn_mfma_f32_16x16x32_bf16(vf[1][s], B2, O1, 0, 0, 0);
        }
        #pragma unroll
        for (int r = 0; r < 4; ++r) {
            Of[widx][q][4 * g + r]      = O0[r] * inv;
            Of[widx][q][16 + 4 * g + r] = O1[r] * inv;
        }
        __syncthreads();
        {
            int rr = L >> 2, c = L & 3;
            int l;
            if (branch == 0) l = (hb + j) * Wn + wb + rr;
            else             l = (hb + 2 * j + (rr >> 3)) * Wn + wb + (rr & 7);
            float gs = gate_s[(size_t)b * Ln + l];
            float* src = &Of[widx][rr][c * 8];
            uint4 o = make_uint4(pk2(src[0] * gs, src[1] * gs),
                                 pk2(src[2] * gs, src[3] * gs),
                                 pk2(src[4] * gs, src[5] * gs),
                                 pk2(src[6] * gs, src[7] * gs));
            *(uint4*)(fu_b + (size_t)(b * Ln + l) * 192 + cf + c * 8) = o;
        }
        __syncthreads();
    }
}

// ---- conv1: dwconv3x3+BN+GELU per (b,c) plane, register row rotation -------
// thread = 4-px float4 strip x 16-row band; each row loaded once per thread.
__global__ __launch_bounds__(256) void conv1_k(const float* __restrict__ x,
        const float* __restrict__ wdw, const float* __restrict__ bdw,
        const float* __restrict__ g1, const float* __restrict__ be1,
        ushort_t* __restrict__ conv1b, float* __restrict__ pooled)
{
    int bc = blockIdx.x;                   // b*192 + c
    int c = bc % 192;
    const float* plane = x + (size_t)bc * Ln;
    ushort_t* oplane = conv1b + (size_t)bc * Ln;
    int t = threadIdx.x;
    int sx = t & 31, sy = t >> 5;          // 32 strips x 8 bands
    int w0 = sx * 4, h0 = sy * 16;
    float wk[9];
    #pragma unroll
    for (int i = 0; i < 9; ++i) wk[i] = wdw[c * 9 + i];
    float gb = g1[c] * BN_RSQ, bb = be1[c], bd = bdw[c];

    float rA[6], rB[6], rC[6];
    auto load6 = [&](int h, float* r) {
        if (h < 0 || h >= Hn) {
            r[0] = r[1] = r[2] = r[3] = r[4] = r[5] = 0.0f;
            return;
        }
        const float* rp = plane + h * Wn;
        float4 m = *(const float4*)(rp + w0);
        r[0] = sx ? rp[w0 - 1] : 0.0f;
        r[1] = m.x; r[2] = m.y; r[3] = m.z; r[4] = m.w;
        r[5] = (sx < 31) ? rp[w0 + 4] : 0.0f;
    };
    load6(h0 - 1, rA);
    load6(h0, rB);
    float psum = 0.0f;
    #pragma unroll
    for (int i = 0; i < 16; ++i) {
        int h = h0 + i;
        load6(h + 1, rC);
        float o[4];
        #pragma unroll
        for (int p = 0; p < 4; ++p) {
            float s = wk[0] * rA[p];
            s = fmaf(wk[1], rA[p + 1], s);
            s = fmaf(wk[2], rA[p + 2], s);
            s = fmaf(wk[3], rB[p],     s);
            s = fmaf(wk[4], rB[p + 1], s);
            s = fmaf(wk[5], rB[p + 2], s);
            s = fmaf(wk[6], rC[p],     s);
            s = fmaf(wk[7], rC[p + 1], s);
            s = fmaf(wk[8], rC[p + 2], s);
            float y = gelu_f((s + bd) * gb + bb);
            psum += y;
            o[p] = y;
        }
        uint2 ow = make_uint2(pk2(o[0], o[1]), pk2(o[2], o[3]));
        *(uint2*)(oplane + h * Wn + w0) = ow;
        #pragma unroll
        for (int q2 = 0; q2 < 6; ++q2) { rA[q2] = rB[q2]; rB[q2] = rC[q2]; }
    }
    __shared__ float red[4];
    for (int off = 32; off; off >>= 1) psum += __shfl_down(psum, off);
    if ((t & 63) == 0) red[t >> 6] = psum;
    __syncthreads();
    if (t == 0)
        pooled[bc] = (red[0] + red[1] + red[2] + red[3]) * (1.0f / Ln);
}

// ------- spatial gate: per-pixel 192->24->1 MLP on bf16 conv1 ---------------
__global__ __launch_bounds__(128) void spatial_gate_k(const ushort_t* __restrict__ conv1b,
        const float* __restrict__ ws1g, const float* __restrict__ bs1,
        const float* __restrict__ gsi, const float* __restrict__ besi,
        const float* __restrict__ ws2, const float* __restrict__ bs2,
        float* __restrict__ gate_s)
{
    int bh = blockIdx.x;                   // b*128 + h
    int b = bh >> 7, h = bh & 127;
    int w = threadIdx.x;
    __shared__ float ws1T[192 * 24];       // [c][o]
    for (int i = w; i < 192 * 24; i += 128) {
        int c = i / 24, o = i - c * 24;
        ws1T[i] = ws1g[o * 192 + c];
    }
    __syncthreads();
    float acc24[24] = {};
    const ushort_t* base = conv1b + (size_t)b * 192 * Ln + h * Wn + w;
    #pragma unroll 4
    for (int c = 0; c < 192; ++c) {
        float v = bf2f(base[(size_t)c * Ln]);
        const float4* wp = (const float4*)&ws1T[c * 24];
        #pragma unroll
        for (int o4 = 0; o4 < 6; ++o4) {
            float4 wv = wp[o4];
            acc24[o4*4+0] = fmaf(v, wv.x, acc24[o4*4+0]);
            acc24[o4*4+1] = fmaf(v, wv.y, acc24[o4*4+1]);
            acc24[o4*4+2] = fmaf(v, wv.z, acc24[o4*4+2]);
            acc24[o4*4+3] = fmaf(v, wv.w, acc24[o4*4+3]);
        }
    }
    float s2 = bs2[0];
    #pragma unroll
    for (int o = 0; o < 24; ++o)
        s2 = fmaf(gelu_f((acc24[o] + bs1[o]) * (gsi[o] * BN_RSQ) + besi[o]), ws2[o], s2);
    gate_s[(size_t)bh * 128 + w] = gate1p(s2);
}

// ---------------- channel gate: 192->24->192 MLP on pooled ------------------
__global__ __launch_bounds__(192) void channel_gate_k(const float* __restrict__ pooled,
        const float* __restrict__ w1, const float* __restrict__ b1,
        const float* __restrict__ g, const float* __restrict__ be,
        const float* __restrict__ w2, const float* __restrict__ b2,
        float* __restrict__ gate_c)
{
    int b = blockIdx.x, t = threadIdx.x;
    __shared__ float pl[192];
    __shared__ float h1[24];
    pl[t] = pooled[b * 192 + t];
    __syncthreads();
    if (t < 24) {
        float a = b1[t];
        for (int c = 0; c < 192; ++c) a = fmaf(pl[c], w1[t * 192 + c], a);
        a = a * (g[t] * BN_RSQ) + be[t];
        h1[t] = gelu_f(a);
    }
    __syncthreads();
    float a = b2[t];
    #pragma unroll
    for (int o = 0; o < 24; ++o) a = fmaf(h1[o], w2[t * 24 + o], a);
    gate_c[b * 192 + t] = gate1p(a);
}

// ---- dwconv2: channels-last register 3x3 stencil on gated bf16 fu ----------
__global__ __launch_bounds__(256) void dwconv2_k(const ushort_t* __restrict__ fu_b,
        const float* __restrict__ gate_c,
        const float* __restrict__ wdw, const float* __restrict__ bdw,
        const float* __restrict__ g2, const float* __restrict__ be2,
        ushort_t* __restrict__ out2b)
{
    int bh = blockIdx.x >> 1;              // b*128 + h
    int whalf = blockIdx.x & 1;
    int b = bh >> 7, h = bh & 127;
    int tid = threadIdx.x;
    __shared__ float cw[192 * 9];
    __shared__ float cbd[192], cgb[192], cbe[192], cgc[192];
    for (int i = tid; i < 192 * 9; i += 256) cw[i] = wdw[i];
    for (int i = tid; i < 192; i += 256) {
        cbd[i] = bdw[i];
        cgb[i] = g2[i] * BN_RSQ;
        cbe[i] = be2[i];
        cgc[i] = gate_c[b * 192 + i];
    }
    __syncthreads();
    const size_t outrow = (size_t)(b * Ln + h * Wn) * 192;
    for (int it = 0; it < 6; ++it) {
        int item = it * 256 + tid;          // 0..1535
        int w = whalf * 64 + item / 24;
        int c8 = item % 24;
        int co = c8 * 8;
        uint4 nb[3][3];
        #pragma unroll
        for (int r = 0; r < 3; ++r)
            #pragma unroll
            for (int d = 0; d < 3; ++d)
                nb[r][d] = make_uint4(0u, 0u, 0u, 0u);
        #pragma unroll
        for (int r = 0; r < 3; ++r) {
            int hh = h - 1 + r;
            if (hh < 0 || hh >= Hn) continue;
            const ushort_t* rp = fu_b + (size_t)(b * Ln + hh * Wn) * 192 + co;
            #pragma unroll
            for (int d = 0; d < 3; ++d) {
                int w2 = w - 1 + d;
                if (w2 < 0 || w2 >= Wn) continue;
                nb[r][d] = *(const uint4*)(rp + (size_t)w2 * 192);
            }
        }
        unsigned ou[4];
        #pragma unroll
        for (int i = 0; i < 8; ++i) {
            int c = co + i;
            float s = 0.0f;
            #pragma unroll
            for (int r = 0; r < 3; ++r) {
                #pragma unroll
                for (int d = 0; d < 3; ++d) {
                    unsigned word = ((const unsigned*)&nb[r][d])[i >> 1];
                    float v = __uint_as_float((i & 1) ? (word & 0xffff0000u)
                                                      : (word << 16));
                    s = fmaf(cw[c * 9 + r * 3 + d], v, s);
                }
            }
            float y = gelu_f((s + cbd[c]) * cgb[c] + cbe[c]) * cgc[c];
            if (i & 1) ou[i >> 1] |= (unsigned)f2bf(y) << 16;
            else       ou[i >> 1] = (unsigned)f2bf(y);
        }
        *(uint4*)(out2b + outrow + (size_t)w * 192 + co) =
            make_uint4(ou[0], ou[1], ou[2], ou[3]);
    }
}

extern "C" void kernel_launch(void* const* d_in, const int* in_sizes, int n_in,
                              void* d_out, int out_size, void* d_ws, size_t ws_size,
                              hipStream_t stream) {
    (void)in_sizes; (void)n_in; (void)out_size; (void)ws_size;
    const float* x      = (const float*)d_in[0];
    const float* w_qkv  = (const float*)d_in[1];
    const float* b_qkv  = (const float*)d_in[2];
    const float* w_dw1  = (const float*)d_in[3];
    const float* b_dw1  = (const float*)d_in[4];
    const float* g_bn1  = (const float*)d_in[5];
    const float* be_bn1 = (const float*)d_in[6];
    const float* w_si1  = (const float*)d_in[7];
    const float* b_si1  = (const float*)d_in[8];
    const float* g_si   = (const float*)d_in[9];
    const float* be_si  = (const float*)d_in[10];
    const float* w_si2  = (const float*)d_in[11];
    const float* b_si2  = (const float*)d_in[12];
    const float* w_ci1  = (const float*)d_in[13];
    const float* b_ci1  = (const float*)d_in[14];
    const float* g_ci   = (const float*)d_in[15];
    const float* be_ci  = (const float*)d_in[16];
    const float* w_ci2  = (const float*)d_in[17];
    const float* b_ci2  = (const float*)d_in[18];
    const float* w_dw2  = (const float*)d_in[19];
    const float* b_dw2  = (const float*)d_in[20];
    const float* g_bn2  = (const float*)d_in[21];
    const float* be_bn2 = (const float*)d_in[22];
    const float* w_proj = (const float*)d_in[23];
    const float* b_proj = (const float*)d_in[24];

    // ws (f32 units):
    //   phase A: conv1b bf16 [0, FUn/2)             [conv1 -> spatial_gate]
    //   phase B: Qb bf16 [0, FUn/2), Kb bf16 [FUn/2, FUn)   [qkv -> attn]
    //   phase C: out2b bf16 at [8M, 8M+FUn/2)       [dwconv2 -> proj]
    //   smalls at FUn: gate_s, gate_c, pooled
    // d_out (shorts): fu_b [0, FUn), Vb [FUn, 2*FUn); proj overwrites all (f32).
    float* ws = (float*)d_ws;
    ushort_t* conv1b = (ushort_t*)ws;
    ushort_t* Qb     = (ushort_t*)ws;
    ushort_t* Kb     = (ushort_t*)(ws + FUn / 2);
    ushort_t* out2b  = (ushort_t*)(ws + 8000000);
    float* gate_s    = ws + FUn;                       // B*L
    float* gate_c    = gate_s + (size_t)Bn * Ln;       // B*192
    float* pooled    = gate_c + Bn * 192;              // B*192
    ushort_t* fu_b   = (ushort_t*)d_out;
    ushort_t* Vb     = (ushort_t*)d_out + FUn;

    conv1_k<<<Bn * 192, 256, 0, stream>>>(x, w_dw1, b_dw1, g_bn1, be_bn1, conv1b, pooled);
    spatial_gate_k<<<Bn * Hn, 128, 0, stream>>>(conv1b, w_si1, b_si1, g_si, be_si,
                                                w_si2, b_si2, gate_s);
    channel_gate_k<<<Bn, 192, 0, stream>>>(pooled, w_ci1, b_ci1, g_ci, be_ci,
                                           w_ci2, b_ci2, gate_c);
    qkv_mfma<<<dim3(Mn / 128, 6), 256, 0, stream>>>(x, w_qkv, b_qkv, Qb, Kb, Vb);
    attn_mfma<<<1536, 256, 0, stream>>>(Qb, Kb, Vb, gate_s, fu_b);
    dwconv2_k<<<Bn * Hn * 2, 256, 0, stream>>>(fu_b, gate_c,
                                               w_dw2, b_dw2, g_bn2, be_bn2, out2b);
    proj_mfma<<<dim3(Mn / 128, 2), 256, 0, stream>>>(out2b, w_proj, b_proj, (float*)d_out);
}

// Round 8
// 463.919 us; speedup vs baseline: 2.8819x; 1.1296x over previous
//
#include <hip/hip_runtime.h>

#define Bn 8
#define Hn 128
#define Wn 128
#define Cn 192
#define Ln (Hn*Wn)          // 16384
#define Mn (Bn*Ln)          // 131072
#define FUn ((size_t)Mn*Cn) // 25,165,824 floats
#define BN_RSQ 0.9999950000374997f   // 1/sqrt(1+1e-5)

typedef unsigned short ushort_t;
typedef __attribute__((ext_vector_type(8))) short short8;
typedef __attribute__((ext_vector_type(4))) float f32x4;
typedef __attribute__((ext_vector_type(4))) unsigned int uint4v;

static __device__ __forceinline__ float gelu_f(float x) {
    return 0.5f * x * (1.0f + erff(x * 0.7071067811865475f));
}
static __device__ __forceinline__ float gate1p(float x) {  // 1 + sigmoid(x)
    return 1.0f + 1.0f / (1.0f + __expf(-x));
}
static __device__ __forceinline__ unsigned short f2bf(float f) {  // RNE
    unsigned u = __float_as_uint(f);
    return (unsigned short)((u + 0x7FFFu + ((u >> 16) & 1u)) >> 16);
}
static __device__ __forceinline__ unsigned int pk2(float lo, float hi) {
    return (unsigned int)f2bf(lo) | ((unsigned int)f2bf(hi) << 16);
}
static __device__ __forceinline__ float bf2f(ushort_t u) {
    return __uint_as_float((unsigned)u << 16);
}

// ---------------- cast x (f32, 100MB) -> xb (bf16, 50MB) --------------------
__global__ __launch_bounds__(256) void cast_k(const float* __restrict__ x,
                                              ushort_t* __restrict__ xb)
{
    size_t i0 = (size_t)blockIdx.x * 256 + threadIdx.x;
    for (size_t i = i0; i < FUn / 8; i += (size_t)gridDim.x * 256) {
        const float* s = x + i * 8;
        float4 a = *(const float4*)s;
        float4 b = *(const float4*)(s + 4);
        uint4 o = make_uint4(pk2(a.x, a.y), pk2(a.z, a.w),
                             pk2(b.x, b.y), pk2(b.z, b.w));
        *(uint4*)(xb + i * 8) = o;
    }
}

// ========== qkv GEMM (bf16 A; all 576 cols), writes Q/K/V parts ============
__global__ __launch_bounds__(256) void qkv_mfma(const ushort_t* __restrict__ Ab,
        const float* __restrict__ Bw, const float* __restrict__ bias,
        ushort_t* __restrict__ Qp, ushort_t* __restrict__ Kp,
        ushort_t* __restrict__ Vp)
{
    __shared__ __align__(16) ushort_t As[128 * 64];
    __shared__ __align__(16) ushort_t Bs[96 * 64];
    const int m0 = blockIdx.x * 128;
    const int n0g = blockIdx.y * 96;                  // 0..480
    const int part = n0g / 192;
    const int coln = n0g - part * 192;
    ushort_t* dst = part == 0 ? Qp : (part == 1 ? Kp : Vp);
    const int tid = threadIdx.x;
    const int lane = tid & 63;
    const int wrow = (tid >> 6) * 32;
    const int r0 = lane >> 4, cl = lane & 15;
    f32x4 acc[2][6] = {};

    for (int ks = 0; ks < 3; ++ks) {
        const int k0 = ks * 64;
        if (ks) __syncthreads();
        // ---- stage A: bf16 copy, conflict-free phases ----
        #pragma unroll
        for (int i = 0; i < 2; ++i) {
            int s = tid + i * 256;
            int row = s >> 2, q = s & 3;
            const ushort_t* src = Ab + (size_t)(m0 + row) * 192 + k0 + q * 16;
            uint4 u0 = *(const uint4*)(src);
            uint4 u1 = *(const uint4*)(src + 8);
            int r7 = row & 7;
            *(uint4*)&As[row * 64 + (((q * 2) ^ r7) * 8)] = u0;
            *(uint4*)&As[row * 64 + (((q * 2 + 1) ^ r7) * 8)] = u1;
        }
        // ---- stage B: thread = (col, kslot), packed uint4 write ----
        #pragma unroll
        for (int i = 0; i < 3; ++i) {
            int f = tid + i * 256;                    // 0..767
            int col = f % 96, kslot = f / 96;
            uint4v wv;
            #pragma unroll
            for (int e2 = 0; e2 < 4; ++e2) {
                float lo = Bw[(size_t)(k0 + kslot * 8 + 2 * e2)     * 576 + n0g + col];
                float hi = Bw[(size_t)(k0 + kslot * 8 + 2 * e2 + 1) * 576 + n0g + col];
                wv[e2] = pk2(lo, hi);
            }
            *(uint4v*)&Bs[col * 64 + ((kslot ^ (col & 7)) * 8)] = wv;
        }
        __syncthreads();
        #pragma unroll
        for (int kk = 0; kk < 2; ++kk) {
            int kslot = kk * 4 + r0;
            int ra0 = wrow + cl, ra1 = wrow + 16 + cl;
            short8 a0 = *(const short8*)&As[ra0 * 64 + ((kslot ^ (ra0 & 7)) * 8)];
            short8 a1 = *(const short8*)&As[ra1 * 64 + ((kslot ^ (ra1 & 7)) * 8)];
            #pragma unroll
            for (int n = 0; n < 6; ++n) {
                int col = n * 16 + cl;
                short8 bn = *(const short8*)&Bs[col * 64 + ((kslot ^ (col & 7)) * 8)];
                acc[0][n] = __builtin_amdgcn_mfma_f32_16x16x32_bf16(a0, bn, acc[0][n], 0, 0, 0);
                acc[1][n] = __builtin_amdgcn_mfma_f32_16x16x32_bf16(a1, bn, acc[1][n], 0, 0, 0);
            }
        }
    }
    #pragma unroll
    for (int m = 0; m < 2; ++m) {
        #pragma unroll
        for (int n = 0; n < 6; ++n) {
            int col = n * 16 + cl;
            float bv = bias[n0g + col];
            #pragma unroll
            for (int j = 0; j < 4; ++j) {
                int row = m0 + wrow + m * 16 + r0 * 4 + j;
                dst[(size_t)row * 192 + coln + col] = f2bf(acc[m][n][j] + bv);
            }
        }
    }
}

// =================== proj GEMM: bf16 A (row-major) x f32 Bw -> f32 out ======
__global__ __launch_bounds__(256) void proj_mfma(const ushort_t* __restrict__ Ab,
        const float* __restrict__ Bw, const float* __restrict__ bias,
        float* __restrict__ Cout)
{
    __shared__ __align__(16) ushort_t As[128 * 64];
    __shared__ __align__(16) ushort_t Bs[96 * 64];
    const int m0 = blockIdx.x * 128;
    const int n0 = blockIdx.y * 96;
    const int tid = threadIdx.x;
    const int lane = tid & 63;
    const int wrow = (tid >> 6) * 32;
    const int r0 = lane >> 4, cl = lane & 15;
    f32x4 acc[2][6] = {};

    for (int ks = 0; ks < 3; ++ks) {
        const int k0 = ks * 64;
        if (ks) __syncthreads();
        #pragma unroll
        for (int i = 0; i < 2; ++i) {
            int s = tid + i * 256;
            int row = s >> 2, q = s & 3;
            const ushort_t* src = Ab + (size_t)(m0 + row) * 192 + k0 + q * 16;
            uint4 u0 = *(const uint4*)(src);
            uint4 u1 = *(const uint4*)(src + 8);
            int r7 = row & 7;
            *(uint4*)&As[row * 64 + (((q * 2) ^ r7) * 8)] = u0;
            *(uint4*)&As[row * 64 + (((q * 2 + 1) ^ r7) * 8)] = u1;
        }
        #pragma unroll
        for (int i = 0; i < 3; ++i) {
            int f = tid + i * 256;
            int col = f % 96, kslot = f / 96;
            uint4v wv;
            #pragma unroll
            for (int e2 = 0; e2 < 4; ++e2) {
                float lo = Bw[(size_t)(k0 + kslot * 8 + 2 * e2)     * 192 + n0 + col];
                float hi = Bw[(size_t)(k0 + kslot * 8 + 2 * e2 + 1) * 192 + n0 + col];
                wv[e2] = pk2(lo, hi);
            }
            *(uint4v*)&Bs[col * 64 + ((kslot ^ (col & 7)) * 8)] = wv;
        }
        __syncthreads();
        #pragma unroll
        for (int kk = 0; kk < 2; ++kk) {
            int kslot = kk * 4 + r0;
            int ra0 = wrow + cl, ra1 = wrow + 16 + cl;
            short8 a0 = *(const short8*)&As[ra0 * 64 + ((kslot ^ (ra0 & 7)) * 8)];
            short8 a1 = *(const short8*)&As[ra1 * 64 + ((kslot ^ (ra1 & 7)) * 8)];
            #pragma unroll
            for (int n = 0; n < 6; ++n) {
                int col = n * 16 + cl;
                short8 bn = *(const short8*)&Bs[col * 64 + ((kslot ^ (col & 7)) * 8)];
                acc[0][n] = __builtin_amdgcn_mfma_f32_16x16x32_bf16(a0, bn, acc[0][n], 0, 0, 0);
                acc[1][n] = __builtin_amdgcn_mfma_f32_16x16x32_bf16(a1, bn, acc[1][n], 0, 0, 0);
            }
        }
    }
    #pragma unroll
    for (int m = 0; m < 2; ++m) {
        #pragma unroll
        for (int n = 0; n < 6; ++n) {
            int col = n0 + n * 16 + cl;
            float bv = bias[col];
            #pragma unroll
            for (int j = 0; j < 4; ++j) {
                int row = m0 + wrow + m * 16 + r0 * 4 + j;
                Cout[(size_t)row * 192 + col] = acc[m][n][j] + bv;
            }
        }
    }
}

// ============ MFMA window attention, both branches in one launch ============
__global__ __launch_bounds__(256) void attn_mfma(const ushort_t* __restrict__ Qb,
        const ushort_t* __restrict__ Kb, const ushort_t* __restrict__ Vb,
        const float* __restrict__ gate_s, ushort_t* __restrict__ fu_b)
{
    __shared__ float Of[4][16][33];
    const int widx = threadIdx.x >> 6;
    const int idx = blockIdx.x * 4 + widx;          // 0..6143
    const int branch = (idx >= 3072) ? 1 : 0;
    const int sub = idx - branch * 3072;
    const int head = sub >> 10;
    const int b = (sub >> 7) & 7;
    const int win = sub & 127;
    const int L = threadIdx.x & 63;
    const int g = L >> 4, q = L & 15;
    int hb, wb;
    if (branch == 0) { hb = (win >> 3) * 8;  wb = (win & 7) * 16; }
    else             { hb = (win >> 4) * 16; wb = (win & 15) * 8; }
    const int cf = branch * 96 + head * 32;

    auto rowoff = [&](int t) -> size_t {
        int l = (branch == 0) ? (hb + (t >> 4)) * Wn + wb + (t & 15)
                              : (hb + (t >> 3)) * Wn + wb + (t & 7);
        return (size_t)(b * Ln + l) * 192;
    };

    short8 kf[8], qf[8];
    #pragma unroll
    for (int i = 0; i < 8; ++i) {
        size_t rb = rowoff(16 * i + q);
        qf[i] = *(const short8*)(Qb + rb + cf + 8 * g);
        kf[i] = *(const short8*)(Kb + rb + cf + 8 * g);
    }
    short8 vf[2][4];
    {
        size_t vrb[8];
        #pragma unroll
        for (int e = 0; e < 8; ++e)
            vrb[e] = rowoff(8 * g + e) + cf + q;
        const size_t sstep = (size_t)(branch == 0 ? 256 : 512) * 192;
        #pragma unroll
        for (int s = 0; s < 4; ++s) {
            #pragma unroll
            for (int dblk = 0; dblk < 2; ++dblk) {
                uint4v wv;
                #pragma unroll
                for (int e2 = 0; e2 < 4; ++e2) {
                    unsigned lo = Vb[vrb[2 * e2]     + s * sstep + 16 * dblk];
                    unsigned hi = Vb[vrb[2 * e2 + 1] + s * sstep + 16 * dblk];
                    wv[e2] = lo | (hi << 16);
                }
                vf[dblk][s] = *(short8*)&wv;
            }
        }
    }

    const float SC = 0.5303300858899106f;   // 3/sqrt(32)
    const int src0 = q + ((g & 1) << 5);
    const bool thi = (g >> 1) != 0;
    #pragma unroll
    for (int j = 0; j < 8; ++j) {
        unsigned wA[8], wB[8];
        float ss = 0.0f;
        #pragma unroll
        for (int i = 0; i < 8; ++i) {
            f32x4 z = {};
            f32x4 S = __builtin_amdgcn_mfma_f32_16x16x32_bf16(kf[i], qf[j], z, 0, 0, 0);
            float p0 = __expf(S[0] * SC), p1 = __expf(S[1] * SC);
            float p2 = __expf(S[2] * SC), p3 = __expf(S[3] * SC);
            ss += (p0 + p1) + (p2 + p3);
            wA[i] = pk2(p0, p1);
            wB[i] = pk2(p2, p3);
        }
        ss += __shfl_xor(ss, 16);
        ss += __shfl_xor(ss, 32);
        float inv = 3.0f / ss;

        f32x4 O0 = {}, O1 = {};
        #pragma unroll
        for (int s = 0; s < 4; ++s) {
            unsigned a0  = (unsigned)__shfl((int)wA[2*s],     src0);
            unsigned b0  = (unsigned)__shfl((int)wB[2*s],     src0);
            unsigned a0h = (unsigned)__shfl((int)wA[2*s],     src0 + 16);
            unsigned b0h = (unsigned)__shfl((int)wB[2*s],     src0 + 16);
            unsigned a1  = (unsigned)__shfl((int)wA[2*s+1],   src0);
            unsigned b1  = (unsigned)__shfl((int)wB[2*s+1],   src0);
            unsigned a1h = (unsigned)__shfl((int)wA[2*s+1],   src0 + 16);
            unsigned b1h = (unsigned)__shfl((int)wB[2*s+1],   src0 + 16);
            uint4v B2u;
            B2u[0] = thi ? a1  : a0;
            B2u[1] = thi ? b1  : b0;
            B2u[2] = thi ? a1h : a0h;
            B2u[3] = thi ? b1h : b0h;
            short8 B2 = *(short8*)&B2u;
            O0 = __builtin_amdgcn_mfma_f32_16x16x32_bf16(vf[0][s], B2, O0, 0, 0, 0);
            O1 = __builtin_amdgcn_mfma_f32_16x16x32_bf16(vf[1][s], B2, O1, 0, 0, 0);
        }
        #pragma unroll
        for (int r = 0; r < 4; ++r) {
            Of[widx][q][4 * g + r]      = O0[r] * inv;
            Of[widx][q][16 + 4 * g + r] = O1[r] * inv;
        }
        __syncthreads();
        {
            int rr = L >> 2, c = L & 3;
            int l;
            if (branch == 0) l = (hb + j) * Wn + wb + rr;
            else             l = (hb + 2 * j + (rr >> 3)) * Wn + wb + (rr & 7);
            float gs = gate_s[(size_t)b * Ln + l];
            float* src = &Of[widx][rr][c * 8];
            uint4 o = make_uint4(pk2(src[0] * gs, src[1] * gs),
                                 pk2(src[2] * gs, src[3] * gs),
                                 pk2(src[4] * gs, src[5] * gs),
                                 pk2(src[6] * gs, src[7] * gs));
            *(uint4*)(fu_b + (size_t)(b * Ln + l) * 192 + cf + c * 8) = o;
        }
        __syncthreads();
    }
}

// ---- conv1: dwconv3x3+BN+GELU per (b,c) plane, register row rotation -------
__global__ __launch_bounds__(256) void conv1_k(const float* __restrict__ x,
        const float* __restrict__ wdw, const float* __restrict__ bdw,
        const float* __restrict__ g1, const float* __restrict__ be1,
        ushort_t* __restrict__ conv1b, float* __restrict__ pooled)
{
    int bc = blockIdx.x;                   // b*192 + c
    int c = bc % 192;
    const float* plane = x + (size_t)bc * Ln;
    ushort_t* oplane = conv1b + (size_t)bc * Ln;
    int t = threadIdx.x;
    int sx = t & 31, sy = t >> 5;          // 32 strips x 8 bands
    int w0 = sx * 4, h0 = sy * 16;
    float wk[9];
    #pragma unroll
    for (int i = 0; i < 9; ++i) wk[i] = wdw[c * 9 + i];
    float gb = g1[c] * BN_RSQ, bb = be1[c], bd = bdw[c];

    float rA[6], rB[6], rC[6];
    auto load6 = [&](int h, float* r) {
        if (h < 0 || h >= Hn) {
            r[0] = r[1] = r[2] = r[3] = r[4] = r[5] = 0.0f;
            return;
        }
        const float* rp = plane + h * Wn;
        float4 m = *(const float4*)(rp + w0);
        r[0] = sx ? rp[w0 - 1] : 0.0f;
        r[1] = m.x; r[2] = m.y; r[3] = m.z; r[4] = m.w;
        r[5] = (sx < 31) ? rp[w0 + 4] : 0.0f;
    };
    load6(h0 - 1, rA);
    load6(h0, rB);
    float psum = 0.0f;
    #pragma unroll
    for (int i = 0; i < 16; ++i) {
        int h = h0 + i;
        load6(h + 1, rC);
        float o[4];
        #pragma unroll
        for (int p = 0; p < 4; ++p) {
            float s = wk[0] * rA[p];
            s = fmaf(wk[1], rA[p + 1], s);
            s = fmaf(wk[2], rA[p + 2], s);
            s = fmaf(wk[3], rB[p],     s);
            s = fmaf(wk[4], rB[p + 1], s);
            s = fmaf(wk[5], rB[p + 2], s);
            s = fmaf(wk[6], rC[p],     s);
            s = fmaf(wk[7], rC[p + 1], s);
            s = fmaf(wk[8], rC[p + 2], s);
            float y = gelu_f((s + bd) * gb + bb);
            psum += y;
            o[p] = y;
        }
        uint2 ow = make_uint2(pk2(o[0], o[1]), pk2(o[2], o[3]));
        *(uint2*)(oplane + h * Wn + w0) = ow;
        #pragma unroll
        for (int q2 = 0; q2 < 6; ++q2) { rA[q2] = rB[q2]; rB[q2] = rC[q2]; }
    }
    __shared__ float red[4];
    for (int off = 32; off; off >>= 1) psum += __shfl_down(psum, off);
    if ((t & 63) == 0) red[t >> 6] = psum;
    __syncthreads();
    if (t == 0)
        pooled[bc] = (red[0] + red[1] + red[2] + red[3]) * (1.0f / Ln);
}

// ------- spatial gate: per-pixel 192->24->1 MLP on bf16 conv1 ---------------
__global__ __launch_bounds__(128) void spatial_gate_k(const ushort_t* __restrict__ conv1b,
        const float* __restrict__ ws1g, const float* __restrict__ bs1,
        const float* __restrict__ gsi, const float* __restrict__ besi,
        const float* __restrict__ ws2, const float* __restrict__ bs2,
        float* __restrict__ gate_s)
{
    int bh = blockIdx.x;                   // b*128 + h
    int b = bh >> 7, h = bh & 127;
    int w = threadIdx.x;
    __shared__ float ws1T[192 * 24];       // [c][o]
    for (int i = w; i < 192 * 24; i += 128) {
        int c = i / 24, o = i - c * 24;
        ws1T[i] = ws1g[o * 192 + c];
    }
    __syncthreads();
    float acc24[24] = {};
    const ushort_t* base = conv1b + (size_t)b * 192 * Ln + h * Wn + w;
    #pragma unroll 4
    for (int c = 0; c < 192; ++c) {
        float v = bf2f(base[(size_t)c * Ln]);
        const float4* wp = (const float4*)&ws1T[c * 24];
        #pragma unroll
        for (int o4 = 0; o4 < 6; ++o4) {
            float4 wv = wp[o4];
            acc24[o4*4+0] = fmaf(v, wv.x, acc24[o4*4+0]);
            acc24[o4*4+1] = fmaf(v, wv.y, acc24[o4*4+1]);
            acc24[o4*4+2] = fmaf(v, wv.z, acc24[o4*4+2]);
            acc24[o4*4+3] = fmaf(v, wv.w, acc24[o4*4+3]);
        }
    }
    float s2 = bs2[0];
    #pragma unroll
    for (int o = 0; o < 24; ++o)
        s2 = fmaf(gelu_f((acc24[o] + bs1[o]) * (gsi[o] * BN_RSQ) + besi[o]), ws2[o], s2);
    gate_s[(size_t)bh * 128 + w] = gate1p(s2);
}

// ---------------- channel gate: 192->24->192 MLP on pooled ------------------
__global__ __launch_bounds__(192) void channel_gate_k(const float* __restrict__ pooled,
        const float* __restrict__ w1, const float* __restrict__ b1,
        const float* __restrict__ g, const float* __restrict__ be,
        const float* __restrict__ w2, const float* __restrict__ b2,
        float* __restrict__ gate_c)
{
    int b = blockIdx.x, t = threadIdx.x;
    __shared__ float pl[192];
    __shared__ float h1[24];
    pl[t] = pooled[b * 192 + t];
    __syncthreads();
    if (t < 24) {
        float a = b1[t];
        for (int c = 0; c < 192; ++c) a = fmaf(pl[c], w1[t * 192 + c], a);
        a = a * (g[t] * BN_RSQ) + be[t];
        h1[t] = gelu_f(a);
    }
    __syncthreads();
    float a = b2[t];
    #pragma unroll
    for (int o = 0; o < 24; ++o) a = fmaf(h1[o], w2[t * 24 + o], a);
    gate_c[b * 192 + t] = gate1p(a);
}

// ---- dwconv2: channels-last register 3x3 stencil on gated bf16 fu ----------
__global__ __launch_bounds__(256) void dwconv2_k(const ushort_t* __restrict__ fu_b,
        const float* __restrict__ gate_c,
        const float* __restrict__ wdw, const float* __restrict__ bdw,
        const float* __restrict__ g2, const float* __restrict__ be2,
        ushort_t* __restrict__ out2b)
{
    int bh = blockIdx.x >> 1;              // b*128 + h
    int whalf = blockIdx.x & 1;
    int b = bh >> 7, h = bh & 127;
    int tid = threadIdx.x;
    __shared__ float cw[192 * 9];
    __shared__ float cbd[192], cgb[192], cbe[192], cgc[192];
    for (int i = tid; i < 192 * 9; i += 256) cw[i] = wdw[i];
    for (int i = tid; i < 192; i += 256) {
        cbd[i] = bdw[i];
        cgb[i] = g2[i] * BN_RSQ;
        cbe[i] = be2[i];
        cgc[i] = gate_c[b * 192 + i];
    }
    __syncthreads();
    const size_t outrow = (size_t)(b * Ln + h * Wn) * 192;
    for (int it = 0; it < 6; ++it) {
        int item = it * 256 + tid;          // 0..1535
        int w = whalf * 64 + item / 24;
        int c8 = item % 24;
        int co = c8 * 8;
        uint4 nb[3][3];
        #pragma unroll
        for (int r = 0; r < 3; ++r)
            #pragma unroll
            for (int d = 0; d < 3; ++d)
                nb[r][d] = make_uint4(0u, 0u, 0u, 0u);
        #pragma unroll
        for (int r = 0; r < 3; ++r) {
            int hh = h - 1 + r;
            if (hh < 0 || hh >= Hn) continue;
            const ushort_t* rp = fu_b + (size_t)(b * Ln + hh * Wn) * 192 + co;
            #pragma unroll
            for (int d = 0; d < 3; ++d) {
                int w2 = w - 1 + d;
                if (w2 < 0 || w2 >= Wn) continue;
                nb[r][d] = *(const uint4*)(rp + (size_t)w2 * 192);
            }
        }
        unsigned ou[4];
        #pragma unroll
        for (int i = 0; i < 8; ++i) {
            int c = co + i;
            float s = 0.0f;
            #pragma unroll
            for (int r = 0; r < 3; ++r) {
                #pragma unroll
                for (int d = 0; d < 3; ++d) {
                    unsigned word = ((const unsigned*)&nb[r][d])[i >> 1];
                    float v = __uint_as_float((i & 1) ? (word & 0xffff0000u)
                                                      : (word << 16));
                    s = fmaf(cw[c * 9 + r * 3 + d], v, s);
                }
            }
            float y = gelu_f((s + cbd[c]) * cgb[c] + cbe[c]) * cgc[c];
            if (i & 1) ou[i >> 1] |= (unsigned)f2bf(y) << 16;
            else       ou[i >> 1] = (unsigned)f2bf(y);
        }
        *(uint4*)(out2b + outrow + (size_t)w * 192 + co) =
            make_uint4(ou[0], ou[1], ou[2], ou[3]);
    }
}

extern "C" void kernel_launch(void* const* d_in, const int* in_sizes, int n_in,
                              void* d_out, int out_size, void* d_ws, size_t ws_size,
                              hipStream_t stream) {
    (void)in_sizes; (void)n_in; (void)out_size; (void)ws_size;
    const float* x      = (const float*)d_in[0];
    const float* w_qkv  = (const float*)d_in[1];
    const float* b_qkv  = (const float*)d_in[2];
    const float* w_dw1  = (const float*)d_in[3];
    const float* b_dw1  = (const float*)d_in[4];
    const float* g_bn1  = (const float*)d_in[5];
    const float* be_bn1 = (const float*)d_in[6];
    const float* w_si1  = (const float*)d_in[7];
    const float* b_si1  = (const float*)d_in[8];
    const float* g_si   = (const float*)d_in[9];
    const float* be_si  = (const float*)d_in[10];
    const float* w_si2  = (const float*)d_in[11];
    const float* b_si2  = (const float*)d_in[12];
    const float* w_ci1  = (const float*)d_in[13];
    const float* b_ci1  = (const float*)d_in[14];
    const float* g_ci   = (const float*)d_in[15];
    const float* be_ci  = (const float*)d_in[16];
    const float* w_ci2  = (const float*)d_in[17];
    const float* b_ci2  = (const float*)d_in[18];
    const float* w_dw2  = (const float*)d_in[19];
    const float* b_dw2  = (const float*)d_in[20];
    const float* g_bn2  = (const float*)d_in[21];
    const float* be_bn2 = (const float*)d_in[22];
    const float* w_proj = (const float*)d_in[23];
    const float* b_proj = (const float*)d_in[24];

    // ws (f32 units):
    //   phase A: conv1b bf16 [0, FUn/2)                  [conv1 -> spatial_gate]
    //   phase B: Qb [0, FUn/2), Kb [FUn/2, FUn) bf16     [qkv -> attn]
    //   phase C: out2b bf16 [8M, 8M+FUn/2)               [dwconv2 -> proj]
    //   smalls at FUn: gate_s, gate_c, pooled
    // d_out (shorts, 2*FUn total):
    //   xb [0, FUn) [cast -> qkv], then fu_b [0, FUn) [attn -> dwconv2]
    //   Vb [FUn, 2*FUn) [qkv -> attn]; proj overwrites all (f32).
    float* ws = (float*)d_ws;
    ushort_t* conv1b = (ushort_t*)ws;
    ushort_t* Qb     = (ushort_t*)ws;
    ushort_t* Kb     = (ushort_t*)(ws + FUn / 2);
    ushort_t* out2b  = (ushort_t*)(ws + 8000000);
    float* gate_s    = ws + FUn;                       // B*L
    float* gate_c    = gate_s + (size_t)Bn * Ln;       // B*192
    float* pooled    = gate_c + Bn * 192;              // B*192
    ushort_t* xb     = (ushort_t*)d_out;
    ushort_t* fu_b   = (ushort_t*)d_out;
    ushort_t* Vb     = (ushort_t*)d_out + FUn;

    conv1_k<<<Bn * 192, 256, 0, stream>>>(x, w_dw1, b_dw1, g_bn1, be_bn1, conv1b, pooled);
    spatial_gate_k<<<Bn * Hn, 128, 0, stream>>>(conv1b, w_si1, b_si1, g_si, be_si,
                                                w_si2, b_si2, gate_s);
    channel_gate_k<<<Bn, 192, 0, stream>>>(pooled, w_ci1, b_ci1, g_ci, be_ci,
                                           w_ci2, b_ci2, gate_c);
    cast_k<<<2048, 256, 0, stream>>>(x, xb);
    qkv_mfma<<<dim3(Mn / 128, 6), 256, 0, stream>>>(xb, w_qkv, b_qkv, Qb, Kb, Vb);
    attn_mfma<<<1536, 256, 0, stream>>>(Qb, Kb, Vb, gate_s, fu_b);
    dwconv2_k<<<Bn * Hn * 2, 256, 0, stream>>>(fu_b, gate_c,
                                               w_dw2, b_dw2, g_bn2, be_bn2, out2b);
    proj_mfma<<<dim3(Mn / 128, 2), 256, 0, stream>>>(out2b, w_proj, b_proj, (float*)d_out);
}

// Round 9
// 443.067 us; speedup vs baseline: 3.0175x; 1.0471x over previous
//
#include <hip/hip_runtime.h>

#define Bn 8
#define Hn 128
#define Wn 128
#define Cn 192
#define Ln (Hn*Wn)          // 16384
#define Mn (Bn*Ln)          // 131072
#define FUn ((size_t)Mn*Cn) // 25,165,824 floats
#define BN_RSQ 0.9999950000374997f   // 1/sqrt(1+1e-5)

typedef unsigned short ushort_t;
typedef __attribute__((ext_vector_type(8))) short short8;
typedef __attribute__((ext_vector_type(4))) float f32x4;
typedef __attribute__((ext_vector_type(4))) unsigned int uint4v;

static __device__ __forceinline__ float gelu_f(float x) {
    return 0.5f * x * (1.0f + erff(x * 0.7071067811865475f));
}
static __device__ __forceinline__ float gate1p(float x) {  // 1 + sigmoid(x)
    return 1.0f + 1.0f / (1.0f + __expf(-x));
}
static __device__ __forceinline__ unsigned short f2bf(float f) {  // RNE
    unsigned u = __float_as_uint(f);
    return (unsigned short)((u + 0x7FFFu + ((u >> 16) & 1u)) >> 16);
}
static __device__ __forceinline__ unsigned int pk2(float lo, float hi) {
    return (unsigned int)f2bf(lo) | ((unsigned int)f2bf(hi) << 16);
}
static __device__ __forceinline__ float bf2f(ushort_t u) {
    return __uint_as_float((unsigned)u << 16);
}

// ========== qkv GEMM (bf16 A; all 576 cols), writes Q/K/V parts ============
__global__ __launch_bounds__(256) void qkv_mfma(const ushort_t* __restrict__ Ab,
        const float* __restrict__ Bw, const float* __restrict__ bias,
        ushort_t* __restrict__ Qp, ushort_t* __restrict__ Kp,
        ushort_t* __restrict__ Vp)
{
    __shared__ __align__(16) ushort_t As[128 * 64];
    __shared__ __align__(16) ushort_t Bs[96 * 64];
    const int m0 = blockIdx.x * 128;
    const int n0g = blockIdx.y * 96;                  // 0..480
    const int part = n0g / 192;
    const int coln = n0g - part * 192;
    ushort_t* dst = part == 0 ? Qp : (part == 1 ? Kp : Vp);
    const int tid = threadIdx.x;
    const int lane = tid & 63;
    const int wrow = (tid >> 6) * 32;
    const int r0 = lane >> 4, cl = lane & 15;
    f32x4 acc[2][6] = {};

    for (int ks = 0; ks < 3; ++ks) {
        const int k0 = ks * 64;
        if (ks) __syncthreads();
        #pragma unroll
        for (int i = 0; i < 2; ++i) {
            int s = tid + i * 256;
            int row = s >> 2, q = s & 3;
            const ushort_t* src = Ab + (size_t)(m0 + row) * 192 + k0 + q * 16;
            uint4 u0 = *(const uint4*)(src);
            uint4 u1 = *(const uint4*)(src + 8);
            int r7 = row & 7;
            *(uint4*)&As[row * 64 + (((q * 2) ^ r7) * 8)] = u0;
            *(uint4*)&As[row * 64 + (((q * 2 + 1) ^ r7) * 8)] = u1;
        }
        #pragma unroll
        for (int i = 0; i < 3; ++i) {
            int f = tid + i * 256;                    // 0..767
            int col = f % 96, kslot = f / 96;
            uint4v wv;
            #pragma unroll
            for (int e2 = 0; e2 < 4; ++e2) {
                float lo = Bw[(size_t)(k0 + kslot * 8 + 2 * e2)     * 576 + n0g + col];
                float hi = Bw[(size_t)(k0 + kslot * 8 + 2 * e2 + 1) * 576 + n0g + col];
                wv[e2] = pk2(lo, hi);
            }
            *(uint4v*)&Bs[col * 64 + ((kslot ^ (col & 7)) * 8)] = wv;
        }
        __syncthreads();
        #pragma unroll
        for (int kk = 0; kk < 2; ++kk) {
            int kslot = kk * 4 + r0;
            int ra0 = wrow + cl, ra1 = wrow + 16 + cl;
            short8 a0 = *(const short8*)&As[ra0 * 64 + ((kslot ^ (ra0 & 7)) * 8)];
            short8 a1 = *(const short8*)&As[ra1 * 64 + ((kslot ^ (ra1 & 7)) * 8)];
            #pragma unroll
            for (int n = 0; n < 6; ++n) {
                int col = n * 16 + cl;
                short8 bn = *(const short8*)&Bs[col * 64 + ((kslot ^ (col & 7)) * 8)];
                acc[0][n] = __builtin_amdgcn_mfma_f32_16x16x32_bf16(a0, bn, acc[0][n], 0, 0, 0);
                acc[1][n] = __builtin_amdgcn_mfma_f32_16x16x32_bf16(a1, bn, acc[1][n], 0, 0, 0);
            }
        }
    }
    #pragma unroll
    for (int m = 0; m < 2; ++m) {
        #pragma unroll
        for (int n = 0; n < 6; ++n) {
            int col = n * 16 + cl;
            float bv = bias[n0g + col];
            #pragma unroll
            for (int j = 0; j < 4; ++j) {
                int row = m0 + wrow + m * 16 + r0 * 4 + j;
                dst[(size_t)row * 192 + coln + col] = f2bf(acc[m][n][j] + bv);
            }
        }
    }
}

// =================== proj GEMM: bf16 A (row-major) x f32 Bw -> f32 out ======
__global__ __launch_bounds__(256) void proj_mfma(const ushort_t* __restrict__ Ab,
        const float* __restrict__ Bw, const float* __restrict__ bias,
        float* __restrict__ Cout)
{
    __shared__ __align__(16) ushort_t As[128 * 64];
    __shared__ __align__(16) ushort_t Bs[96 * 64];
    const int m0 = blockIdx.x * 128;
    const int n0 = blockIdx.y * 96;
    const int tid = threadIdx.x;
    const int lane = tid & 63;
    const int wrow = (tid >> 6) * 32;
    const int r0 = lane >> 4, cl = lane & 15;
    f32x4 acc[2][6] = {};

    for (int ks = 0; ks < 3; ++ks) {
        const int k0 = ks * 64;
        if (ks) __syncthreads();
        #pragma unroll
        for (int i = 0; i < 2; ++i) {
            int s = tid + i * 256;
            int row = s >> 2, q = s & 3;
            const ushort_t* src = Ab + (size_t)(m0 + row) * 192 + k0 + q * 16;
            uint4 u0 = *(const uint4*)(src);
            uint4 u1 = *(const uint4*)(src + 8);
            int r7 = row & 7;
            *(uint4*)&As[row * 64 + (((q * 2) ^ r7) * 8)] = u0;
            *(uint4*)&As[row * 64 + (((q * 2 + 1) ^ r7) * 8)] = u1;
        }
        #pragma unroll
        for (int i = 0; i < 3; ++i) {
            int f = tid + i * 256;
            int col = f % 96, kslot = f / 96;
            uint4v wv;
            #pragma unroll
            for (int e2 = 0; e2 < 4; ++e2) {
                float lo = Bw[(size_t)(k0 + kslot * 8 + 2 * e2)     * 192 + n0 + col];
                float hi = Bw[(size_t)(k0 + kslot * 8 + 2 * e2 + 1) * 192 + n0 + col];
                wv[e2] = pk2(lo, hi);
            }
            *(uint4v*)&Bs[col * 64 + ((kslot ^ (col & 7)) * 8)] = wv;
        }
        __syncthreads();
        #pragma unroll
        for (int kk = 0; kk < 2; ++kk) {
            int kslot = kk * 4 + r0;
            int ra0 = wrow + cl, ra1 = wrow + 16 + cl;
            short8 a0 = *(const short8*)&As[ra0 * 64 + ((kslot ^ (ra0 & 7)) * 8)];
            short8 a1 = *(const short8*)&As[ra1 * 64 + ((kslot ^ (ra1 & 7)) * 8)];
            #pragma unroll
            for (int n = 0; n < 6; ++n) {
                int col = n * 16 + cl;
                short8 bn = *(const short8*)&Bs[col * 64 + ((kslot ^ (col & 7)) * 8)];
                acc[0][n] = __builtin_amdgcn_mfma_f32_16x16x32_bf16(a0, bn, acc[0][n], 0, 0, 0);
                acc[1][n] = __builtin_amdgcn_mfma_f32_16x16x32_bf16(a1, bn, acc[1][n], 0, 0, 0);
            }
        }
    }
    #pragma unroll
    for (int m = 0; m < 2; ++m) {
        #pragma unroll
        for (int n = 0; n < 6; ++n) {
            int col = n0 + n * 16 + cl;
            float bv = bias[col];
            #pragma unroll
            for (int j = 0; j < 4; ++j) {
                int row = m0 + wrow + m * 16 + r0 * 4 + j;
                Cout[(size_t)row * 192 + col] = acc[m][n][j] + bv;
            }
        }
    }
}

// ===== MFMA window attention, LDS-free, no barriers, gated bf16 output =====
__global__ __launch_bounds__(256) void attn_mfma(const ushort_t* __restrict__ Qb,
        const ushort_t* __restrict__ Kb, const ushort_t* __restrict__ Vb,
        const float* __restrict__ gate_s, ushort_t* __restrict__ fu_b)
{
    const int widx = threadIdx.x >> 6;
    const int idx = blockIdx.x * 4 + widx;          // 0..6143
    const int branch = (idx >= 3072) ? 1 : 0;
    const int sub = idx - branch * 3072;
    const int head = sub >> 10;
    const int b = (sub >> 7) & 7;
    const int win = sub & 127;
    const int L = threadIdx.x & 63;
    const int g = L >> 4, q = L & 15;
    int hb, wb;
    if (branch == 0) { hb = (win >> 3) * 8;  wb = (win & 7) * 16; }
    else             { hb = (win >> 4) * 16; wb = (win & 15) * 8; }
    const int cf = branch * 96 + head * 32;

    auto rowoff = [&](int t) -> size_t {
        int l = (branch == 0) ? (hb + (t >> 4)) * Wn + wb + (t & 15)
                              : (hb + (t >> 3)) * Wn + wb + (t & 7);
        return (size_t)(b * Ln + l) * 192;
    };

    short8 kf[8], qf[8];
    #pragma unroll
    for (int i = 0; i < 8; ++i) {
        size_t rb = rowoff(16 * i + q);
        qf[i] = *(const short8*)(Qb + rb + cf + 8 * g);
        kf[i] = *(const short8*)(Kb + rb + cf + 8 * g);
    }
    short8 vf[2][4];
    {
        size_t vrb[8];
        #pragma unroll
        for (int e = 0; e < 8; ++e)
            vrb[e] = rowoff(8 * g + e) + cf + q;
        const size_t sstep = (size_t)(branch == 0 ? 256 : 512) * 192;
        #pragma unroll
        for (int s = 0; s < 4; ++s) {
            #pragma unroll
            for (int dblk = 0; dblk < 2; ++dblk) {
                uint4v wv;
                #pragma unroll
                for (int e2 = 0; e2 < 4; ++e2) {
                    unsigned lo = Vb[vrb[2 * e2]     + s * sstep + 16 * dblk];
                    unsigned hi = Vb[vrb[2 * e2 + 1] + s * sstep + 16 * dblk];
                    wv[e2] = lo | (hi << 16);
                }
                vf[dblk][s] = *(short8*)&wv;
            }
        }
    }

    const float SC = 0.5303300858899106f;   // 3/sqrt(32)
    const int src0 = q + ((g & 1) << 5);
    const bool thi = (g >> 1) != 0;
    const bool glo = (g < 2);
    #pragma unroll
    for (int j = 0; j < 8; ++j) {
        unsigned wA[8], wB[8];
        float ss = 0.0f;
        #pragma unroll
        for (int i = 0; i < 8; ++i) {
            f32x4 z = {};
            f32x4 S = __builtin_amdgcn_mfma_f32_16x16x32_bf16(kf[i], qf[j], z, 0, 0, 0);
            float p0 = __expf(S[0] * SC), p1 = __expf(S[1] * SC);
            float p2 = __expf(S[2] * SC), p3 = __expf(S[3] * SC);
            ss += (p0 + p1) + (p2 + p3);
            wA[i] = pk2(p0, p1);
            wB[i] = pk2(p2, p3);
        }
        ss += __shfl_xor(ss, 16);
        ss += __shfl_xor(ss, 32);
        // own query pixel + fused gate scale (lane-uniform across the 4-lane column)
        int l_own;
        if (branch == 0) l_own = (hb + j) * Wn + wb + q;
        else             l_own = (hb + 2 * j + (q >> 3)) * Wn + wb + (q & 7);
        float s_own = 3.0f * gate_s[(size_t)b * Ln + l_own] / ss;

        f32x4 O0 = {}, O1 = {};
        #pragma unroll
        for (int s = 0; s < 4; ++s) {
            unsigned a0  = (unsigned)__shfl((int)wA[2*s],     src0);
            unsigned b0  = (unsigned)__shfl((int)wB[2*s],     src0);
            unsigned a0h = (unsigned)__shfl((int)wA[2*s],     src0 + 16);
            unsigned b0h = (unsigned)__shfl((int)wB[2*s],     src0 + 16);
            unsigned a1  = (unsigned)__shfl((int)wA[2*s+1],   src0);
            unsigned b1  = (unsigned)__shfl((int)wB[2*s+1],   src0);
            unsigned a1h = (unsigned)__shfl((int)wA[2*s+1],   src0 + 16);
            unsigned b1h = (unsigned)__shfl((int)wB[2*s+1],   src0 + 16);
            uint4v B2u;
            B2u[0] = thi ? a1  : a0;
            B2u[1] = thi ? b1  : b0;
            B2u[2] = thi ? a1h : a0h;
            B2u[3] = thi ? b1h : b0h;
            short8 B2 = *(short8*)&B2u;
            O0 = __builtin_amdgcn_mfma_f32_16x16x32_bf16(vf[0][s], B2, O0, 0, 0, 0);
            O1 = __builtin_amdgcn_mfma_f32_16x16x32_bf16(vf[1][s], B2, O1, 0, 0, 0);
        }
        // pack scaled O^T fragment to bf16, then 4-lane in-register transpose:
        // lane (g,q) ends with channels d = 8g..8g+7 of its own query.
        unsigned w0 = pk2(O0[0] * s_own, O0[1] * s_own);
        unsigned w1 = pk2(O0[2] * s_own, O0[3] * s_own);
        unsigned w2 = pk2(O1[0] * s_own, O1[1] * s_own);
        unsigned w3 = pk2(O1[2] * s_own, O1[3] * s_own);
        unsigned a0 = (unsigned)__shfl((int)w0, src0);
        unsigned a1 = (unsigned)__shfl((int)w1, src0);
        unsigned b0 = (unsigned)__shfl((int)w0, src0 + 16);
        unsigned b1 = (unsigned)__shfl((int)w1, src0 + 16);
        unsigned c0 = (unsigned)__shfl((int)w2, src0);
        unsigned c1 = (unsigned)__shfl((int)w3, src0);
        unsigned d0 = (unsigned)__shfl((int)w2, src0 + 16);
        unsigned d1 = (unsigned)__shfl((int)w3, src0 + 16);
        uint4 o = make_uint4(glo ? a0 : c0, glo ? a1 : c1,
                             glo ? b0 : d0, glo ? b1 : d1);
        *(uint4*)(fu_b + (size_t)(b * Ln + l_own) * 192 + cf + 8 * g) = o;
    }
}

// ---- conv1: dwconv3x3+BN+GELU per (b,c) plane + bf16 x-cast + pooled mean --
__global__ __launch_bounds__(256) void conv1_k(const float* __restrict__ x,
        const float* __restrict__ wdw, const float* __restrict__ bdw,
        const float* __restrict__ g1, const float* __restrict__ be1,
        ushort_t* __restrict__ conv1b, ushort_t* __restrict__ xb,
        float* __restrict__ pooled)
{
    int bc = blockIdx.x;                   // b*192 + c
    int c = bc % 192;
    const float* plane = x + (size_t)bc * Ln;
    ushort_t* oplane = conv1b + (size_t)bc * Ln;
    ushort_t* xplane = xb + (size_t)bc * Ln;
    int t = threadIdx.x;
    int sx = t & 31, sy = t >> 5;          // 32 strips x 8 bands
    int w0 = sx * 4, h0 = sy * 16;
    float wk[9];
    #pragma unroll
    for (int i = 0; i < 9; ++i) wk[i] = wdw[c * 9 + i];
    float gb = g1[c] * BN_RSQ, bb = be1[c], bd = bdw[c];

    float rA[6], rB[6], rC[6];
    auto load6 = [&](int h, float* r) {
        if (h < 0 || h >= Hn) {
            r[0] = r[1] = r[2] = r[3] = r[4] = r[5] = 0.0f;
            return;
        }
        const float* rp = plane + h * Wn;
        float4 m = *(const float4*)(rp + w0);
        r[0] = sx ? rp[w0 - 1] : 0.0f;
        r[1] = m.x; r[2] = m.y; r[3] = m.z; r[4] = m.w;
        r[5] = (sx < 31) ? rp[w0 + 4] : 0.0f;
    };
    load6(h0 - 1, rA);
    load6(h0, rB);
    float psum = 0.0f;
    #pragma unroll
    for (int i = 0; i < 16; ++i) {
        int h = h0 + i;
        load6(h + 1, rC);
        // bf16 cast of the center row (raw x)
        *(uint2*)(xplane + h * Wn + w0) =
            make_uint2(pk2(rB[1], rB[2]), pk2(rB[3], rB[4]));
        float o[4];
        #pragma unroll
        for (int p = 0; p < 4; ++p) {
            float s = wk[0] * rA[p];
            s = fmaf(wk[1], rA[p + 1], s);
            s = fmaf(wk[2], rA[p + 2], s);
            s = fmaf(wk[3], rB[p],     s);
            s = fmaf(wk[4], rB[p + 1], s);
            s = fmaf(wk[5], rB[p + 2], s);
            s = fmaf(wk[6], rC[p],     s);
            s = fmaf(wk[7], rC[p + 1], s);
            s = fmaf(wk[8], rC[p + 2], s);
            float y = gelu_f((s + bd) * gb + bb);
            psum += y;
            o[p] = y;
        }
        uint2 ow = make_uint2(pk2(o[0], o[1]), pk2(o[2], o[3]));
        *(uint2*)(oplane + h * Wn + w0) = ow;
        #pragma unroll
        for (int q2 = 0; q2 < 6; ++q2) { rA[q2] = rB[q2]; rB[q2] = rC[q2]; }
    }
    __shared__ float red[4];
    for (int off = 32; off; off >>= 1) psum += __shfl_down(psum, off);
    if ((t & 63) == 0) red[t >> 6] = psum;
    __syncthreads();
    if (t == 0)
        pooled[bc] = (red[0] + red[1] + red[2] + red[3]) * (1.0f / Ln);
}

// ------- spatial gate: per-pixel 192->24->1 MLP on bf16 conv1 ---------------
__global__ __launch_bounds__(128) void spatial_gate_k(const ushort_t* __restrict__ conv1b,
        const float* __restrict__ ws1g, const float* __restrict__ bs1,
        const float* __restrict__ gsi, const float* __restrict__ besi,
        const float* __restrict__ ws2, const float* __restrict__ bs2,
        float* __restrict__ gate_s)
{
    int bh = blockIdx.x;                   // b*128 + h
    int b = bh >> 7, h = bh & 127;
    int w = threadIdx.x;
    __shared__ float ws1T[192 * 24];       // [c][o]
    for (int i = w; i < 192 * 24; i += 128) {
        int c = i / 24, o = i - c * 24;
        ws1T[i] = ws1g[o * 192 + c];
    }
    __syncthreads();
    float acc24[24] = {};
    const ushort_t* base = conv1b + (size_t)b * 192 * Ln + h * Wn + w;
    #pragma unroll 4
    for (int c = 0; c < 192; ++c) {
        float v = bf2f(base[(size_t)c * Ln]);
        const float4* wp = (const float4*)&ws1T[c * 24];
        #pragma unroll
        for (int o4 = 0; o4 < 6; ++o4) {
            float4 wv = wp[o4];
            acc24[o4*4+0] = fmaf(v, wv.x, acc24[o4*4+0]);
            acc24[o4*4+1] = fmaf(v, wv.y, acc24[o4*4+1]);
            acc24[o4*4+2] = fmaf(v, wv.z, acc24[o4*4+2]);
            acc24[o4*4+3] = fmaf(v, wv.w, acc24[o4*4+3]);
        }
    }
    float s2 = bs2[0];
    #pragma unroll
    for (int o = 0; o < 24; ++o)
        s2 = fmaf(gelu_f((acc24[o] + bs1[o]) * (gsi[o] * BN_RSQ) + besi[o]), ws2[o], s2);
    gate_s[(size_t)bh * 128 + w] = gate1p(s2);
}

// ---------------- channel gate: 192->24->192 MLP on pooled ------------------
__global__ __launch_bounds__(192) void channel_gate_k(const float* __restrict__ pooled,
        const float* __restrict__ w1, const float* __restrict__ b1,
        const float* __restrict__ g, const float* __restrict__ be,
        const float* __restrict__ w2, const float* __restrict__ b2,
        float* __restrict__ gate_c)
{
    int b = blockIdx.x, t = threadIdx.x;
    __shared__ float pl[192];
    __shared__ float h1[24];
    pl[t] = pooled[b * 192 + t];
    __syncthreads();
    if (t < 24) {
        float a = b1[t];
        for (int c = 0; c < 192; ++c) a = fmaf(pl[c], w1[t * 192 + c], a);
        a = a * (g[t] * BN_RSQ) + be[t];
        h1[t] = gelu_f(a);
    }
    __syncthreads();
    float a = b2[t];
    #pragma unroll
    for (int o = 0; o < 24; ++o) a = fmaf(h1[o], w2[t * 24 + o], a);
    gate_c[b * 192 + t] = gate1p(a);
}

// ---- dwconv2: channels-last register 3x3 stencil on gated bf16 fu ----------
__global__ __launch_bounds__(256) void dwconv2_k(const ushort_t* __restrict__ fu_b,
        const float* __restrict__ gate_c,
        const float* __restrict__ wdw, const float* __restrict__ bdw,
        const float* __restrict__ g2, const float* __restrict__ be2,
        ushort_t* __restrict__ out2b)
{
    int bh = blockIdx.x >> 1;              // b*128 + h
    int whalf = blockIdx.x & 1;
    int b = bh >> 7, h = bh & 127;
    int tid = threadIdx.x;
    __shared__ float cw[192 * 9];
    __shared__ float cbd[192], cgb[192], cbe[192], cgc[192];
    for (int i = tid; i < 192 * 9; i += 256) cw[i] = wdw[i];
    for (int i = tid; i < 192; i += 256) {
        cbd[i] = bdw[i];
        cgb[i] = g2[i] * BN_RSQ;
        cbe[i] = be2[i];
        cgc[i] = gate_c[b * 192 + i];
    }
    __syncthreads();
    const size_t outrow = (size_t)(b * Ln + h * Wn) * 192;
    for (int it = 0; it < 6; ++it) {
        int item = it * 256 + tid;          // 0..1535
        int w = whalf * 64 + item / 24;
        int c8 = item % 24;
        int co = c8 * 8;
        uint4 nb[3][3];
        #pragma unroll
        for (int r = 0; r < 3; ++r)
            #pragma unroll
            for (int d = 0; d < 3; ++d)
                nb[r][d] = make_uint4(0u, 0u, 0u, 0u);
        #pragma unroll
        for (int r = 0; r < 3; ++r) {
            int hh = h - 1 + r;
            if (hh < 0 || hh >= Hn) continue;
            const ushort_t* rp = fu_b + (size_t)(b * Ln + hh * Wn) * 192 + co;
            #pragma unroll
            for (int d = 0; d < 3; ++d) {
                int w2 = w - 1 + d;
                if (w2 < 0 || w2 >= Wn) continue;
                nb[r][d] = *(const uint4*)(rp + (size_t)w2 * 192);
            }
        }
        unsigned ou[4];
        #pragma unroll
        for (int i = 0; i < 8; ++i) {
            int c = co + i;
            float s = 0.0f;
            #pragma unroll
            for (int r = 0; r < 3; ++r) {
                #pragma unroll
                for (int d = 0; d < 3; ++d) {
                    unsigned word = ((const unsigned*)&nb[r][d])[i >> 1];
                    float v = __uint_as_float((i & 1) ? (word & 0xffff0000u)
                                                      : (word << 16));
                    s = fmaf(cw[c * 9 + r * 3 + d], v, s);
                }
            }
            float y = gelu_f((s + cbd[c]) * cgb[c] + cbe[c]) * cgc[c];
            if (i & 1) ou[i >> 1] |= (unsigned)f2bf(y) << 16;
            else       ou[i >> 1] = (unsigned)f2bf(y);
        }
        *(uint4*)(out2b + outrow + (size_t)w * 192 + co) =
            make_uint4(ou[0], ou[1], ou[2], ou[3]);
    }
}

extern "C" void kernel_launch(void* const* d_in, const int* in_sizes, int n_in,
                              void* d_out, int out_size, void* d_ws, size_t ws_size,
                              hipStream_t stream) {
    (void)in_sizes; (void)n_in; (void)out_size; (void)ws_size;
    const float* x      = (const float*)d_in[0];
    const float* w_qkv  = (const float*)d_in[1];
    const float* b_qkv  = (const float*)d_in[2];
    const float* w_dw1  = (const float*)d_in[3];
    const float* b_dw1  = (const float*)d_in[4];
    const float* g_bn1  = (const float*)d_in[5];
    const float* be_bn1 = (const float*)d_in[6];
    const float* w_si1  = (const float*)d_in[7];
    const float* b_si1  = (const float*)d_in[8];
    const float* g_si   = (const float*)d_in[9];
    const float* be_si  = (const float*)d_in[10];
    const float* w_si2  = (const float*)d_in[11];
    const float* b_si2  = (const float*)d_in[12];
    const float* w_ci1  = (const float*)d_in[13];
    const float* b_ci1  = (const float*)d_in[14];
    const float* g_ci   = (const float*)d_in[15];
    const float* be_ci  = (const float*)d_in[16];
    const float* w_ci2  = (const float*)d_in[17];
    const float* b_ci2  = (const float*)d_in[18];
    const float* w_dw2  = (const float*)d_in[19];
    const float* b_dw2  = (const float*)d_in[20];
    const float* g_bn2  = (const float*)d_in[21];
    const float* be_bn2 = (const float*)d_in[22];
    const float* w_proj = (const float*)d_in[23];
    const float* b_proj = (const float*)d_in[24];

    // ws (f32 units):
    //   phase A: conv1b bf16 [0, FUn/2)                  [conv1 -> spatial_gate]
    //   phase B: Qb [0, FUn/2), Kb [FUn/2, FUn) bf16     [qkv -> attn]
    //   phase C: out2b bf16 [8M, 8M+FUn/2)               [dwconv2 -> proj]
    //   smalls at FUn: gate_s, gate_c, pooled
    // d_out (shorts, 2*FUn total):
    //   xb [0, FUn) [conv1 -> qkv], then fu_b [0, FUn) [attn -> dwconv2]
    //   Vb [FUn, 2*FUn) [qkv -> attn]; proj overwrites all (f32).
    float* ws = (float*)d_ws;
    ushort_t* conv1b = (ushort_t*)ws;
    ushort_t* Qb     = (ushort_t*)ws;
    ushort_t* Kb     = (ushort_t*)(ws + FUn / 2);
    ushort_t* out2b  = (ushort_t*)(ws + 8000000);
    float* gate_s    = ws + FUn;                       // B*L
    float* gate_c    = gate_s + (size_t)Bn * Ln;       // B*192
    float* pooled    = gate_c + Bn * 192;              // B*192
    ushort_t* xb     = (ushort_t*)d_out;
    ushort_t* fu_b   = (ushort_t*)d_out;
    ushort_t* Vb     = (ushort_t*)d_out + FUn;

    conv1_k<<<Bn * 192, 256, 0, stream>>>(x, w_dw1, b_dw1, g_bn1, be_bn1,
                                          conv1b, xb, pooled);
    spatial_gate_k<<<Bn * Hn, 128, 0, stream>>>(conv1b, w_si1, b_si1, g_si, be_si,
                                                w_si2, b_si2, gate_s);
    channel_gate_k<<<Bn, 192, 0, stream>>>(pooled, w_ci1, b_ci1, g_ci, be_ci,
                                           w_ci2, b_ci2, gate_c);
    qkv_mfma<<<dim3(Mn / 128, 6), 256, 0, stream>>>(xb, w_qkv, b_qkv, Qb, Kb, Vb);
    attn_mfma<<<1536, 256, 0, stream>>>(Qb, Kb, Vb, gate_s, fu_b);
    dwconv2_k<<<Bn * Hn * 2, 256, 0, stream>>>(fu_b, gate_c,
                                               w_dw2, b_dw2, g_bn2, be_bn2, out2b);
    proj_mfma<<<dim3(Mn / 128, 2), 256, 0, stream>>>(out2b, w_proj, b_proj, (float*)d_out);
}

// Round 10
// 441.291 us; speedup vs baseline: 3.0297x; 1.0040x over previous
//
#include <hip/hip_runtime.h>

#define Bn 8
#define Hn 128
#define Wn 128
#define Cn 192
#define Ln (Hn*Wn)          // 16384
#define Mn (Bn*Ln)          // 131072
#define FUn ((size_t)Mn*Cn) // 25,165,824 floats
#define BANKn ((size_t)Mn*96) // shorts per branch-bank
#define BN_RSQ 0.9999950000374997f   // 1/sqrt(1+1e-5)

typedef unsigned short ushort_t;
typedef __attribute__((ext_vector_type(8))) short short8;
typedef __attribute__((ext_vector_type(4))) float f32x4;
typedef __attribute__((ext_vector_type(4))) unsigned int uint4v;

static __device__ __forceinline__ float gelu_f(float x) {
    return 0.5f * x * (1.0f + erff(x * 0.7071067811865475f));
}
static __device__ __forceinline__ float gate1p(float x) {  // 1 + sigmoid(x)
    return 1.0f + 1.0f / (1.0f + __expf(-x));
}
static __device__ __forceinline__ unsigned short f2bf(float f) {  // RNE
    unsigned u = __float_as_uint(f);
    return (unsigned short)((u + 0x7FFFu + ((u >> 16) & 1u)) >> 16);
}
static __device__ __forceinline__ unsigned int pk2(float lo, float hi) {
    return (unsigned int)f2bf(lo) | ((unsigned int)f2bf(hi) << 16);
}
static __device__ __forceinline__ float bf2f(ushort_t u) {
    return __uint_as_float((unsigned)u << 16);
}

// ========== qkv GEMM (bf16 A; all 576 cols) -> window-contiguous Q/K/V =====
// Each part (Q/K/V) stored as 2 banks (one per attn branch, 96 ch each):
//   bank[br][((b*128 + win)*128 + t)*96 + ch]
__global__ __launch_bounds__(256) void qkv_mfma(const ushort_t* __restrict__ Ab,
        const float* __restrict__ Bw, const float* __restrict__ bias,
        ushort_t* __restrict__ Qp, ushort_t* __restrict__ Kp,
        ushort_t* __restrict__ Vp)
{
    __shared__ __align__(16) ushort_t As[128 * 64];
    __shared__ __align__(16) ushort_t Bs[96 * 64];
    const int m0 = blockIdx.x * 128;
    const int n0g = blockIdx.y * 96;                  // 0..480
    const int part = n0g / 192;
    const int coln = n0g - part * 192;                // 0 or 96 (block-uniform)
    ushort_t* dst = part == 0 ? Qp : (part == 1 ? Kp : Vp);
    ushort_t* bptr = dst + (coln ? BANKn : 0);
    const int tid = threadIdx.x;
    const int lane = tid & 63;
    const int wrow = (tid >> 6) * 32;
    const int r0 = lane >> 4, cl = lane & 15;
    f32x4 acc[2][6] = {};

    for (int ks = 0; ks < 3; ++ks) {
        const int k0 = ks * 64;
        if (ks) __syncthreads();
        #pragma unroll
        for (int i = 0; i < 2; ++i) {
            int s = tid + i * 256;
            int row = s >> 2, q = s & 3;
            const ushort_t* src = Ab + (size_t)(m0 + row) * 192 + k0 + q * 16;
            uint4 u0 = *(const uint4*)(src);
            uint4 u1 = *(const uint4*)(src + 8);
            int r7 = row & 7;
            *(uint4*)&As[row * 64 + (((q * 2) ^ r7) * 8)] = u0;
            *(uint4*)&As[row * 64 + (((q * 2 + 1) ^ r7) * 8)] = u1;
        }
        #pragma unroll
        for (int i = 0; i < 3; ++i) {
            int f = tid + i * 256;                    // 0..767
            int col = f % 96, kslot = f / 96;
            uint4v wv;
            #pragma unroll
            for (int e2 = 0; e2 < 4; ++e2) {
                float lo = Bw[(size_t)(k0 + kslot * 8 + 2 * e2)     * 576 + n0g + col];
                float hi = Bw[(size_t)(k0 + kslot * 8 + 2 * e2 + 1) * 576 + n0g + col];
                wv[e2] = pk2(lo, hi);
            }
            *(uint4v*)&Bs[col * 64 + ((kslot ^ (col & 7)) * 8)] = wv;
        }
        __syncthreads();
        #pragma unroll
        for (int kk = 0; kk < 2; ++kk) {
            int kslot = kk * 4 + r0;
            int ra0 = wrow + cl, ra1 = wrow + 16 + cl;
            short8 a0 = *(const short8*)&As[ra0 * 64 + ((kslot ^ (ra0 & 7)) * 8)];
            short8 a1 = *(const short8*)&As[ra1 * 64 + ((kslot ^ (ra1 & 7)) * 8)];
            #pragma unroll
            for (int n = 0; n < 6; ++n) {
                int col = n * 16 + cl;
                short8 bn = *(const short8*)&Bs[col * 64 + ((kslot ^ (col & 7)) * 8)];
                acc[0][n] = __builtin_amdgcn_mfma_f32_16x16x32_bf16(a0, bn, acc[0][n], 0, 0, 0);
                acc[1][n] = __builtin_amdgcn_mfma_f32_16x16x32_bf16(a1, bn, acc[1][n], 0, 0, 0);
            }
        }
    }
    float bv[6];
    #pragma unroll
    for (int n = 0; n < 6; ++n) bv[n] = bias[n0g + n * 16 + cl];
    #pragma unroll
    for (int m = 0; m < 2; ++m) {
        #pragma unroll
        for (int j = 0; j < 4; ++j) {
            int row = m0 + wrow + m * 16 + r0 * 4 + j;
            int b = row >> 14, l = row & 16383;
            int h = l >> 7, w = l & 127;
            int win, t;
            if (coln == 0) { win = (h >> 3) * 8 + (w >> 4);  t = (h & 7) * 16 + (w & 15); }
            else           { win = (h >> 4) * 16 + (w >> 3); t = (h & 15) * 8 + (w & 7); }
            size_t rbase = ((size_t)((b * 128 + win) * 128 + t)) * 96;
            #pragma unroll
            for (int n = 0; n < 6; ++n)
                bptr[rbase + n * 16 + cl] = f2bf(acc[m][n][j] + bv[n]);
        }
    }
}

// =================== proj GEMM: bf16 A (row-major) x f32 Bw -> f32 out ======
__global__ __launch_bounds__(256) void proj_mfma(const ushort_t* __restrict__ Ab,
        const float* __restrict__ Bw, const float* __restrict__ bias,
        float* __restrict__ Cout)
{
    __shared__ __align__(16) ushort_t As[128 * 64];
    __shared__ __align__(16) ushort_t Bs[96 * 64];
    const int m0 = blockIdx.x * 128;
    const int n0 = blockIdx.y * 96;
    const int tid = threadIdx.x;
    const int lane = tid & 63;
    const int wrow = (tid >> 6) * 32;
    const int r0 = lane >> 4, cl = lane & 15;
    f32x4 acc[2][6] = {};

    for (int ks = 0; ks < 3; ++ks) {
        const int k0 = ks * 64;
        if (ks) __syncthreads();
        #pragma unroll
        for (int i = 0; i < 2; ++i) {
            int s = tid + i * 256;
            int row = s >> 2, q = s & 3;
            const ushort_t* src = Ab + (size_t)(m0 + row) * 192 + k0 + q * 16;
            uint4 u0 = *(const uint4*)(src);
            uint4 u1 = *(const uint4*)(src + 8);
            int r7 = row & 7;
            *(uint4*)&As[row * 64 + (((q * 2) ^ r7) * 8)] = u0;
            *(uint4*)&As[row * 64 + (((q * 2 + 1) ^ r7) * 8)] = u1;
        }
        #pragma unroll
        for (int i = 0; i < 3; ++i) {
            int f = tid + i * 256;
            int col = f % 96, kslot = f / 96;
            uint4v wv;
            #pragma unroll
            for (int e2 = 0; e2 < 4; ++e2) {
                float lo = Bw[(size_t)(k0 + kslot * 8 + 2 * e2)     * 192 + n0 + col];
                float hi = Bw[(size_t)(k0 + kslot * 8 + 2 * e2 + 1) * 192 + n0 + col];
                wv[e2] = pk2(lo, hi);
            }
            *(uint4v*)&Bs[col * 64 + ((kslot ^ (col & 7)) * 8)] = wv;
        }
        __syncthreads();
        #pragma unroll
        for (int kk = 0; kk < 2; ++kk) {
            int kslot = kk * 4 + r0;
            int ra0 = wrow + cl, ra1 = wrow + 16 + cl;
            short8 a0 = *(const short8*)&As[ra0 * 64 + ((kslot ^ (ra0 & 7)) * 8)];
            short8 a1 = *(const short8*)&As[ra1 * 64 + ((kslot ^ (ra1 & 7)) * 8)];
            #pragma unroll
            for (int n = 0; n < 6; ++n) {
                int col = n * 16 + cl;
                short8 bn = *(const short8*)&Bs[col * 64 + ((kslot ^ (col & 7)) * 8)];
                acc[0][n] = __builtin_amdgcn_mfma_f32_16x16x32_bf16(a0, bn, acc[0][n], 0, 0, 0);
                acc[1][n] = __builtin_amdgcn_mfma_f32_16x16x32_bf16(a1, bn, acc[1][n], 0, 0, 0);
            }
        }
    }
    #pragma unroll
    for (int m = 0; m < 2; ++m) {
        #pragma unroll
        for (int n = 0; n < 6; ++n) {
            int col = n0 + n * 16 + cl;
            float bv = bias[col];
            #pragma unroll
            for (int j = 0; j < 4; ++j) {
                int row = m0 + wrow + m * 16 + r0 * 4 + j;
                Cout[(size_t)row * 192 + col] = acc[m][n][j] + bv;
            }
        }
    }
}

// ===== MFMA window attention on window-contiguous Q/K/V, LDS/barrier-free ===
__global__ __launch_bounds__(256) void attn_mfma(const ushort_t* __restrict__ Qp,
        const ushort_t* __restrict__ Kp, const ushort_t* __restrict__ Vp,
        const float* __restrict__ gate_s, ushort_t* __restrict__ fu_b)
{
    const int widx = threadIdx.x >> 6;
    const int idx = blockIdx.x * 4 + widx;          // 0..6143
    const int branch = (idx >= 3072) ? 1 : 0;
    const int sub = idx - branch * 3072;
    const int head = sub >> 10;
    const int b = (sub >> 7) & 7;
    const int win = sub & 127;
    const int L = threadIdx.x & 63;
    const int g = L >> 4, q = L & 15;
    int hb, wb;
    if (branch == 0) { hb = (win >> 3) * 8;  wb = (win & 7) * 16; }
    else             { hb = (win >> 4) * 16; wb = (win & 15) * 8; }
    const int cf = branch * 96 + head * 32;         // fu channel base
    const int hch = head * 32;                      // in-bank channel base

    const size_t bank = branch ? BANKn : 0;
    const size_t wbase = ((size_t)((b * 128 + win) * 128)) * 96;
    const ushort_t* Qw = Qp + bank + wbase;
    const ushort_t* Kw = Kp + bank + wbase;
    const ushort_t* Vw = Vp + bank + wbase;

    short8 kf[8], qf[8];
    #pragma unroll
    for (int i = 0; i < 8; ++i) {
        size_t off = (size_t)(16 * i + q) * 96 + hch + 8 * g;
        qf[i] = *(const short8*)(Qw + off);
        kf[i] = *(const short8*)(Kw + off);
    }
    short8 vf[2][4];
    {
        #pragma unroll
        for (int s = 0; s < 4; ++s) {
            #pragma unroll
            for (int dblk = 0; dblk < 2; ++dblk) {
                uint4v wv;
                #pragma unroll
                for (int e2 = 0; e2 < 4; ++e2) {
                    size_t base = (size_t)(32 * s + 8 * g + 2 * e2) * 96 + hch + 16 * dblk + q;
                    unsigned lo = Vw[base];
                    unsigned hi = Vw[base + 96];
                    wv[e2] = lo | (hi << 16);
                }
                vf[dblk][s] = *(short8*)&wv;
            }
        }
    }

    const float SC = 0.5303300858899106f;   // 3/sqrt(32)
    const int src0 = q + ((g & 1) << 5);
    const bool thi = (g >> 1) != 0;
    const bool glo = (g < 2);
    #pragma unroll
    for (int j = 0; j < 8; ++j) {
        unsigned wA[8], wB[8];
        float ss = 0.0f;
        #pragma unroll
        for (int i = 0; i < 8; ++i) {
            f32x4 z = {};
            f32x4 S = __builtin_amdgcn_mfma_f32_16x16x32_bf16(kf[i], qf[j], z, 0, 0, 0);
            float p0 = __expf(S[0] * SC), p1 = __expf(S[1] * SC);
            float p2 = __expf(S[2] * SC), p3 = __expf(S[3] * SC);
            ss += (p0 + p1) + (p2 + p3);
            wA[i] = pk2(p0, p1);
            wB[i] = pk2(p2, p3);
        }
        ss += __shfl_xor(ss, 16);
        ss += __shfl_xor(ss, 32);
        int l_own;
        if (branch == 0) l_own = (hb + j) * Wn + wb + q;
        else             l_own = (hb + 2 * j + (q >> 3)) * Wn + wb + (q & 7);
        float s_own = 3.0f * gate_s[(size_t)b * Ln + l_own] / ss;

        f32x4 O0 = {}, O1 = {};
        #pragma unroll
        for (int s = 0; s < 4; ++s) {
            unsigned a0  = (unsigned)__shfl((int)wA[2*s],     src0);
            unsigned b0  = (unsigned)__shfl((int)wB[2*s],     src0);
            unsigned a0h = (unsigned)__shfl((int)wA[2*s],     src0 + 16);
            unsigned b0h = (unsigned)__shfl((int)wB[2*s],     src0 + 16);
            unsigned a1  = (unsigned)__shfl((int)wA[2*s+1],   src0);
            unsigned b1  = (unsigned)__shfl((int)wB[2*s+1],   src0);
            unsigned a1h = (unsigned)__shfl((int)wA[2*s+1],   src0 + 16);
            unsigned b1h = (unsigned)__shfl((int)wB[2*s+1],   src0 + 16);
            uint4v B2u;
            B2u[0] = thi ? a1  : a0;
            B2u[1] = thi ? b1  : b0;
            B2u[2] = thi ? a1h : a0h;
            B2u[3] = thi ? b1h : b0h;
            short8 B2 = *(short8*)&B2u;
            O0 = __builtin_amdgcn_mfma_f32_16x16x32_bf16(vf[0][s], B2, O0, 0, 0, 0);
            O1 = __builtin_amdgcn_mfma_f32_16x16x32_bf16(vf[1][s], B2, O1, 0, 0, 0);
        }
        unsigned w0 = pk2(O0[0] * s_own, O0[1] * s_own);
        unsigned w1 = pk2(O0[2] * s_own, O0[3] * s_own);
        unsigned w2 = pk2(O1[0] * s_own, O1[1] * s_own);
        unsigned w3 = pk2(O1[2] * s_own, O1[3] * s_own);
        unsigned a0 = (unsigned)__shfl((int)w0, src0);
        unsigned a1 = (unsigned)__shfl((int)w1, src0);
        unsigned b0 = (unsigned)__shfl((int)w0, src0 + 16);
        unsigned b1 = (unsigned)__shfl((int)w1, src0 + 16);
        unsigned c0 = (unsigned)__shfl((int)w2, src0);
        unsigned c1 = (unsigned)__shfl((int)w3, src0);
        unsigned d0 = (unsigned)__shfl((int)w2, src0 + 16);
        unsigned d1 = (unsigned)__shfl((int)w3, src0 + 16);
        uint4 o = make_uint4(glo ? a0 : c0, glo ? a1 : c1,
                             glo ? b0 : d0, glo ? b1 : d1);
        *(uint4*)(fu_b + (size_t)(b * Ln + l_own) * 192 + cf + 8 * g) = o;
    }
}

// ---- conv1: dwconv3x3+BN+GELU per (b,c) plane + bf16 x-cast + pooled mean --
__global__ __launch_bounds__(256) void conv1_k(const float* __restrict__ x,
        const float* __restrict__ wdw, const float* __restrict__ bdw,
        const float* __restrict__ g1, const float* __restrict__ be1,
        ushort_t* __restrict__ conv1b, ushort_t* __restrict__ xb,
        float* __restrict__ pooled)
{
    int bc = blockIdx.x;                   // b*192 + c
    int c = bc % 192;
    const float* plane = x + (size_t)bc * Ln;
    ushort_t* oplane = conv1b + (size_t)bc * Ln;
    ushort_t* xplane = xb + (size_t)bc * Ln;
    int t = threadIdx.x;
    int sx = t & 31, sy = t >> 5;          // 32 strips x 8 bands
    int w0 = sx * 4, h0 = sy * 16;
    float wk[9];
    #pragma unroll
    for (int i = 0; i < 9; ++i) wk[i] = wdw[c * 9 + i];
    float gb = g1[c] * BN_RSQ, bb = be1[c], bd = bdw[c];

    float rA[6], rB[6], rC[6];
    auto load6 = [&](int h, float* r) {
        if (h < 0 || h >= Hn) {
            r[0] = r[1] = r[2] = r[3] = r[4] = r[5] = 0.0f;
            return;
        }
        const float* rp = plane + h * Wn;
        float4 m = *(const float4*)(rp + w0);
        r[0] = sx ? rp[w0 - 1] : 0.0f;
        r[1] = m.x; r[2] = m.y; r[3] = m.z; r[4] = m.w;
        r[5] = (sx < 31) ? rp[w0 + 4] : 0.0f;
    };
    load6(h0 - 1, rA);
    load6(h0, rB);
    float psum = 0.0f;
    #pragma unroll
    for (int i = 0; i < 16; ++i) {
        int h = h0 + i;
        load6(h + 1, rC);
        *(uint2*)(xplane + h * Wn + w0) =
            make_uint2(pk2(rB[1], rB[2]), pk2(rB[3], rB[4]));
        float o[4];
        #pragma unroll
        for (int p = 0; p < 4; ++p) {
            float s = wk[0] * rA[p];
            s = fmaf(wk[1], rA[p + 1], s);
            s = fmaf(wk[2], rA[p + 2], s);
            s = fmaf(wk[3], rB[p],     s);
            s = fmaf(wk[4], rB[p + 1], s);
            s = fmaf(wk[5], rB[p + 2], s);
            s = fmaf(wk[6], rC[p],     s);
            s = fmaf(wk[7], rC[p + 1], s);
            s = fmaf(wk[8], rC[p + 2], s);
            float y = gelu_f((s + bd) * gb + bb);
            psum += y;
            o[p] = y;
        }
        uint2 ow = make_uint2(pk2(o[0], o[1]), pk2(o[2], o[3]));
        *(uint2*)(oplane + h * Wn + w0) = ow;
        #pragma unroll
        for (int q2 = 0; q2 < 6; ++q2) { rA[q2] = rB[q2]; rB[q2] = rC[q2]; }
    }
    __shared__ float red[4];
    for (int off = 32; off; off >>= 1) psum += __shfl_down(psum, off);
    if ((t & 63) == 0) red[t >> 6] = psum;
    __syncthreads();
    if (t == 0)
        pooled[bc] = (red[0] + red[1] + red[2] + red[3]) * (1.0f / Ln);
}

// ------- spatial gate: per-pixel 192->24->1 MLP on bf16 conv1 ---------------
__global__ __launch_bounds__(128) void spatial_gate_k(const ushort_t* __restrict__ conv1b,
        const float* __restrict__ ws1g, const float* __restrict__ bs1,
        const float* __restrict__ gsi, const float* __restrict__ besi,
        const float* __restrict__ ws2, const float* __restrict__ bs2,
        float* __restrict__ gate_s)
{
    int bh = blockIdx.x;                   // b*128 + h
    int b = bh >> 7, h = bh & 127;
    int w = threadIdx.x;
    __shared__ float ws1T[192 * 24];       // [c][o]
    for (int i = w; i < 192 * 24; i += 128) {
        int c = i / 24, o = i - c * 24;
        ws1T[i] = ws1g[o * 192 + c];
    }
    __syncthreads();
    float acc24[24] = {};
    const ushort_t* base = conv1b + (size_t)b * 192 * Ln + h * Wn + w;
    #pragma unroll 4
    for (int c = 0; c < 192; ++c) {
        float v = bf2f(base[(size_t)c * Ln]);
        const float4* wp = (const float4*)&ws1T[c * 24];
        #pragma unroll
        for (int o4 = 0; o4 < 6; ++o4) {
            float4 wv = wp[o4];
            acc24[o4*4+0] = fmaf(v, wv.x, acc24[o4*4+0]);
            acc24[o4*4+1] = fmaf(v, wv.y, acc24[o4*4+1]);
            acc24[o4*4+2] = fmaf(v, wv.z, acc24[o4*4+2]);
            acc24[o4*4+3] = fmaf(v, wv.w, acc24[o4*4+3]);
        }
    }
    float s2 = bs2[0];
    #pragma unroll
    for (int o = 0; o < 24; ++o)
        s2 = fmaf(gelu_f((acc24[o] + bs1[o]) * (gsi[o] * BN_RSQ) + besi[o]), ws2[o], s2);
    gate_s[(size_t)bh * 128 + w] = gate1p(s2);
}

// ---------------- channel gate: 192->24->192 MLP on pooled ------------------
__global__ __launch_bounds__(192) void channel_gate_k(const float* __restrict__ pooled,
        const float* __restrict__ w1, const float* __restrict__ b1,
        const float* __restrict__ g, const float* __restrict__ be,
        const float* __restrict__ w2, const float* __restrict__ b2,
        float* __restrict__ gate_c)
{
    int b = blockIdx.x, t = threadIdx.x;
    __shared__ float pl[192];
    __shared__ float h1[24];
    pl[t] = pooled[b * 192 + t];
    __syncthreads();
    if (t < 24) {
        float a = b1[t];
        for (int c = 0; c < 192; ++c) a = fmaf(pl[c], w1[t * 192 + c], a);
        a = a * (g[t] * BN_RSQ) + be[t];
        h1[t] = gelu_f(a);
    }
    __syncthreads();
    float a = b2[t];
    #pragma unroll
    for (int o = 0; o < 24; ++o) a = fmaf(h1[o], w2[t * 24 + o], a);
    gate_c[b * 192 + t] = gate1p(a);
}

// ---- dwconv2: channels-last register 3x3 stencil on gated bf16 fu ----------
__global__ __launch_bounds__(256) void dwconv2_k(const ushort_t* __restrict__ fu_b,
        const float* __restrict__ gate_c,
        const float* __restrict__ wdw, const float* __restrict__ bdw,
        const float* __restrict__ g2, const float* __restrict__ be2,
        ushort_t* __restrict__ out2b)
{
    int bh = blockIdx.x >> 1;              // b*128 + h
    int whalf = blockIdx.x & 1;
    int b = bh >> 7, h = bh & 127;
    int tid = threadIdx.x;
    __shared__ float cw[192 * 9];
    __shared__ float cbd[192], cgb[192], cbe[192], cgc[192];
    for (int i = tid; i < 192 * 9; i += 256) cw[i] = wdw[i];
    for (int i = tid; i < 192; i += 256) {
        cbd[i] = bdw[i];
        cgb[i] = g2[i] * BN_RSQ;
        cbe[i] = be2[i];
        cgc[i] = gate_c[b * 192 + i];
    }
    __syncthreads();
    const size_t outrow = (size_t)(b * Ln + h * Wn) * 192;
    for (int it = 0; it < 6; ++it) {
        int item = it * 256 + tid;          // 0..1535
        int w = whalf * 64 + item / 24;
        int c8 = item % 24;
        int co = c8 * 8;
        uint4 nb[3][3];
        #pragma unroll
        for (int r = 0; r < 3; ++r)
            #pragma unroll
            for (int d = 0; d < 3; ++d)
                nb[r][d] = make_uint4(0u, 0u, 0u, 0u);
        #pragma unroll
        for (int r = 0; r < 3; ++r) {
            int hh = h - 1 + r;
            if (hh < 0 || hh >= Hn) continue;
            const ushort_t* rp = fu_b + (size_t)(b * Ln + hh * Wn) * 192 + co;
            #pragma unroll
            for (int d = 0; d < 3; ++d) {
                int w2 = w - 1 + d;
                if (w2 < 0 || w2 >= Wn) continue;
                nb[r][d] = *(const uint4*)(rp + (size_t)w2 * 192);
            }
        }
        unsigned ou[4];
        #pragma unroll
        for (int i = 0; i < 8; ++i) {
            int c = co + i;
            float s = 0.0f;
            #pragma unroll
            for (int r = 0; r < 3; ++r) {
                #pragma unroll
                for (int d = 0; d < 3; ++d) {
                    unsigned word = ((const unsigned*)&nb[r][d])[i >> 1];
                    float v = __uint_as_float((i & 1) ? (word & 0xffff0000u)
                                                      : (word << 16));
                    s = fmaf(cw[c * 9 + r * 3 + d], v, s);
                }
            }
            float y = gelu_f((s + cbd[c]) * cgb[c] + cbe[c]) * cgc[c];
            if (i & 1) ou[i >> 1] |= (unsigned)f2bf(y) << 16;
            else       ou[i >> 1] = (unsigned)f2bf(y);
        }
        *(uint4*)(out2b + outrow + (size_t)w * 192 + co) =
            make_uint4(ou[0], ou[1], ou[2], ou[3]);
    }
}

extern "C" void kernel_launch(void* const* d_in, const int* in_sizes, int n_in,
                              void* d_out, int out_size, void* d_ws, size_t ws_size,
                              hipStream_t stream) {
    (void)in_sizes; (void)n_in; (void)out_size; (void)ws_size;
    const float* x      = (const float*)d_in[0];
    const float* w_qkv  = (const float*)d_in[1];
    const float* b_qkv  = (const float*)d_in[2];
    const float* w_dw1  = (const float*)d_in[3];
    const float* b_dw1  = (const float*)d_in[4];
    const float* g_bn1  = (const float*)d_in[5];
    const float* be_bn1 = (const float*)d_in[6];
    const float* w_si1  = (const float*)d_in[7];
    const float* b_si1  = (const float*)d_in[8];
    const float* g_si   = (const float*)d_in[9];
    const float* be_si  = (const float*)d_in[10];
    const float* w_si2  = (const float*)d_in[11];
    const float* b_si2  = (const float*)d_in[12];
    const float* w_ci1  = (const float*)d_in[13];
    const float* b_ci1  = (const float*)d_in[14];
    const float* g_ci   = (const float*)d_in[15];
    const float* be_ci  = (const float*)d_in[16];
    const float* w_ci2  = (const float*)d_in[17];
    const float* b_ci2  = (const float*)d_in[18];
    const float* w_dw2  = (const float*)d_in[19];
    const float* b_dw2  = (const float*)d_in[20];
    const float* g_bn2  = (const float*)d_in[21];
    const float* be_bn2 = (const float*)d_in[22];
    const float* w_proj = (const float*)d_in[23];
    const float* b_proj = (const float*)d_in[24];

    // ws (f32 units):
    //   phase A: conv1b bf16 [0, FUn/2)                  [conv1 -> spatial_gate]
    //   phase B: Qp [0, FUn/2), Kp [FUn/2, FUn) bf16 (2 banks each)  [qkv -> attn]
    //   phase C: out2b bf16 [8M, 8M+FUn/2)               [dwconv2 -> proj]
    //   smalls at FUn: gate_s, gate_c, pooled
    // d_out (shorts, 2*FUn total):
    //   xb [0, FUn) [conv1 -> qkv], then fu_b [0, FUn) [attn -> dwconv2]
    //   Vp [FUn, 2*FUn) (2 banks) [qkv -> attn]; proj overwrites all (f32).
    float* ws = (float*)d_ws;
    ushort_t* conv1b = (ushort_t*)ws;
    ushort_t* Qp     = (ushort_t*)ws;
    ushort_t* Kp     = (ushort_t*)(ws + FUn / 2);
    ushort_t* out2b  = (ushort_t*)(ws + 8000000);
    float* gate_s    = ws + FUn;                       // B*L
    float* gate_c    = gate_s + (size_t)Bn * Ln;       // B*192
    float* pooled    = gate_c + Bn * 192;              // B*192
    ushort_t* xb     = (ushort_t*)d_out;
    ushort_t* fu_b   = (ushort_t*)d_out;
    ushort_t* Vp     = (ushort_t*)d_out + FUn;

    conv1_k<<<Bn * 192, 256, 0, stream>>>(x, w_dw1, b_dw1, g_bn1, be_bn1,
                                          conv1b, xb, pooled);
    spatial_gate_k<<<Bn * Hn, 128, 0, stream>>>(conv1b, w_si1, b_si1, g_si, be_si,
                                                w_si2, b_si2, gate_s);
    channel_gate_k<<<Bn, 192, 0, stream>>>(pooled, w_ci1, b_ci1, g_ci, be_ci,
                                           w_ci2, b_ci2, gate_c);
    qkv_mfma<<<dim3(Mn / 128, 6), 256, 0, stream>>>(xb, w_qkv, b_qkv, Qp, Kp, Vp);
    attn_mfma<<<1536, 256, 0, stream>>>(Qp, Kp, Vp, gate_s, fu_b);
    dwconv2_k<<<Bn * Hn * 2, 256, 0, stream>>>(fu_b, gate_c,
                                               w_dw2, b_dw2, g_bn2, be_bn2, out2b);
    proj_mfma<<<dim3(Mn / 128, 2), 256, 0, stream>>>(out2b, w_proj, b_proj, (float*)d_out);
}

// Round 11
// 402.719 us; speedup vs baseline: 3.3198x; 1.0958x over previous
//
#include <hip/hip_runtime.h>

#define Bn 8
#define Hn 128
#define Wn 128
#define Cn 192
#define Ln (Hn*Wn)          // 16384
#define Mn (Bn*Ln)          // 131072
#define FUn ((size_t)Mn*Cn) // 25,165,824 floats
#define BANKn ((size_t)Mn*96) // shorts per branch-bank
#define BN_RSQ 0.9999950000374997f   // 1/sqrt(1+1e-5)

typedef unsigned short ushort_t;
typedef __attribute__((ext_vector_type(8))) short short8;
typedef __attribute__((ext_vector_type(4))) float f32x4;
typedef __attribute__((ext_vector_type(4))) unsigned int uint4v;

static __device__ __forceinline__ float gelu_f(float x) {
    return 0.5f * x * (1.0f + erff(x * 0.7071067811865475f));
}
static __device__ __forceinline__ float gate1p(float x) {  // 1 + sigmoid(x)
    return 1.0f + 1.0f / (1.0f + __expf(-x));
}
static __device__ __forceinline__ unsigned short f2bf(float f) {  // RNE
    unsigned u = __float_as_uint(f);
    return (unsigned short)((u + 0x7FFFu + ((u >> 16) & 1u)) >> 16);
}
static __device__ __forceinline__ unsigned int pk2(float lo, float hi) {
    return (unsigned int)f2bf(lo) | ((unsigned int)f2bf(hi) << 16);
}
static __device__ __forceinline__ float bf2f(ushort_t u) {
    return __uint_as_float((unsigned)u << 16);
}

// ========== qkv GEMM (bf16 A; all 576 cols) -> window-contiguous Q/K/V =====
// Each part (Q/K/V) stored as 2 banks (one per attn branch, 96 ch each):
//   bank[br][((b*128 + win)*128 + t)*96 + ch]
__global__ __launch_bounds__(256) void qkv_mfma(const ushort_t* __restrict__ Ab,
        const float* __restrict__ Bw, const float* __restrict__ bias,
        ushort_t* __restrict__ Qp, ushort_t* __restrict__ Kp,
        ushort_t* __restrict__ Vp)
{
    __shared__ __align__(16) ushort_t As[128 * 64];
    __shared__ __align__(16) ushort_t Bs[96 * 64];
    const int m0 = blockIdx.x * 128;
    const int n0g = blockIdx.y * 96;                  // 0..480
    const int part = n0g / 192;
    const int coln = n0g - part * 192;                // 0 or 96 (block-uniform)
    ushort_t* dst = part == 0 ? Qp : (part == 1 ? Kp : Vp);
    ushort_t* bptr = dst + (coln ? BANKn : 0);
    const int tid = threadIdx.x;
    const int lane = tid & 63;
    const int wrow = (tid >> 6) * 32;
    const int r0 = lane >> 4, cl = lane & 15;
    f32x4 acc[2][6] = {};

    for (int ks = 0; ks < 3; ++ks) {
        const int k0 = ks * 64;
        if (ks) __syncthreads();
        #pragma unroll
        for (int i = 0; i < 2; ++i) {
            int s = tid + i * 256;
            int row = s >> 2, q = s & 3;
            const ushort_t* src = Ab + (size_t)(m0 + row) * 192 + k0 + q * 16;
            uint4 u0 = *(const uint4*)(src);
            uint4 u1 = *(const uint4*)(src + 8);
            int r7 = row & 7;
            *(uint4*)&As[row * 64 + (((q * 2) ^ r7) * 8)] = u0;
            *(uint4*)&As[row * 64 + (((q * 2 + 1) ^ r7) * 8)] = u1;
        }
        #pragma unroll
        for (int i = 0; i < 3; ++i) {
            int f = tid + i * 256;                    // 0..767
            int col = f % 96, kslot = f / 96;
            uint4v wv;
            #pragma unroll
            for (int e2 = 0; e2 < 4; ++e2) {
                float lo = Bw[(size_t)(k0 + kslot * 8 + 2 * e2)     * 576 + n0g + col];
                float hi = Bw[(size_t)(k0 + kslot * 8 + 2 * e2 + 1) * 576 + n0g + col];
                wv[e2] = pk2(lo, hi);
            }
            *(uint4v*)&Bs[col * 64 + ((kslot ^ (col & 7)) * 8)] = wv;
        }
        __syncthreads();
        #pragma unroll
        for (int kk = 0; kk < 2; ++kk) {
            int kslot = kk * 4 + r0;
            int ra0 = wrow + cl, ra1 = wrow + 16 + cl;
            short8 a0 = *(const short8*)&As[ra0 * 64 + ((kslot ^ (ra0 & 7)) * 8)];
            short8 a1 = *(const short8*)&As[ra1 * 64 + ((kslot ^ (ra1 & 7)) * 8)];
            #pragma unroll
            for (int n = 0; n < 6; ++n) {
                int col = n * 16 + cl;
                short8 bn = *(const short8*)&Bs[col * 64 + ((kslot ^ (col & 7)) * 8)];
                acc[0][n] = __builtin_amdgcn_mfma_f32_16x16x32_bf16(a0, bn, acc[0][n], 0, 0, 0);
                acc[1][n] = __builtin_amdgcn_mfma_f32_16x16x32_bf16(a1, bn, acc[1][n], 0, 0, 0);
            }
        }
    }
    float bv[6];
    #pragma unroll
    for (int n = 0; n < 6; ++n) bv[n] = bias[n0g + n * 16 + cl];
    #pragma unroll
    for (int m = 0; m < 2; ++m) {
        #pragma unroll
        for (int j = 0; j < 4; ++j) {
            int row = m0 + wrow + m * 16 + r0 * 4 + j;
            int b = row >> 14, l = row & 16383;
            int h = l >> 7, w = l & 127;
            int win, t;
            if (coln == 0) { win = (h >> 3) * 8 + (w >> 4);  t = (h & 7) * 16 + (w & 15); }
            else           { win = (h >> 4) * 16 + (w >> 3); t = (h & 15) * 8 + (w & 7); }
            size_t rbase = ((size_t)((b * 128 + win) * 128 + t)) * 96;
            #pragma unroll
            for (int n = 0; n < 6; ++n)
                bptr[rbase + n * 16 + cl] = f2bf(acc[m][n][j] + bv[n]);
        }
    }
}

// =================== proj GEMM: bf16 A (row-major) x f32 Bw -> f32 out ======
__global__ __launch_bounds__(256) void proj_mfma(const ushort_t* __restrict__ Ab,
        const float* __restrict__ Bw, const float* __restrict__ bias,
        float* __restrict__ Cout)
{
    __shared__ __align__(16) ushort_t As[128 * 64];
    __shared__ __align__(16) ushort_t Bs[96 * 64];
    const int m0 = blockIdx.x * 128;
    const int n0 = blockIdx.y * 96;
    const int tid = threadIdx.x;
    const int lane = tid & 63;
    const int wrow = (tid >> 6) * 32;
    const int r0 = lane >> 4, cl = lane & 15;
    f32x4 acc[2][6] = {};

    for (int ks = 0; ks < 3; ++ks) {
        const int k0 = ks * 64;
        if (ks) __syncthreads();
        #pragma unroll
        for (int i = 0; i < 2; ++i) {
            int s = tid + i * 256;
            int row = s >> 2, q = s & 3;
            const ushort_t* src = Ab + (size_t)(m0 + row) * 192 + k0 + q * 16;
            uint4 u0 = *(const uint4*)(src);
            uint4 u1 = *(const uint4*)(src + 8);
            int r7 = row & 7;
            *(uint4*)&As[row * 64 + (((q * 2) ^ r7) * 8)] = u0;
            *(uint4*)&As[row * 64 + (((q * 2 + 1) ^ r7) * 8)] = u1;
        }
        #pragma unroll
        for (int i = 0; i < 3; ++i) {
            int f = tid + i * 256;
            int col = f % 96, kslot = f / 96;
            uint4v wv;
            #pragma unroll
            for (int e2 = 0; e2 < 4; ++e2) {
                float lo = Bw[(size_t)(k0 + kslot * 8 + 2 * e2)     * 192 + n0 + col];
                float hi = Bw[(size_t)(k0 + kslot * 8 + 2 * e2 + 1) * 192 + n0 + col];
                wv[e2] = pk2(lo, hi);
            }
            *(uint4v*)&Bs[col * 64 + ((kslot ^ (col & 7)) * 8)] = wv;
        }
        __syncthreads();
        #pragma unroll
        for (int kk = 0; kk < 2; ++kk) {
            int kslot = kk * 4 + r0;
            int ra0 = wrow + cl, ra1 = wrow + 16 + cl;
            short8 a0 = *(const short8*)&As[ra0 * 64 + ((kslot ^ (ra0 & 7)) * 8)];
            short8 a1 = *(const short8*)&As[ra1 * 64 + ((kslot ^ (ra1 & 7)) * 8)];
            #pragma unroll
            for (int n = 0; n < 6; ++n) {
                int col = n * 16 + cl;
                short8 bn = *(const short8*)&Bs[col * 64 + ((kslot ^ (col & 7)) * 8)];
                acc[0][n] = __builtin_amdgcn_mfma_f32_16x16x32_bf16(a0, bn, acc[0][n], 0, 0, 0);
                acc[1][n] = __builtin_amdgcn_mfma_f32_16x16x32_bf16(a1, bn, acc[1][n], 0, 0, 0);
            }
        }
    }
    #pragma unroll
    for (int m = 0; m < 2; ++m) {
        #pragma unroll
        for (int n = 0; n < 6; ++n) {
            int col = n0 + n * 16 + cl;
            float bv = bias[col];
            #pragma unroll
            for (int j = 0; j < 4; ++j) {
                int row = m0 + wrow + m * 16 + r0 * 4 + j;
                Cout[(size_t)row * 192 + col] = acc[m][n][j] + bv;
            }
        }
    }
}

// ===== MFMA window attention, j-split: wave = (win, head, query-half) ======
__global__ __launch_bounds__(256) void attn_mfma(const ushort_t* __restrict__ Qp,
        const ushort_t* __restrict__ Kp, const ushort_t* __restrict__ Vp,
        const float* __restrict__ gate_s, ushort_t* __restrict__ fu_b)
{
    const int widx = threadIdx.x >> 6;
    const int idx = blockIdx.x * 4 + widx;          // 0..12287
    const int jhalf = idx & 1;                      // sibling waves share a block
    const int sub0 = idx >> 1;                      // 0..6143
    const int branch = (sub0 >= 3072) ? 1 : 0;
    const int sub = sub0 - branch * 3072;
    const int head = sub >> 10;
    const int b = (sub >> 7) & 7;
    const int win = sub & 127;
    const int L = threadIdx.x & 63;
    const int g = L >> 4, q = L & 15;
    int hb, wb;
    if (branch == 0) { hb = (win >> 3) * 8;  wb = (win & 7) * 16; }
    else             { hb = (win >> 4) * 16; wb = (win & 15) * 8; }
    const int cf = branch * 96 + head * 32;         // fu channel base
    const int hch = head * 32;                      // in-bank channel base
    const int jbase = jhalf * 4;

    const size_t bank = branch ? BANKn : 0;
    const size_t wbase = ((size_t)((b * 128 + win) * 128)) * 96;
    const ushort_t* Qw = Qp + bank + wbase;
    const ushort_t* Kw = Kp + bank + wbase;
    const ushort_t* Vw = Vp + bank + wbase;

    short8 kf[8], qf[4];
    #pragma unroll
    for (int i = 0; i < 8; ++i)
        kf[i] = *(const short8*)(Kw + (size_t)(16 * i + q) * 96 + hch + 8 * g);
    #pragma unroll
    for (int jj = 0; jj < 4; ++jj)
        qf[jj] = *(const short8*)(Qw + (size_t)(16 * (jbase + jj) + q) * 96 + hch + 8 * g);
    short8 vf[2][4];
    {
        #pragma unroll
        for (int s = 0; s < 4; ++s) {
            #pragma unroll
            for (int dblk = 0; dblk < 2; ++dblk) {
                uint4v wv;
                #pragma unroll
                for (int e2 = 0; e2 < 4; ++e2) {
                    size_t base = (size_t)(32 * s + 8 * g + 2 * e2) * 96 + hch + 16 * dblk + q;
                    unsigned lo = Vw[base];
                    unsigned hi = Vw[base + 96];
                    wv[e2] = lo | (hi << 16);
                }
                vf[dblk][s] = *(short8*)&wv;
            }
        }
    }

    const float SC = 0.5303300858899106f;   // 3/sqrt(32)
    const int src0 = q + ((g & 1) << 5);
    const bool thi = (g >> 1) != 0;
    const bool glo = (g < 2);
    #pragma unroll
    for (int jj = 0; jj < 4; ++jj) {
        const int j = jbase + jj;
        unsigned wA[8], wB[8];
        float ss = 0.0f;
        #pragma unroll
        for (int i = 0; i < 8; ++i) {
            f32x4 z = {};
            f32x4 S = __builtin_amdgcn_mfma_f32_16x16x32_bf16(kf[i], qf[jj], z, 0, 0, 0);
            float p0 = __expf(S[0] * SC), p1 = __expf(S[1] * SC);
            float p2 = __expf(S[2] * SC), p3 = __expf(S[3] * SC);
            ss += (p0 + p1) + (p2 + p3);
            wA[i] = pk2(p0, p1);
            wB[i] = pk2(p2, p3);
        }
        ss += __shfl_xor(ss, 16);
        ss += __shfl_xor(ss, 32);
        int l_own;
        if (branch == 0) l_own = (hb + j) * Wn + wb + q;
        else             l_own = (hb + 2 * j + (q >> 3)) * Wn + wb + (q & 7);
        float s_own = 3.0f * gate_s[(size_t)b * Ln + l_own] / ss;

        f32x4 O0 = {}, O1 = {};
        #pragma unroll
        for (int s = 0; s < 4; ++s) {
            unsigned a0  = (unsigned)__shfl((int)wA[2*s],     src0);
            unsigned b0  = (unsigned)__shfl((int)wB[2*s],     src0);
            unsigned a0h = (unsigned)__shfl((int)wA[2*s],     src0 + 16);
            unsigned b0h = (unsigned)__shfl((int)wB[2*s],     src0 + 16);
            unsigned a1  = (unsigned)__shfl((int)wA[2*s+1],   src0);
            unsigned b1  = (unsigned)__shfl((int)wB[2*s+1],   src0);
            unsigned a1h = (unsigned)__shfl((int)wA[2*s+1],   src0 + 16);
            unsigned b1h = (unsigned)__shfl((int)wB[2*s+1],   src0 + 16);
            uint4v B2u;
            B2u[0] = thi ? a1  : a0;
            B2u[1] = thi ? b1  : b0;
            B2u[2] = thi ? a1h : a0h;
            B2u[3] = thi ? b1h : b0h;
            short8 B2 = *(short8*)&B2u;
            O0 = __builtin_amdgcn_mfma_f32_16x16x32_bf16(vf[0][s], B2, O0, 0, 0, 0);
            O1 = __builtin_amdgcn_mfma_f32_16x16x32_bf16(vf[1][s], B2, O1, 0, 0, 0);
        }
        unsigned w0 = pk2(O0[0] * s_own, O0[1] * s_own);
        unsigned w1 = pk2(O0[2] * s_own, O0[3] * s_own);
        unsigned w2 = pk2(O1[0] * s_own, O1[1] * s_own);
        unsigned w3 = pk2(O1[2] * s_own, O1[3] * s_own);
        unsigned a0 = (unsigned)__shfl((int)w0, src0);
        unsigned a1 = (unsigned)__shfl((int)w1, src0);
        unsigned b0 = (unsigned)__shfl((int)w0, src0 + 16);
        unsigned b1 = (unsigned)__shfl((int)w1, src0 + 16);
        unsigned c0 = (unsigned)__shfl((int)w2, src0);
        unsigned c1 = (unsigned)__shfl((int)w3, src0);
        unsigned d0 = (unsigned)__shfl((int)w2, src0 + 16);
        unsigned d1 = (unsigned)__shfl((int)w3, src0 + 16);
        uint4 o = make_uint4(glo ? a0 : c0, glo ? a1 : c1,
                             glo ? b0 : d0, glo ? b1 : d1);
        *(uint4*)(fu_b + (size_t)(b * Ln + l_own) * 192 + cf + 8 * g) = o;
    }
}

// ---- conv1: dwconv3x3+BN+GELU per (b,c) plane + bf16 x-cast + pooled mean --
__global__ __launch_bounds__(256) void conv1_k(const float* __restrict__ x,
        const float* __restrict__ wdw, const float* __restrict__ bdw,
        const float* __restrict__ g1, const float* __restrict__ be1,
        ushort_t* __restrict__ conv1b, ushort_t* __restrict__ xb,
        float* __restrict__ pooled)
{
    int bc = blockIdx.x;                   // b*192 + c
    int c = bc % 192;
    const float* plane = x + (size_t)bc * Ln;
    ushort_t* oplane = conv1b + (size_t)bc * Ln;
    ushort_t* xplane = xb + (size_t)bc * Ln;
    int t = threadIdx.x;
    int sx = t & 31, sy = t >> 5;          // 32 strips x 8 bands
    int w0 = sx * 4, h0 = sy * 16;
    float wk[9];
    #pragma unroll
    for (int i = 0; i < 9; ++i) wk[i] = wdw[c * 9 + i];
    float gb = g1[c] * BN_RSQ, bb = be1[c], bd = bdw[c];

    float rA[6], rB[6], rC[6];
    auto load6 = [&](int h, float* r) {
        if (h < 0 || h >= Hn) {
            r[0] = r[1] = r[2] = r[3] = r[4] = r[5] = 0.0f;
            return;
        }
        const float* rp = plane + h * Wn;
        float4 m = *(const float4*)(rp + w0);
        r[0] = sx ? rp[w0 - 1] : 0.0f;
        r[1] = m.x; r[2] = m.y; r[3] = m.z; r[4] = m.w;
        r[5] = (sx < 31) ? rp[w0 + 4] : 0.0f;
    };
    load6(h0 - 1, rA);
    load6(h0, rB);
    float psum = 0.0f;
    #pragma unroll
    for (int i = 0; i < 16; ++i) {
        int h = h0 + i;
        load6(h + 1, rC);
        *(uint2*)(xplane + h * Wn + w0) =
            make_uint2(pk2(rB[1], rB[2]), pk2(rB[3], rB[4]));
        float o[4];
        #pragma unroll
        for (int p = 0; p < 4; ++p) {
            float s = wk[0] * rA[p];
            s = fmaf(wk[1], rA[p + 1], s);
            s = fmaf(wk[2], rA[p + 2], s);
            s = fmaf(wk[3], rB[p],     s);
            s = fmaf(wk[4], rB[p + 1], s);
            s = fmaf(wk[5], rB[p + 2], s);
            s = fmaf(wk[6], rC[p],     s);
            s = fmaf(wk[7], rC[p + 1], s);
            s = fmaf(wk[8], rC[p + 2], s);
            float y = gelu_f((s + bd) * gb + bb);
            psum += y;
            o[p] = y;
        }
        uint2 ow = make_uint2(pk2(o[0], o[1]), pk2(o[2], o[3]));
        *(uint2*)(oplane + h * Wn + w0) = ow;
        #pragma unroll
        for (int q2 = 0; q2 < 6; ++q2) { rA[q2] = rB[q2]; rB[q2] = rC[q2]; }
    }
    __shared__ float red[4];
    for (int off = 32; off; off >>= 1) psum += __shfl_down(psum, off);
    if ((t & 63) == 0) red[t >> 6] = psum;
    __syncthreads();
    if (t == 0)
        pooled[bc] = (red[0] + red[1] + red[2] + red[3]) * (1.0f / Ln);
}

// ------- spatial gate: per-pixel 192->24->1 MLP on bf16 conv1 ---------------
__global__ __launch_bounds__(128) void spatial_gate_k(const ushort_t* __restrict__ conv1b,
        const float* __restrict__ ws1g, const float* __restrict__ bs1,
        const float* __restrict__ gsi, const float* __restrict__ besi,
        const float* __restrict__ ws2, const float* __restrict__ bs2,
        float* __restrict__ gate_s)
{
    int bh = blockIdx.x;                   // b*128 + h
    int b = bh >> 7, h = bh & 127;
    int w = threadIdx.x;
    __shared__ float ws1T[192 * 24];       // [c][o]
    for (int i = w; i < 192 * 24; i += 128) {
        int c = i / 24, o = i - c * 24;
        ws1T[i] = ws1g[o * 192 + c];
    }
    __syncthreads();
    float acc24[24] = {};
    const ushort_t* base = conv1b + (size_t)b * 192 * Ln + h * Wn + w;
    #pragma unroll 4
    for (int c = 0; c < 192; ++c) {
        float v = bf2f(base[(size_t)c * Ln]);
        const float4* wp = (const float4*)&ws1T[c * 24];
        #pragma unroll
        for (int o4 = 0; o4 < 6; ++o4) {
            float4 wv = wp[o4];
            acc24[o4*4+0] = fmaf(v, wv.x, acc24[o4*4+0]);
            acc24[o4*4+1] = fmaf(v, wv.y, acc24[o4*4+1]);
            acc24[o4*4+2] = fmaf(v, wv.z, acc24[o4*4+2]);
            acc24[o4*4+3] = fmaf(v, wv.w, acc24[o4*4+3]);
        }
    }
    float s2 = bs2[0];
    #pragma unroll
    for (int o = 0; o < 24; ++o)
        s2 = fmaf(gelu_f((acc24[o] + bs1[o]) * (gsi[o] * BN_RSQ) + besi[o]), ws2[o], s2);
    gate_s[(size_t)bh * 128 + w] = gate1p(s2);
}

// ---------------- channel gate: 192->24->192 MLP on pooled ------------------
__global__ __launch_bounds__(192) void channel_gate_k(const float* __restrict__ pooled,
        const float* __restrict__ w1, const float* __restrict__ b1,
        const float* __restrict__ g, const float* __restrict__ be,
        const float* __restrict__ w2, const float* __restrict__ b2,
        float* __restrict__ gate_c)
{
    int b = blockIdx.x, t = threadIdx.x;
    __shared__ float pl[192];
    __shared__ float h1[24];
    pl[t] = pooled[b * 192 + t];
    __syncthreads();
    if (t < 24) {
        float a = b1[t];
        for (int c = 0; c < 192; ++c) a = fmaf(pl[c], w1[t * 192 + c], a);
        a = a * (g[t] * BN_RSQ) + be[t];
        h1[t] = gelu_f(a);
    }
    __syncthreads();
    float a = b2[t];
    #pragma unroll
    for (int o = 0; o < 24; ++o) a = fmaf(h1[o], w2[t * 24 + o], a);
    gate_c[b * 192 + t] = gate1p(a);
}

// ---- dwconv2: channels-last register 3x3 stencil on gated bf16 fu ----------
__global__ __launch_bounds__(256) void dwconv2_k(const ushort_t* __restrict__ fu_b,
        const float* __restrict__ gate_c,
        const float* __restrict__ wdw, const float* __restrict__ bdw,
        const float* __restrict__ g2, const float* __restrict__ be2,
        ushort_t* __restrict__ out2b)
{
    int bh = blockIdx.x >> 1;              // b*128 + h
    int whalf = blockIdx.x & 1;
    int b = bh >> 7, h = bh & 127;
    int tid = threadIdx.x;
    __shared__ float cw[192 * 9];
    __shared__ float cbd[192], cgb[192], cbe[192], cgc[192];
    for (int i = tid; i < 192 * 9; i += 256) cw[i] = wdw[i];
    for (int i = tid; i < 192; i += 256) {
        cbd[i] = bdw[i];
        cgb[i] = g2[i] * BN_RSQ;
        cbe[i] = be2[i];
        cgc[i] = gate_c[b * 192 + i];
    }
    __syncthreads();
    const size_t outrow = (size_t)(b * Ln + h * Wn) * 192;
    for (int it = 0; it < 6; ++it) {
        int item = it * 256 + tid;          // 0..1535
        int w = whalf * 64 + item / 24;
        int c8 = item % 24;
        int co = c8 * 8;
        uint4 nb[3][3];
        #pragma unroll
        for (int r = 0; r < 3; ++r)
            #pragma unroll
            for (int d = 0; d < 3; ++d)
                nb[r][d] = make_uint4(0u, 0u, 0u, 0u);
        #pragma unroll
        for (int r = 0; r < 3; ++r) {
            int hh = h - 1 + r;
            if (hh < 0 || hh >= Hn) continue;
            const ushort_t* rp = fu_b + (size_t)(b * Ln + hh * Wn) * 192 + co;
            #pragma unroll
            for (int d = 0; d < 3; ++d) {
                int w2 = w - 1 + d;
                if (w2 < 0 || w2 >= Wn) continue;
                nb[r][d] = *(const uint4*)(rp + (size_t)w2 * 192);
            }
        }
        unsigned ou[4];
        #pragma unroll
        for (int i = 0; i < 8; ++i) {
            int c = co + i;
            float s = 0.0f;
            #pragma unroll
            for (int r = 0; r < 3; ++r) {
                #pragma unroll
                for (int d = 0; d < 3; ++d) {
                    unsigned word = ((const unsigned*)&nb[r][d])[i >> 1];
                    float v = __uint_as_float((i & 1) ? (word & 0xffff0000u)
                                                      : (word << 16));
                    s = fmaf(cw[c * 9 + r * 3 + d], v, s);
                }
            }
            float y = gelu_f((s + cbd[c]) * cgb[c] + cbe[c]) * cgc[c];
            if (i & 1) ou[i >> 1] |= (unsigned)f2bf(y) << 16;
            else       ou[i >> 1] = (unsigned)f2bf(y);
        }
        *(uint4*)(out2b + outrow + (size_t)w * 192 + co) =
            make_uint4(ou[0], ou[1], ou[2], ou[3]);
    }
}

extern "C" void kernel_launch(void* const* d_in, const int* in_sizes, int n_in,
                              void* d_out, int out_size, void* d_ws, size_t ws_size,
                              hipStream_t stream) {
    (void)in_sizes; (void)n_in; (void)out_size; (void)ws_size;
    const float* x      = (const float*)d_in[0];
    const float* w_qkv  = (const float*)d_in[1];
    const float* b_qkv  = (const float*)d_in[2];
    const float* w_dw1  = (const float*)d_in[3];
    const float* b_dw1  = (const float*)d_in[4];
    const float* g_bn1  = (const float*)d_in[5];
    const float* be_bn1 = (const float*)d_in[6];
    const float* w_si1  = (const float*)d_in[7];
    const float* b_si1  = (const float*)d_in[8];
    const float* g_si   = (const float*)d_in[9];
    const float* be_si  = (const float*)d_in[10];
    const float* w_si2  = (const float*)d_in[11];
    const float* b_si2  = (const float*)d_in[12];
    const float* w_ci1  = (const float*)d_in[13];
    const float* b_ci1  = (const float*)d_in[14];
    const float* g_ci   = (const float*)d_in[15];
    const float* be_ci  = (const float*)d_in[16];
    const float* w_ci2  = (const float*)d_in[17];
    const float* b_ci2  = (const float*)d_in[18];
    const float* w_dw2  = (const float*)d_in[19];
    const float* b_dw2  = (const float*)d_in[20];
    const float* g_bn2  = (const float*)d_in[21];
    const float* be_bn2 = (const float*)d_in[22];
    const float* w_proj = (const float*)d_in[23];
    const float* b_proj = (const float*)d_in[24];

    // ws (f32 units):
    //   phase A: conv1b bf16 [0, FUn/2)                  [conv1 -> spatial_gate]
    //   phase B: Qp [0, FUn/2), Kp [FUn/2, FUn) bf16 (2 banks each)  [qkv -> attn]
    //   phase C: out2b bf16 [8M, 8M+FUn/2)               [dwconv2 -> proj]
    //   smalls at FUn: gate_s, gate_c, pooled
    // d_out (shorts, 2*FUn total):
    //   xb [0, FUn) [conv1 -> qkv], then fu_b [0, FUn) [attn -> dwconv2]
    //   Vp [FUn, 2*FUn) (2 banks) [qkv -> attn]; proj overwrites all (f32).
    float* ws = (float*)d_ws;
    ushort_t* conv1b = (ushort_t*)ws;
    ushort_t* Qp     = (ushort_t*)ws;
    ushort_t* Kp     = (ushort_t*)(ws + FUn / 2);
    ushort_t* out2b  = (ushort_t*)(ws + 8000000);
    float* gate_s    = ws + FUn;                       // B*L
    float* gate_c    = gate_s + (size_t)Bn * Ln;       // B*192
    float* pooled    = gate_c + Bn * 192;              // B*192
    ushort_t* xb     = (ushort_t*)d_out;
    ushort_t* fu_b   = (ushort_t*)d_out;
    ushort_t* Vp     = (ushort_t*)d_out + FUn;

    conv1_k<<<Bn * 192, 256, 0, stream>>>(x, w_dw1, b_dw1, g_bn1, be_bn1,
                                          conv1b, xb, pooled);
    spatial_gate_k<<<Bn * Hn, 128, 0, stream>>>(conv1b, w_si1, b_si1, g_si, be_si,
                                                w_si2, b_si2, gate_s);
    channel_gate_k<<<Bn, 192, 0, stream>>>(pooled, w_ci1, b_ci1, g_ci, be_ci,
                                           w_ci2, b_ci2, gate_c);
    qkv_mfma<<<dim3(Mn / 128, 6), 256, 0, stream>>>(xb, w_qkv, b_qkv, Qp, Kp, Vp);
    attn_mfma<<<3072, 256, 0, stream>>>(Qp, Kp, Vp, gate_s, fu_b);
    dwconv2_k<<<Bn * Hn * 2, 256, 0, stream>>>(fu_b, gate_c,
                                               w_dw2, b_dw2, g_bn2, be_bn2, out2b);
    proj_mfma<<<dim3(Mn / 128, 2), 256, 0, stream>>>(out2b, w_proj, b_proj, (float*)d_out);
}

// Round 12
// 356.059 us; speedup vs baseline: 3.7549x; 1.1310x over previous
//
#include <hip/hip_runtime.h>

#define Bn 8
#define Hn 128
#define Wn 128
#define Cn 192
#define Ln (Hn*Wn)          // 16384
#define Mn (Bn*Ln)          // 131072
#define FUn ((size_t)Mn*Cn) // 25,165,824 floats
#define BANKn ((size_t)Mn*96) // shorts per branch-bank
#define BN_RSQ 0.9999950000374997f   // 1/sqrt(1+1e-5)

typedef unsigned short ushort_t;
typedef __attribute__((ext_vector_type(8))) short short8;
typedef __attribute__((ext_vector_type(4))) float f32x4;
typedef __attribute__((ext_vector_type(4))) unsigned int uint4v;

static __device__ __forceinline__ float gelu_f(float x) {
    return 0.5f * x * (1.0f + erff(x * 0.7071067811865475f));
}
static __device__ __forceinline__ float gate1p(float x) {  // 1 + sigmoid(x)
    return 1.0f + 1.0f / (1.0f + __expf(-x));
}
static __device__ __forceinline__ unsigned short f2bf(float f) {  // RNE
    unsigned u = __float_as_uint(f);
    return (unsigned short)((u + 0x7FFFu + ((u >> 16) & 1u)) >> 16);
}
static __device__ __forceinline__ unsigned int pk2(float lo, float hi) {
    return (unsigned int)f2bf(lo) | ((unsigned int)f2bf(hi) << 16);
}
static __device__ __forceinline__ float bf2f(ushort_t u) {
    return __uint_as_float((unsigned)u << 16);
}

// ========== qkv GEMM (bf16 A; all 576 cols) -> window-contiguous Q/K/V =====
// Each part (Q/K/V) stored as 2 banks (one per attn branch, 96 ch each):
//   bank[br][((b*128 + win)*128 + t)*96 + ch]
__global__ __launch_bounds__(256) void qkv_mfma(const ushort_t* __restrict__ Ab,
        const float* __restrict__ Bw, const float* __restrict__ bias,
        ushort_t* __restrict__ Qp, ushort_t* __restrict__ Kp,
        ushort_t* __restrict__ Vp)
{
    __shared__ __align__(16) ushort_t As[128 * 64];
    __shared__ __align__(16) ushort_t Bs[96 * 64];
    const int m0 = blockIdx.x * 128;
    const int n0g = blockIdx.y * 96;                  // 0..480
    const int part = n0g / 192;
    const int coln = n0g - part * 192;                // 0 or 96 (block-uniform)
    ushort_t* dst = part == 0 ? Qp : (part == 1 ? Kp : Vp);
    ushort_t* bptr = dst + (coln ? BANKn : 0);
    const int tid = threadIdx.x;
    const int lane = tid & 63;
    const int wrow = (tid >> 6) * 32;
    const int r0 = lane >> 4, cl = lane & 15;
    f32x4 acc[2][6] = {};

    for (int ks = 0; ks < 3; ++ks) {
        const int k0 = ks * 64;
        if (ks) __syncthreads();
        #pragma unroll
        for (int i = 0; i < 2; ++i) {
            int s = tid + i * 256;
            int row = s >> 2, q = s & 3;
            const ushort_t* src = Ab + (size_t)(m0 + row) * 192 + k0 + q * 16;
            uint4 u0 = *(const uint4*)(src);
            uint4 u1 = *(const uint4*)(src + 8);
            int r7 = row & 7;
            *(uint4*)&As[row * 64 + (((q * 2) ^ r7) * 8)] = u0;
            *(uint4*)&As[row * 64 + (((q * 2 + 1) ^ r7) * 8)] = u1;
        }
        #pragma unroll
        for (int i = 0; i < 3; ++i) {
            int f = tid + i * 256;                    // 0..767
            int col = f % 96, kslot = f / 96;
            uint4v wv;
            #pragma unroll
            for (int e2 = 0; e2 < 4; ++e2) {
                float lo = Bw[(size_t)(k0 + kslot * 8 + 2 * e2)     * 576 + n0g + col];
                float hi = Bw[(size_t)(k0 + kslot * 8 + 2 * e2 + 1) * 576 + n0g + col];
                wv[e2] = pk2(lo, hi);
            }
            *(uint4v*)&Bs[col * 64 + ((kslot ^ (col & 7)) * 8)] = wv;
        }
        __syncthreads();
        #pragma unroll
        for (int kk = 0; kk < 2; ++kk) {
            int kslot = kk * 4 + r0;
            int ra0 = wrow + cl, ra1 = wrow + 16 + cl;
            short8 a0 = *(const short8*)&As[ra0 * 64 + ((kslot ^ (ra0 & 7)) * 8)];
            short8 a1 = *(const short8*)&As[ra1 * 64 + ((kslot ^ (ra1 & 7)) * 8)];
            #pragma unroll
            for (int n = 0; n < 6; ++n) {
                int col = n * 16 + cl;
                short8 bn = *(const short8*)&Bs[col * 64 + ((kslot ^ (col & 7)) * 8)];
                acc[0][n] = __builtin_amdgcn_mfma_f32_16x16x32_bf16(a0, bn, acc[0][n], 0, 0, 0);
                acc[1][n] = __builtin_amdgcn_mfma_f32_16x16x32_bf16(a1, bn, acc[1][n], 0, 0, 0);
            }
        }
    }
    float bv[6];
    #pragma unroll
    for (int n = 0; n < 6; ++n) bv[n] = bias[n0g + n * 16 + cl];
    #pragma unroll
    for (int m = 0; m < 2; ++m) {
        #pragma unroll
        for (int j = 0; j < 4; ++j) {
            int row = m0 + wrow + m * 16 + r0 * 4 + j;
            int b = row >> 14, l = row & 16383;
            int h = l >> 7, w = l & 127;
            int win, t;
            if (coln == 0) { win = (h >> 3) * 8 + (w >> 4);  t = (h & 7) * 16 + (w & 15); }
            else           { win = (h >> 4) * 16 + (w >> 3); t = (h & 15) * 8 + (w & 7); }
            size_t rbase = ((size_t)((b * 128 + win) * 128 + t)) * 96;
            #pragma unroll
            for (int n = 0; n < 6; ++n)
                bptr[rbase + n * 16 + cl] = f2bf(acc[m][n][j] + bv[n]);
        }
    }
}

// =================== proj GEMM: bf16 A (row-major) x f32 Bw -> f32 out ======
__global__ __launch_bounds__(256) void proj_mfma(const ushort_t* __restrict__ Ab,
        const float* __restrict__ Bw, const float* __restrict__ bias,
        float* __restrict__ Cout)
{
    __shared__ __align__(16) ushort_t As[128 * 64];
    __shared__ __align__(16) ushort_t Bs[96 * 64];
    const int m0 = blockIdx.x * 128;
    const int n0 = blockIdx.y * 96;
    const int tid = threadIdx.x;
    const int lane = tid & 63;
    const int wrow = (tid >> 6) * 32;
    const int r0 = lane >> 4, cl = lane & 15;
    f32x4 acc[2][6] = {};

    for (int ks = 0; ks < 3; ++ks) {
        const int k0 = ks * 64;
        if (ks) __syncthreads();
        #pragma unroll
        for (int i = 0; i < 2; ++i) {
            int s = tid + i * 256;
            int row = s >> 2, q = s & 3;
            const ushort_t* src = Ab + (size_t)(m0 + row) * 192 + k0 + q * 16;
            uint4 u0 = *(const uint4*)(src);
            uint4 u1 = *(const uint4*)(src + 8);
            int r7 = row & 7;
            *(uint4*)&As[row * 64 + (((q * 2) ^ r7) * 8)] = u0;
            *(uint4*)&As[row * 64 + (((q * 2 + 1) ^ r7) * 8)] = u1;
        }
        #pragma unroll
        for (int i = 0; i < 3; ++i) {
            int f = tid + i * 256;
            int col = f % 96, kslot = f / 96;
            uint4v wv;
            #pragma unroll
            for (int e2 = 0; e2 < 4; ++e2) {
                float lo = Bw[(size_t)(k0 + kslot * 8 + 2 * e2)     * 192 + n0 + col];
                float hi = Bw[(size_t)(k0 + kslot * 8 + 2 * e2 + 1) * 192 + n0 + col];
                wv[e2] = pk2(lo, hi);
            }
            *(uint4v*)&Bs[col * 64 + ((kslot ^ (col & 7)) * 8)] = wv;
        }
        __syncthreads();
        #pragma unroll
        for (int kk = 0; kk < 2; ++kk) {
            int kslot = kk * 4 + r0;
            int ra0 = wrow + cl, ra1 = wrow + 16 + cl;
            short8 a0 = *(const short8*)&As[ra0 * 64 + ((kslot ^ (ra0 & 7)) * 8)];
            short8 a1 = *(const short8*)&As[ra1 * 64 + ((kslot ^ (ra1 & 7)) * 8)];
            #pragma unroll
            for (int n = 0; n < 6; ++n) {
                int col = n * 16 + cl;
                short8 bn = *(const short8*)&Bs[col * 64 + ((kslot ^ (col & 7)) * 8)];
                acc[0][n] = __builtin_amdgcn_mfma_f32_16x16x32_bf16(a0, bn, acc[0][n], 0, 0, 0);
                acc[1][n] = __builtin_amdgcn_mfma_f32_16x16x32_bf16(a1, bn, acc[1][n], 0, 0, 0);
            }
        }
    }
    #pragma unroll
    for (int m = 0; m < 2; ++m) {
        #pragma unroll
        for (int n = 0; n < 6; ++n) {
            int col = n0 + n * 16 + cl;
            float bv = bias[col];
            #pragma unroll
            for (int j = 0; j < 4; ++j) {
                int row = m0 + wrow + m * 16 + r0 * 4 + j;
                Cout[(size_t)row * 192 + col] = acc[m][n][j] + bv;
            }
        }
    }
}

// ===== MFMA window attention, j-split: wave = (win, head, query-half) ======
__global__ __launch_bounds__(256) void attn_mfma(const ushort_t* __restrict__ Qp,
        const ushort_t* __restrict__ Kp, const ushort_t* __restrict__ Vp,
        const float* __restrict__ gate_s, ushort_t* __restrict__ fu_b)
{
    const int widx = threadIdx.x >> 6;
    const int idx = blockIdx.x * 4 + widx;          // 0..12287
    const int jhalf = idx & 1;                      // sibling waves share a block
    const int sub0 = idx >> 1;                      // 0..6143
    const int branch = (sub0 >= 3072) ? 1 : 0;
    const int sub = sub0 - branch * 3072;
    const int head = sub >> 10;
    const int b = (sub >> 7) & 7;
    const int win = sub & 127;
    const int L = threadIdx.x & 63;
    const int g = L >> 4, q = L & 15;
    int hb, wb;
    if (branch == 0) { hb = (win >> 3) * 8;  wb = (win & 7) * 16; }
    else             { hb = (win >> 4) * 16; wb = (win & 15) * 8; }
    const int cf = branch * 96 + head * 32;         // fu channel base
    const int hch = head * 32;                      // in-bank channel base
    const int jbase = jhalf * 4;

    const size_t bank = branch ? BANKn : 0;
    const size_t wbase = ((size_t)((b * 128 + win) * 128)) * 96;
    const ushort_t* Qw = Qp + bank + wbase;
    const ushort_t* Kw = Kp + bank + wbase;
    const ushort_t* Vw = Vp + bank + wbase;

    short8 kf[8], qf[4];
    #pragma unroll
    for (int i = 0; i < 8; ++i)
        kf[i] = *(const short8*)(Kw + (size_t)(16 * i + q) * 96 + hch + 8 * g);
    #pragma unroll
    for (int jj = 0; jj < 4; ++jj)
        qf[jj] = *(const short8*)(Qw + (size_t)(16 * (jbase + jj) + q) * 96 + hch + 8 * g);
    short8 vf[2][4];
    {
        #pragma unroll
        for (int s = 0; s < 4; ++s) {
            #pragma unroll
            for (int dblk = 0; dblk < 2; ++dblk) {
                uint4v wv;
                #pragma unroll
                for (int e2 = 0; e2 < 4; ++e2) {
                    size_t base = (size_t)(32 * s + 8 * g + 2 * e2) * 96 + hch + 16 * dblk + q;
                    unsigned lo = Vw[base];
                    unsigned hi = Vw[base + 96];
                    wv[e2] = lo | (hi << 16);
                }
                vf[dblk][s] = *(short8*)&wv;
            }
        }
    }

    const float SC = 0.5303300858899106f;   // 3/sqrt(32)
    const int src0 = q + ((g & 1) << 5);
    const bool thi = (g >> 1) != 0;
    const bool glo = (g < 2);
    #pragma unroll
    for (int jj = 0; jj < 4; ++jj) {
        const int j = jbase + jj;
        unsigned wA[8], wB[8];
        float ss = 0.0f;
        #pragma unroll
        for (int i = 0; i < 8; ++i) {
            f32x4 z = {};
            f32x4 S = __builtin_amdgcn_mfma_f32_16x16x32_bf16(kf[i], qf[jj], z, 0, 0, 0);
            float p0 = __expf(S[0] * SC), p1 = __expf(S[1] * SC);
            float p2 = __expf(S[2] * SC), p3 = __expf(S[3] * SC);
            ss += (p0 + p1) + (p2 + p3);
            wA[i] = pk2(p0, p1);
            wB[i] = pk2(p2, p3);
        }
        ss += __shfl_xor(ss, 16);
        ss += __shfl_xor(ss, 32);
        int l_own;
        if (branch == 0) l_own = (hb + j) * Wn + wb + q;
        else             l_own = (hb + 2 * j + (q >> 3)) * Wn + wb + (q & 7);
        float s_own = 3.0f * gate_s[(size_t)b * Ln + l_own] / ss;

        f32x4 O0 = {}, O1 = {};
        #pragma unroll
        for (int s = 0; s < 4; ++s) {
            unsigned a0  = (unsigned)__shfl((int)wA[2*s],     src0);
            unsigned b0  = (unsigned)__shfl((int)wB[2*s],     src0);
            unsigned a0h = (unsigned)__shfl((int)wA[2*s],     src0 + 16);
            unsigned b0h = (unsigned)__shfl((int)wB[2*s],     src0 + 16);
            unsigned a1  = (unsigned)__shfl((int)wA[2*s+1],   src0);
            unsigned b1  = (unsigned)__shfl((int)wB[2*s+1],   src0);
            unsigned a1h = (unsigned)__shfl((int)wA[2*s+1],   src0 + 16);
            unsigned b1h = (unsigned)__shfl((int)wB[2*s+1],   src0 + 16);
            uint4v B2u;
            B2u[0] = thi ? a1  : a0;
            B2u[1] = thi ? b1  : b0;
            B2u[2] = thi ? a1h : a0h;
            B2u[3] = thi ? b1h : b0h;
            short8 B2 = *(short8*)&B2u;
            O0 = __builtin_amdgcn_mfma_f32_16x16x32_bf16(vf[0][s], B2, O0, 0, 0, 0);
            O1 = __builtin_amdgcn_mfma_f32_16x16x32_bf16(vf[1][s], B2, O1, 0, 0, 0);
        }
        unsigned w0 = pk2(O0[0] * s_own, O0[1] * s_own);
        unsigned w1 = pk2(O0[2] * s_own, O0[3] * s_own);
        unsigned w2 = pk2(O1[0] * s_own, O1[1] * s_own);
        unsigned w3 = pk2(O1[2] * s_own, O1[3] * s_own);
        unsigned a0 = (unsigned)__shfl((int)w0, src0);
        unsigned a1 = (unsigned)__shfl((int)w1, src0);
        unsigned b0 = (unsigned)__shfl((int)w0, src0 + 16);
        unsigned b1 = (unsigned)__shfl((int)w1, src0 + 16);
        unsigned c0 = (unsigned)__shfl((int)w2, src0);
        unsigned c1 = (unsigned)__shfl((int)w3, src0);
        unsigned d0 = (unsigned)__shfl((int)w2, src0 + 16);
        unsigned d1 = (unsigned)__shfl((int)w3, src0 + 16);
        uint4 o = make_uint4(glo ? a0 : c0, glo ? a1 : c1,
                             glo ? b0 : d0, glo ? b1 : d1);
        *(uint4*)(fu_b + (size_t)(b * Ln + l_own) * 192 + cf + 8 * g) = o;
    }
}

// ---- conv1: dwconv3x3+BN+GELU, half-plane blocks, batched register loads ---
// grid (Bn*192, 2). Thread: 4-px strip x 8-row band; 10 row-loads issued
// upfront into r[10][6] (no serial chain). Pooled as 2 per-plane partials.
__global__ __launch_bounds__(256) void conv1_k(const float* __restrict__ x,
        const float* __restrict__ wdw, const float* __restrict__ bdw,
        const float* __restrict__ g1, const float* __restrict__ be1,
        ushort_t* __restrict__ conv1b, ushort_t* __restrict__ xb,
        float* __restrict__ pooled2)
{
    int bc = blockIdx.x;                   // b*192 + c
    int half = blockIdx.y;                 // 0/1
    int c = bc % 192;
    const float* plane = x + (size_t)bc * Ln;
    ushort_t* oplane = conv1b + (size_t)bc * Ln;
    ushort_t* xplane = xb + (size_t)bc * Ln;
    int t = threadIdx.x;
    int sx = t & 31, sy = t >> 5;          // 32 strips x 8 bands
    int w0 = sx * 4, h0 = half * 64 + sy * 8;
    float wk[9];
    #pragma unroll
    for (int i = 0; i < 9; ++i) wk[i] = wdw[c * 9 + i];
    float gb = g1[c] * BN_RSQ, bb = be1[c], bd = bdw[c];

    float r[10][6];
    #pragma unroll
    for (int i = 0; i < 10; ++i) {
        int h = h0 - 1 + i;
        if (h < 0 || h >= Hn) {
            r[i][0] = r[i][1] = r[i][2] = r[i][3] = r[i][4] = r[i][5] = 0.0f;
        } else {
            const float* rp = plane + h * Wn;
            float4 m = *(const float4*)(rp + w0);
            r[i][0] = sx ? rp[w0 - 1] : 0.0f;
            r[i][1] = m.x; r[i][2] = m.y; r[i][3] = m.z; r[i][4] = m.w;
            r[i][5] = (sx < 31) ? rp[w0 + 4] : 0.0f;
        }
    }
    float psum = 0.0f;
    #pragma unroll
    for (int i = 0; i < 8; ++i) {
        int h = h0 + i;
        *(uint2*)(xplane + h * Wn + w0) =
            make_uint2(pk2(r[i+1][1], r[i+1][2]), pk2(r[i+1][3], r[i+1][4]));
        float o[4];
        #pragma unroll
        for (int p = 0; p < 4; ++p) {
            float s = wk[0] * r[i][p];
            s = fmaf(wk[1], r[i][p + 1], s);
            s = fmaf(wk[2], r[i][p + 2], s);
            s = fmaf(wk[3], r[i+1][p],     s);
            s = fmaf(wk[4], r[i+1][p + 1], s);
            s = fmaf(wk[5], r[i+1][p + 2], s);
            s = fmaf(wk[6], r[i+2][p],     s);
            s = fmaf(wk[7], r[i+2][p + 1], s);
            s = fmaf(wk[8], r[i+2][p + 2], s);
            float y = gelu_f((s + bd) * gb + bb);
            psum += y;
            o[p] = y;
        }
        *(uint2*)(oplane + h * Wn + w0) =
            make_uint2(pk2(o[0], o[1]), pk2(o[2], o[3]));
    }
    __shared__ float red[4];
    for (int off = 32; off; off >>= 1) psum += __shfl_down(psum, off);
    if ((t & 63) == 0) red[t >> 6] = psum;
    __syncthreads();
    if (t == 0)
        pooled2[bc * 2 + half] = red[0] + red[1] + red[2] + red[3];
}

// ------- spatial gate: per-pixel 192->24->1 MLP on bf16 conv1 ---------------
__global__ __launch_bounds__(128) void spatial_gate_k(const ushort_t* __restrict__ conv1b,
        const float* __restrict__ ws1g, const float* __restrict__ bs1,
        const float* __restrict__ gsi, const float* __restrict__ besi,
        const float* __restrict__ ws2, const float* __restrict__ bs2,
        float* __restrict__ gate_s)
{
    int bh = blockIdx.x;                   // b*128 + h
    int b = bh >> 7, h = bh & 127;
    int w = threadIdx.x;
    __shared__ float ws1T[192 * 24];       // [c][o]
    for (int i = w; i < 192 * 24; i += 128) {
        int c = i / 24, o = i - c * 24;
        ws1T[i] = ws1g[o * 192 + c];
    }
    __syncthreads();
    float acc24[24] = {};
    const ushort_t* base = conv1b + (size_t)b * 192 * Ln + h * Wn + w;
    #pragma unroll 4
    for (int c = 0; c < 192; ++c) {
        float v = bf2f(base[(size_t)c * Ln]);
        const float4* wp = (const float4*)&ws1T[c * 24];
        #pragma unroll
        for (int o4 = 0; o4 < 6; ++o4) {
            float4 wv = wp[o4];
            acc24[o4*4+0] = fmaf(v, wv.x, acc24[o4*4+0]);
            acc24[o4*4+1] = fmaf(v, wv.y, acc24[o4*4+1]);
            acc24[o4*4+2] = fmaf(v, wv.z, acc24[o4*4+2]);
            acc24[o4*4+3] = fmaf(v, wv.w, acc24[o4*4+3]);
        }
    }
    float s2 = bs2[0];
    #pragma unroll
    for (int o = 0; o < 24; ++o)
        s2 = fmaf(gelu_f((acc24[o] + bs1[o]) * (gsi[o] * BN_RSQ) + besi[o]), ws2[o], s2);
    gate_s[(size_t)bh * 128 + w] = gate1p(s2);
}

// ------ channel gate: combine pooled halves + 192->24->192, 1+sigmoid ------
__global__ __launch_bounds__(192) void channel_gate_k(const float* __restrict__ pooled2,
        const float* __restrict__ w1, const float* __restrict__ b1,
        const float* __restrict__ g, const float* __restrict__ be,
        const float* __restrict__ w2, const float* __restrict__ b2,
        float* __restrict__ gate_c)
{
    int b = blockIdx.x, t = threadIdx.x;
    __shared__ float pl[192];
    __shared__ float h1[24];
    int bc = b * 192 + t;
    pl[t] = (pooled2[bc * 2] + pooled2[bc * 2 + 1]) * (1.0f / Ln);
    __syncthreads();
    if (t < 24) {
        float a = b1[t];
        for (int c = 0; c < 192; ++c) a = fmaf(pl[c], w1[t * 192 + c], a);
        a = a * (g[t] * BN_RSQ) + be[t];
        h1[t] = gelu_f(a);
    }
    __syncthreads();
    float a = b2[t];
    #pragma unroll
    for (int o = 0; o < 24; ++o) a = fmaf(h1[o], w2[t * 24 + o], a);
    gate_c[b * 192 + t] = gate1p(a);
}

// ---- dwconv2: channels-last register 3x3 stencil on gated bf16 fu ----------
__global__ __launch_bounds__(256) void dwconv2_k(const ushort_t* __restrict__ fu_b,
        const float* __restrict__ gate_c,
        const float* __restrict__ wdw, const float* __restrict__ bdw,
        const float* __restrict__ g2, const float* __restrict__ be2,
        ushort_t* __restrict__ out2b)
{
    int bh = blockIdx.x >> 1;              // b*128 + h
    int whalf = blockIdx.x & 1;
    int b = bh >> 7, h = bh & 127;
    int tid = threadIdx.x;
    __shared__ float cw[192 * 9];
    __shared__ float cbd[192], cgb[192], cbe[192], cgc[192];
    for (int i = tid; i < 192 * 9; i += 256) cw[i] = wdw[i];
    for (int i = tid; i < 192; i += 256) {
        cbd[i] = bdw[i];
        cgb[i] = g2[i] * BN_RSQ;
        cbe[i] = be2[i];
        cgc[i] = gate_c[b * 192 + i];
    }
    __syncthreads();
    const size_t outrow = (size_t)(b * Ln + h * Wn) * 192;
    for (int it = 0; it < 6; ++it) {
        int item = it * 256 + tid;          // 0..1535
        int w = whalf * 64 + item / 24;
        int c8 = item % 24;
        int co = c8 * 8;
        uint4 nb[3][3];
        #pragma unroll
        for (int r = 0; r < 3; ++r)
            #pragma unroll
            for (int d = 0; d < 3; ++d)
                nb[r][d] = make_uint4(0u, 0u, 0u, 0u);
        #pragma unroll
        for (int r = 0; r < 3; ++r) {
            int hh = h - 1 + r;
            if (hh < 0 || hh >= Hn) continue;
            const ushort_t* rp = fu_b + (size_t)(b * Ln + hh * Wn) * 192 + co;
            #pragma unroll
            for (int d = 0; d < 3; ++d) {
                int w2 = w - 1 + d;
                if (w2 < 0 || w2 >= Wn) continue;
                nb[r][d] = *(const uint4*)(rp + (size_t)w2 * 192);
            }
        }
        unsigned ou[4];
        #pragma unroll
        for (int i = 0; i < 8; ++i) {
            int c = co + i;
            float s = 0.0f;
            #pragma unroll
            for (int r = 0; r < 3; ++r) {
                #pragma unroll
                for (int d = 0; d < 3; ++d) {
                    unsigned word = ((const unsigned*)&nb[r][d])[i >> 1];
                    float v = __uint_as_float((i & 1) ? (word & 0xffff0000u)
                                                      : (word << 16));
                    s = fmaf(cw[c * 9 + r * 3 + d], v, s);
                }
            }
            float y = gelu_f((s + cbd[c]) * cgb[c] + cbe[c]) * cgc[c];
            if (i & 1) ou[i >> 1] |= (unsigned)f2bf(y) << 16;
            else       ou[i >> 1] = (unsigned)f2bf(y);
        }
        *(uint4*)(out2b + outrow + (size_t)w * 192 + co) =
            make_uint4(ou[0], ou[1], ou[2], ou[3]);
    }
}

extern "C" void kernel_launch(void* const* d_in, const int* in_sizes, int n_in,
                              void* d_out, int out_size, void* d_ws, size_t ws_size,
                              hipStream_t stream) {
    (void)in_sizes; (void)n_in; (void)out_size; (void)ws_size;
    const float* x      = (const float*)d_in[0];
    const float* w_qkv  = (const float*)d_in[1];
    const float* b_qkv  = (const float*)d_in[2];
    const float* w_dw1  = (const float*)d_in[3];
    const float* b_dw1  = (const float*)d_in[4];
    const float* g_bn1  = (const float*)d_in[5];
    const float* be_bn1 = (const float*)d_in[6];
    const float* w_si1  = (const float*)d_in[7];
    const float* b_si1  = (const float*)d_in[8];
    const float* g_si   = (const float*)d_in[9];
    const float* be_si  = (const float*)d_in[10];
    const float* w_si2  = (const float*)d_in[11];
    const float* b_si2  = (const float*)d_in[12];
    const float* w_ci1  = (const float*)d_in[13];
    const float* b_ci1  = (const float*)d_in[14];
    const float* g_ci   = (const float*)d_in[15];
    const float* be_ci  = (const float*)d_in[16];
    const float* w_ci2  = (const float*)d_in[17];
    const float* b_ci2  = (const float*)d_in[18];
    const float* w_dw2  = (const float*)d_in[19];
    const float* b_dw2  = (const float*)d_in[20];
    const float* g_bn2  = (const float*)d_in[21];
    const float* be_bn2 = (const float*)d_in[22];
    const float* w_proj = (const float*)d_in[23];
    const float* b_proj = (const float*)d_in[24];

    // ws (f32 units):
    //   phase A: conv1b bf16 [0, FUn/2)                  [conv1 -> spatial_gate]
    //   phase B: Qp [0, FUn/2), Kp [FUn/2, FUn) bf16 (2 banks each)  [qkv -> attn]
    //   phase C: out2b bf16 [8M, 8M+FUn/2)               [dwconv2 -> proj]
    //   smalls at FUn: gate_s, gate_c, pooled2
    // d_out (shorts, 2*FUn total):
    //   xb [0, FUn) [conv1 -> qkv], then fu_b [0, FUn) [attn -> dwconv2]
    //   Vp [FUn, 2*FUn) (2 banks) [qkv -> attn]; proj overwrites all (f32).
    float* ws = (float*)d_ws;
    ushort_t* conv1b = (ushort_t*)ws;
    ushort_t* Qp     = (ushort_t*)ws;
    ushort_t* Kp     = (ushort_t*)(ws + FUn / 2);
    ushort_t* out2b  = (ushort_t*)(ws + 8000000);
    float* gate_s    = ws + FUn;                       // B*L
    float* gate_c    = gate_s + (size_t)Bn * Ln;       // B*192
    float* pooled2   = gate_c + Bn * 192;              // B*192*2
    ushort_t* xb     = (ushort_t*)d_out;
    ushort_t* fu_b   = (ushort_t*)d_out;
    ushort_t* Vp     = (ushort_t*)d_out + FUn;

    conv1_k<<<dim3(Bn * 192, 2), 256, 0, stream>>>(x, w_dw1, b_dw1, g_bn1, be_bn1,
                                                   conv1b, xb, pooled2);
    spatial_gate_k<<<Bn * Hn, 128, 0, stream>>>(conv1b, w_si1, b_si1, g_si, be_si,
                                                w_si2, b_si2, gate_s);
    channel_gate_k<<<Bn, 192, 0, stream>>>(pooled2, w_ci1, b_ci1, g_ci, be_ci,
                                           w_ci2, b_ci2, gate_c);
    qkv_mfma<<<dim3(Mn / 128, 6), 256, 0, stream>>>(xb, w_qkv, b_qkv, Qp, Kp, Vp);
    attn_mfma<<<3072, 256, 0, stream>>>(Qp, Kp, Vp, gate_s, fu_b);
    dwconv2_k<<<Bn * Hn * 2, 256, 0, stream>>>(fu_b, gate_c,
                                               w_dw2, b_dw2, g_bn2, be_bn2, out2b);
    proj_mfma<<<dim3(Mn / 128, 2), 256, 0, stream>>>(out2b, w_proj, b_proj, (float*)d_out);
}

// Round 13
// 315.016 us; speedup vs baseline: 4.2441x; 1.1303x over previous
//
#include <hip/hip_runtime.h>

#define Bn 8
#define Hn 128
#define Wn 128
#define Cn 192
#define Ln (Hn*Wn)          // 16384
#define Mn (Bn*Ln)          // 131072
#define FUn ((size_t)Mn*Cn) // 25,165,824 floats
#define BANKn ((size_t)Mn*96) // shorts per branch-bank
#define BN_RSQ 0.9999950000374997f   // 1/sqrt(1+1e-5)

typedef unsigned short ushort_t;
typedef __attribute__((ext_vector_type(8))) short short8;
typedef __attribute__((ext_vector_type(4))) float f32x4;
typedef __attribute__((ext_vector_type(4))) unsigned int uint4v;

static __device__ __forceinline__ float gelu_f(float x) {
    return 0.5f * x * (1.0f + erff(x * 0.7071067811865475f));
}
static __device__ __forceinline__ float gate1p(float x) {  // 1 + sigmoid(x)
    return 1.0f + 1.0f / (1.0f + __expf(-x));
}
static __device__ __forceinline__ unsigned short f2bf(float f) {  // RNE
    unsigned u = __float_as_uint(f);
    return (unsigned short)((u + 0x7FFFu + ((u >> 16) & 1u)) >> 16);
}
static __device__ __forceinline__ unsigned int pk2(float lo, float hi) {
    return (unsigned int)f2bf(lo) | ((unsigned int)f2bf(hi) << 16);
}
static __device__ __forceinline__ float bf2f(ushort_t u) {
    return __uint_as_float((unsigned)u << 16);
}

// ========== qkv GEMM (bf16 A; all 576 cols) -> window-contiguous Q/K/V =====
__global__ __launch_bounds__(256) void qkv_mfma(const ushort_t* __restrict__ Ab,
        const float* __restrict__ Bw, const float* __restrict__ bias,
        ushort_t* __restrict__ Qp, ushort_t* __restrict__ Kp,
        ushort_t* __restrict__ Vp)
{
    __shared__ __align__(16) ushort_t As[128 * 64];
    __shared__ __align__(16) ushort_t Bs[96 * 64];
    const int m0 = blockIdx.x * 128;
    const int n0g = blockIdx.y * 96;                  // 0..480
    const int part = n0g / 192;
    const int coln = n0g - part * 192;                // 0 or 96 (block-uniform)
    ushort_t* dst = part == 0 ? Qp : (part == 1 ? Kp : Vp);
    ushort_t* bptr = dst + (coln ? BANKn : 0);
    const int tid = threadIdx.x;
    const int lane = tid & 63;
    const int wrow = (tid >> 6) * 32;
    const int r0 = lane >> 4, cl = lane & 15;
    f32x4 acc[2][6] = {};

    for (int ks = 0; ks < 3; ++ks) {
        const int k0 = ks * 64;
        if (ks) __syncthreads();
        #pragma unroll
        for (int i = 0; i < 2; ++i) {
            int s = tid + i * 256;
            int row = s >> 2, q = s & 3;
            const ushort_t* src = Ab + (size_t)(m0 + row) * 192 + k0 + q * 16;
            uint4 u0 = *(const uint4*)(src);
            uint4 u1 = *(const uint4*)(src + 8);
            int r7 = row & 7;
            *(uint4*)&As[row * 64 + (((q * 2) ^ r7) * 8)] = u0;
            *(uint4*)&As[row * 64 + (((q * 2 + 1) ^ r7) * 8)] = u1;
        }
        #pragma unroll
        for (int i = 0; i < 3; ++i) {
            int f = tid + i * 256;                    // 0..767
            int col = f % 96, kslot = f / 96;
            uint4v wv;
            #pragma unroll
            for (int e2 = 0; e2 < 4; ++e2) {
                float lo = Bw[(size_t)(k0 + kslot * 8 + 2 * e2)     * 576 + n0g + col];
                float hi = Bw[(size_t)(k0 + kslot * 8 + 2 * e2 + 1) * 576 + n0g + col];
                wv[e2] = pk2(lo, hi);
            }
            *(uint4v*)&Bs[col * 64 + ((kslot ^ (col & 7)) * 8)] = wv;
        }
        __syncthreads();
        #pragma unroll
        for (int kk = 0; kk < 2; ++kk) {
            int kslot = kk * 4 + r0;
            int ra0 = wrow + cl, ra1 = wrow + 16 + cl;
            short8 a0 = *(const short8*)&As[ra0 * 64 + ((kslot ^ (ra0 & 7)) * 8)];
            short8 a1 = *(const short8*)&As[ra1 * 64 + ((kslot ^ (ra1 & 7)) * 8)];
            #pragma unroll
            for (int n = 0; n < 6; ++n) {
                int col = n * 16 + cl;
                short8 bn = *(const short8*)&Bs[col * 64 + ((kslot ^ (col & 7)) * 8)];
                acc[0][n] = __builtin_amdgcn_mfma_f32_16x16x32_bf16(a0, bn, acc[0][n], 0, 0, 0);
                acc[1][n] = __builtin_amdgcn_mfma_f32_16x16x32_bf16(a1, bn, acc[1][n], 0, 0, 0);
            }
        }
    }
    float bv[6];
    #pragma unroll
    for (int n = 0; n < 6; ++n) bv[n] = bias[n0g + n * 16 + cl];
    #pragma unroll
    for (int m = 0; m < 2; ++m) {
        #pragma unroll
        for (int j = 0; j < 4; ++j) {
            int row = m0 + wrow + m * 16 + r0 * 4 + j;
            int b = row >> 14, l = row & 16383;
            int h = l >> 7, w = l & 127;
            int win, t;
            if (coln == 0) { win = (h >> 3) * 8 + (w >> 4);  t = (h & 7) * 16 + (w & 15); }
            else           { win = (h >> 4) * 16 + (w >> 3); t = (h & 15) * 8 + (w & 7); }
            size_t rbase = ((size_t)((b * 128 + win) * 128 + t)) * 96;
            #pragma unroll
            for (int n = 0; n < 6; ++n)
                bptr[rbase + n * 16 + cl] = f2bf(acc[m][n][j] + bv[n]);
        }
    }
}

// =================== proj GEMM: bf16 A (row-major) x f32 Bw -> f32 out ======
__global__ __launch_bounds__(256) void proj_mfma(const ushort_t* __restrict__ Ab,
        const float* __restrict__ Bw, const float* __restrict__ bias,
        float* __restrict__ Cout)
{
    __shared__ __align__(16) ushort_t As[128 * 64];
    __shared__ __align__(16) ushort_t Bs[96 * 64];
    const int m0 = blockIdx.x * 128;
    const int n0 = blockIdx.y * 96;
    const int tid = threadIdx.x;
    const int lane = tid & 63;
    const int wrow = (tid >> 6) * 32;
    const int r0 = lane >> 4, cl = lane & 15;
    f32x4 acc[2][6] = {};

    for (int ks = 0; ks < 3; ++ks) {
        const int k0 = ks * 64;
        if (ks) __syncthreads();
        #pragma unroll
        for (int i = 0; i < 2; ++i) {
            int s = tid + i * 256;
            int row = s >> 2, q = s & 3;
            const ushort_t* src = Ab + (size_t)(m0 + row) * 192 + k0 + q * 16;
            uint4 u0 = *(const uint4*)(src);
            uint4 u1 = *(const uint4*)(src + 8);
            int r7 = row & 7;
            *(uint4*)&As[row * 64 + (((q * 2) ^ r7) * 8)] = u0;
            *(uint4*)&As[row * 64 + (((q * 2 + 1) ^ r7) * 8)] = u1;
        }
        #pragma unroll
        for (int i = 0; i < 3; ++i) {
            int f = tid + i * 256;
            int col = f % 96, kslot = f / 96;
            uint4v wv;
            #pragma unroll
            for (int e2 = 0; e2 < 4; ++e2) {
                float lo = Bw[(size_t)(k0 + kslot * 8 + 2 * e2)     * 192 + n0 + col];
                float hi = Bw[(size_t)(k0 + kslot * 8 + 2 * e2 + 1) * 192 + n0 + col];
                wv[e2] = pk2(lo, hi);
            }
            *(uint4v*)&Bs[col * 64 + ((kslot ^ (col & 7)) * 8)] = wv;
        }
        __syncthreads();
        #pragma unroll
        for (int kk = 0; kk < 2; ++kk) {
            int kslot = kk * 4 + r0;
            int ra0 = wrow + cl, ra1 = wrow + 16 + cl;
            short8 a0 = *(const short8*)&As[ra0 * 64 + ((kslot ^ (ra0 & 7)) * 8)];
            short8 a1 = *(const short8*)&As[ra1 * 64 + ((kslot ^ (ra1 & 7)) * 8)];
            #pragma unroll
            for (int n = 0; n < 6; ++n) {
                int col = n * 16 + cl;
                short8 bn = *(const short8*)&Bs[col * 64 + ((kslot ^ (col & 7)) * 8)];
                acc[0][n] = __builtin_amdgcn_mfma_f32_16x16x32_bf16(a0, bn, acc[0][n], 0, 0, 0);
                acc[1][n] = __builtin_amdgcn_mfma_f32_16x16x32_bf16(a1, bn, acc[1][n], 0, 0, 0);
            }
        }
    }
    #pragma unroll
    for (int m = 0; m < 2; ++m) {
        #pragma unroll
        for (int n = 0; n < 6; ++n) {
            int col = n0 + n * 16 + cl;
            float bv = bias[col];
            #pragma unroll
            for (int j = 0; j < 4; ++j) {
                int row = m0 + wrow + m * 16 + r0 * 4 + j;
                Cout[(size_t)row * 192 + col] = acc[m][n][j] + bv;
            }
        }
    }
}

// ===== MFMA window attention, j-split: wave = (win, head, query-half) ======
__global__ __launch_bounds__(256) void attn_mfma(const ushort_t* __restrict__ Qp,
        const ushort_t* __restrict__ Kp, const ushort_t* __restrict__ Vp,
        const float* __restrict__ gate_s, ushort_t* __restrict__ fu_b)
{
    const int widx = threadIdx.x >> 6;
    const int idx = blockIdx.x * 4 + widx;          // 0..12287
    const int jhalf = idx & 1;                      // sibling waves share a block
    const int sub0 = idx >> 1;                      // 0..6143
    const int branch = (sub0 >= 3072) ? 1 : 0;
    const int sub = sub0 - branch * 3072;
    const int head = sub >> 10;
    const int b = (sub >> 7) & 7;
    const int win = sub & 127;
    const int L = threadIdx.x & 63;
    const int g = L >> 4, q = L & 15;
    int hb, wb;
    if (branch == 0) { hb = (win >> 3) * 8;  wb = (win & 7) * 16; }
    else             { hb = (win >> 4) * 16; wb = (win & 15) * 8; }
    const int cf = branch * 96 + head * 32;         // fu channel base
    const int hch = head * 32;                      // in-bank channel base
    const int jbase = jhalf * 4;

    const size_t bank = branch ? BANKn : 0;
    const size_t wbase = ((size_t)((b * 128 + win) * 128)) * 96;
    const ushort_t* Qw = Qp + bank + wbase;
    const ushort_t* Kw = Kp + bank + wbase;
    const ushort_t* Vw = Vp + bank + wbase;

    short8 kf[8], qf[4];
    #pragma unroll
    for (int i = 0; i < 8; ++i)
        kf[i] = *(const short8*)(Kw + (size_t)(16 * i + q) * 96 + hch + 8 * g);
    #pragma unroll
    for (int jj = 0; jj < 4; ++jj)
        qf[jj] = *(const short8*)(Qw + (size_t)(16 * (jbase + jj) + q) * 96 + hch + 8 * g);
    short8 vf[2][4];
    {
        #pragma unroll
        for (int s = 0; s < 4; ++s) {
            #pragma unroll
            for (int dblk = 0; dblk < 2; ++dblk) {
                uint4v wv;
                #pragma unroll
                for (int e2 = 0; e2 < 4; ++e2) {
                    size_t base = (size_t)(32 * s + 8 * g + 2 * e2) * 96 + hch + 16 * dblk + q;
                    unsigned lo = Vw[base];
                    unsigned hi = Vw[base + 96];
                    wv[e2] = lo | (hi << 16);
                }
                vf[dblk][s] = *(short8*)&wv;
            }
        }
    }

    const float SC = 0.5303300858899106f;   // 3/sqrt(32)
    const int src0 = q + ((g & 1) << 5);
    const bool thi = (g >> 1) != 0;
    const bool glo = (g < 2);
    #pragma unroll
    for (int jj = 0; jj < 4; ++jj) {
        const int j = jbase + jj;
        unsigned wA[8], wB[8];
        float ss = 0.0f;
        #pragma unroll
        for (int i = 0; i < 8; ++i) {
            f32x4 z = {};
            f32x4 S = __builtin_amdgcn_mfma_f32_16x16x32_bf16(kf[i], qf[jj], z, 0, 0, 0);
            float p0 = __expf(S[0] * SC), p1 = __expf(S[1] * SC);
            float p2 = __expf(S[2] * SC), p3 = __expf(S[3] * SC);
            ss += (p0 + p1) + (p2 + p3);
            wA[i] = pk2(p0, p1);
            wB[i] = pk2(p2, p3);
        }
        ss += __shfl_xor(ss, 16);
        ss += __shfl_xor(ss, 32);
        int l_own;
        if (branch == 0) l_own = (hb + j) * Wn + wb + q;
        else             l_own = (hb + 2 * j + (q >> 3)) * Wn + wb + (q & 7);
        float s_own = 3.0f * gate_s[(size_t)b * Ln + l_own] / ss;

        f32x4 O0 = {}, O1 = {};
        #pragma unroll
        for (int s = 0; s < 4; ++s) {
            unsigned a0  = (unsigned)__shfl((int)wA[2*s],     src0);
            unsigned b0  = (unsigned)__shfl((int)wB[2*s],     src0);
            unsigned a0h = (unsigned)__shfl((int)wA[2*s],     src0 + 16);
            unsigned b0h = (unsigned)__shfl((int)wB[2*s],     src0 + 16);
            unsigned a1  = (unsigned)__shfl((int)wA[2*s+1],   src0);
            unsigned b1  = (unsigned)__shfl((int)wB[2*s+1],   src0);
            unsigned a1h = (unsigned)__shfl((int)wA[2*s+1],   src0 + 16);
            unsigned b1h = (unsigned)__shfl((int)wB[2*s+1],   src0 + 16);
            uint4v B2u;
            B2u[0] = thi ? a1  : a0;
            B2u[1] = thi ? b1  : b0;
            B2u[2] = thi ? a1h : a0h;
            B2u[3] = thi ? b1h : b0h;
            short8 B2 = *(short8*)&B2u;
            O0 = __builtin_amdgcn_mfma_f32_16x16x32_bf16(vf[0][s], B2, O0, 0, 0, 0);
            O1 = __builtin_amdgcn_mfma_f32_16x16x32_bf16(vf[1][s], B2, O1, 0, 0, 0);
        }
        unsigned w0 = pk2(O0[0] * s_own, O0[1] * s_own);
        unsigned w1 = pk2(O0[2] * s_own, O0[3] * s_own);
        unsigned w2 = pk2(O1[0] * s_own, O1[1] * s_own);
        unsigned w3 = pk2(O1[2] * s_own, O1[3] * s_own);
        unsigned a0 = (unsigned)__shfl((int)w0, src0);
        unsigned a1 = (unsigned)__shfl((int)w1, src0);
        unsigned b0 = (unsigned)__shfl((int)w0, src0 + 16);
        unsigned b1 = (unsigned)__shfl((int)w1, src0 + 16);
        unsigned c0 = (unsigned)__shfl((int)w2, src0);
        unsigned c1 = (unsigned)__shfl((int)w3, src0);
        unsigned d0 = (unsigned)__shfl((int)w2, src0 + 16);
        unsigned d1 = (unsigned)__shfl((int)w3, src0 + 16);
        uint4 o = make_uint4(glo ? a0 : c0, glo ? a1 : c1,
                             glo ? b0 : d0, glo ? b1 : d1);
        *(uint4*)(fu_b + (size_t)(b * Ln + l_own) * 192 + cf + 8 * g) = o;
    }
}

// ---- conv1: dwconv3x3+BN+GELU, half-plane blocks, batched register loads ---
__global__ __launch_bounds__(256) void conv1_k(const float* __restrict__ x,
        const float* __restrict__ wdw, const float* __restrict__ bdw,
        const float* __restrict__ g1, const float* __restrict__ be1,
        ushort_t* __restrict__ conv1b, ushort_t* __restrict__ xb,
        float* __restrict__ pooled2)
{
    int bc = blockIdx.x;                   // b*192 + c
    int half = blockIdx.y;                 // 0/1
    int c = bc % 192;
    const float* plane = x + (size_t)bc * Ln;
    ushort_t* oplane = conv1b + (size_t)bc * Ln;
    ushort_t* xplane = xb + (size_t)bc * Ln;
    int t = threadIdx.x;
    int sx = t & 31, sy = t >> 5;          // 32 strips x 8 bands
    int w0 = sx * 4, h0 = half * 64 + sy * 8;
    float wk[9];
    #pragma unroll
    for (int i = 0; i < 9; ++i) wk[i] = wdw[c * 9 + i];
    float gb = g1[c] * BN_RSQ, bb = be1[c], bd = bdw[c];

    float r[10][6];
    #pragma unroll
    for (int i = 0; i < 10; ++i) {
        int h = h0 - 1 + i;
        if (h < 0 || h >= Hn) {
            r[i][0] = r[i][1] = r[i][2] = r[i][3] = r[i][4] = r[i][5] = 0.0f;
        } else {
            const float* rp = plane + h * Wn;
            float4 m = *(const float4*)(rp + w0);
            r[i][0] = sx ? rp[w0 - 1] : 0.0f;
            r[i][1] = m.x; r[i][2] = m.y; r[i][3] = m.z; r[i][4] = m.w;
            r[i][5] = (sx < 31) ? rp[w0 + 4] : 0.0f;
        }
    }
    float psum = 0.0f;
    #pragma unroll
    for (int i = 0; i < 8; ++i) {
        int h = h0 + i;
        *(uint2*)(xplane + h * Wn + w0) =
            make_uint2(pk2(r[i+1][1], r[i+1][2]), pk2(r[i+1][3], r[i+1][4]));
        float o[4];
        #pragma unroll
        for (int p = 0; p < 4; ++p) {
            float s = wk[0] * r[i][p];
            s = fmaf(wk[1], r[i][p + 1], s);
            s = fmaf(wk[2], r[i][p + 2], s);
            s = fmaf(wk[3], r[i+1][p],     s);
            s = fmaf(wk[4], r[i+1][p + 1], s);
            s = fmaf(wk[5], r[i+1][p + 2], s);
            s = fmaf(wk[6], r[i+2][p],     s);
            s = fmaf(wk[7], r[i+2][p + 1], s);
            s = fmaf(wk[8], r[i+2][p + 2], s);
            float y = gelu_f((s + bd) * gb + bb);
            psum += y;
            o[p] = y;
        }
        *(uint2*)(oplane + h * Wn + w0) =
            make_uint2(pk2(o[0], o[1]), pk2(o[2], o[3]));
    }
    __shared__ float red[4];
    for (int off = 32; off; off >>= 1) psum += __shfl_down(psum, off);
    if ((t & 63) == 0) red[t >> 6] = psum;
    __syncthreads();
    if (t == 0)
        pooled2[bc * 2 + half] = red[0] + red[1] + red[2] + red[3];
}

// ------- spatial gate: per-pixel 192->24->1 MLP on bf16 conv1 ---------------
__global__ __launch_bounds__(128) void spatial_gate_k(const ushort_t* __restrict__ conv1b,
        const float* __restrict__ ws1g, const float* __restrict__ bs1,
        const float* __restrict__ gsi, const float* __restrict__ besi,
        const float* __restrict__ ws2, const float* __restrict__ bs2,
        float* __restrict__ gate_s)
{
    int bh = blockIdx.x;                   // b*128 + h
    int b = bh >> 7, h = bh & 127;
    int w = threadIdx.x;
    __shared__ float ws1T[192 * 24];       // [c][o]
    for (int i = w; i < 192 * 24; i += 128) {
        int c = i / 24, o = i - c * 24;
        ws1T[i] = ws1g[o * 192 + c];
    }
    __syncthreads();
    float acc24[24] = {};
    const ushort_t* base = conv1b + (size_t)b * 192 * Ln + h * Wn + w;
    #pragma unroll 4
    for (int c = 0; c < 192; ++c) {
        float v = bf2f(base[(size_t)c * Ln]);
        const float4* wp = (const float4*)&ws1T[c * 24];
        #pragma unroll
        for (int o4 = 0; o4 < 6; ++o4) {
            float4 wv = wp[o4];
            acc24[o4*4+0] = fmaf(v, wv.x, acc24[o4*4+0]);
            acc24[o4*4+1] = fmaf(v, wv.y, acc24[o4*4+1]);
            acc24[o4*4+2] = fmaf(v, wv.z, acc24[o4*4+2]);
            acc24[o4*4+3] = fmaf(v, wv.w, acc24[o4*4+3]);
        }
    }
    float s2 = bs2[0];
    #pragma unroll
    for (int o = 0; o < 24; ++o)
        s2 = fmaf(gelu_f((acc24[o] + bs1[o]) * (gsi[o] * BN_RSQ) + besi[o]), ws2[o], s2);
    gate_s[(size_t)bh * 128 + w] = gate1p(s2);
}

// ------ channel gate: combine pooled halves + 192->24->192, 1+sigmoid ------
__global__ __launch_bounds__(192) void channel_gate_k(const float* __restrict__ pooled2,
        const float* __restrict__ w1, const float* __restrict__ b1,
        const float* __restrict__ g, const float* __restrict__ be,
        const float* __restrict__ w2, const float* __restrict__ b2,
        float* __restrict__ gate_c)
{
    int b = blockIdx.x, t = threadIdx.x;
    __shared__ float pl[192];
    __shared__ float h1[24];
    int bc = b * 192 + t;
    pl[t] = (pooled2[bc * 2] + pooled2[bc * 2 + 1]) * (1.0f / Ln);
    __syncthreads();
    if (t < 24) {
        float a = b1[t];
        for (int c = 0; c < 192; ++c) a = fmaf(pl[c], w1[t * 192 + c], a);
        a = a * (g[t] * BN_RSQ) + be[t];
        h1[t] = gelu_f(a);
    }
    __syncthreads();
    float a = b2[t];
    #pragma unroll
    for (int o = 0; o < 24; ++o) a = fmaf(h1[o], w2[t * 24 + o], a);
    gate_c[b * 192 + t] = gate1p(a);
}

// ---- dwconv2: channels-last register 3x3 stencil, conflict-free LDS -------
// Per-c8 LDS block of stride 105 (105%32=9, odd): banks 9*c8%32 distinct for
// all 24 c8 -> no conflicts. Params folded to 3/channel (A, B=bd*A+be, G).
__global__ __launch_bounds__(256) void dwconv2_k(const ushort_t* __restrict__ fu_b,
        const float* __restrict__ gate_c,
        const float* __restrict__ wdw, const float* __restrict__ bdw,
        const float* __restrict__ g2, const float* __restrict__ be2,
        ushort_t* __restrict__ out2b)
{
    int bh = blockIdx.x >> 1;              // b*128 + h
    int whalf = blockIdx.x & 1;
    int b = bh >> 7, h = bh & 127;
    int tid = threadIdx.x;
    __shared__ float cwp[24 * 105];        // [c8]{72 weights, 24 params}
    for (int idx = tid; idx < 24 * 96; idx += 256) {
        int c8 = idx / 96, r = idx - c8 * 96;
        float v;
        if (r < 72) {
            int i = r / 9, p = r - i * 9;
            v = wdw[(c8 * 8 + i) * 9 + p];
        } else {
            int r2 = r - 72;
            int i = r2 / 3, j = r2 - i * 3;
            int c = c8 * 8 + i;
            float A = g2[c] * BN_RSQ;
            v = (j == 0) ? A : (j == 1) ? fmaf(bdw[c], A, be2[c])
                                        : gate_c[b * 192 + c];
        }
        cwp[c8 * 105 + r] = v;
    }
    __syncthreads();
    const size_t outrow = (size_t)(b * Ln + h * Wn) * 192;
    for (int it = 0; it < 6; ++it) {
        int item = it * 256 + tid;          // 0..1535
        int w = whalf * 64 + item / 24;
        int c8 = item % 24;
        int co = c8 * 8;
        const float* wp = &cwp[c8 * 105];
        uint4 nb[3][3];
        #pragma unroll
        for (int r = 0; r < 3; ++r)
            #pragma unroll
            for (int d = 0; d < 3; ++d)
                nb[r][d] = make_uint4(0u, 0u, 0u, 0u);
        #pragma unroll
        for (int r = 0; r < 3; ++r) {
            int hh = h - 1 + r;
            if (hh < 0 || hh >= Hn) continue;
            const ushort_t* rp = fu_b + (size_t)(b * Ln + hh * Wn) * 192 + co;
            #pragma unroll
            for (int d = 0; d < 3; ++d) {
                int w2 = w - 1 + d;
                if (w2 < 0 || w2 >= Wn) continue;
                nb[r][d] = *(const uint4*)(rp + (size_t)w2 * 192);
            }
        }
        unsigned ou[4];
        #pragma unroll
        for (int i = 0; i < 8; ++i) {
            float s = 0.0f;
            #pragma unroll
            for (int r = 0; r < 3; ++r) {
                #pragma unroll
                for (int d = 0; d < 3; ++d) {
                    unsigned word = ((const unsigned*)&nb[r][d])[i >> 1];
                    float v = __uint_as_float((i & 1) ? (word & 0xffff0000u)
                                                      : (word << 16));
                    s = fmaf(wp[i * 9 + r * 3 + d], v, s);
                }
            }
            float A = wp[72 + i * 3];
            float Bc = wp[72 + i * 3 + 1];
            float G = wp[72 + i * 3 + 2];
            float y = gelu_f(fmaf(s, A, Bc)) * G;
            if (i & 1) ou[i >> 1] |= (unsigned)f2bf(y) << 16;
            else       ou[i >> 1] = (unsigned)f2bf(y);
        }
        *(uint4*)(out2b + outrow + (size_t)w * 192 + co) =
            make_uint4(ou[0], ou[1], ou[2], ou[3]);
    }
}

extern "C" void kernel_launch(void* const* d_in, const int* in_sizes, int n_in,
                              void* d_out, int out_size, void* d_ws, size_t ws_size,
                              hipStream_t stream) {
    (void)in_sizes; (void)n_in; (void)out_size; (void)ws_size;
    const float* x      = (const float*)d_in[0];
    const float* w_qkv  = (const float*)d_in[1];
    const float* b_qkv  = (const float*)d_in[2];
    const float* w_dw1  = (const float*)d_in[3];
    const float* b_dw1  = (const float*)d_in[4];
    const float* g_bn1  = (const float*)d_in[5];
    const float* be_bn1 = (const float*)d_in[6];
    const float* w_si1  = (const float*)d_in[7];
    const float* b_si1  = (const float*)d_in[8];
    const float* g_si   = (const float*)d_in[9];
    const float* be_si  = (const float*)d_in[10];
    const float* w_si2  = (const float*)d_in[11];
    const float* b_si2  = (const float*)d_in[12];
    const float* w_ci1  = (const float*)d_in[13];
    const float* b_ci1  = (const float*)d_in[14];
    const float* g_ci   = (const float*)d_in[15];
    const float* be_ci  = (const float*)d_in[16];
    const float* w_ci2  = (const float*)d_in[17];
    const float* b_ci2  = (const float*)d_in[18];
    const float* w_dw2  = (const float*)d_in[19];
    const float* b_dw2  = (const float*)d_in[20];
    const float* g_bn2  = (const float*)d_in[21];
    const float* be_bn2 = (const float*)d_in[22];
    const float* w_proj = (const float*)d_in[23];
    const float* b_proj = (const float*)d_in[24];

    float* ws = (float*)d_ws;
    ushort_t* conv1b = (ushort_t*)ws;
    ushort_t* Qp     = (ushort_t*)ws;
    ushort_t* Kp     = (ushort_t*)(ws + FUn / 2);
    ushort_t* out2b  = (ushort_t*)(ws + 8000000);
    float* gate_s    = ws + FUn;                       // B*L
    float* gate_c    = gate_s + (size_t)Bn * Ln;       // B*192
    float* pooled2   = gate_c + Bn * 192;              // B*192*2
    ushort_t* xb     = (ushort_t*)d_out;
    ushort_t* fu_b   = (ushort_t*)d_out;
    ushort_t* Vp     = (ushort_t*)d_out + FUn;

    conv1_k<<<dim3(Bn * 192, 2), 256, 0, stream>>>(x, w_dw1, b_dw1, g_bn1, be_bn1,
                                                   conv1b, xb, pooled2);
    spatial_gate_k<<<Bn * Hn, 128, 0, stream>>>(conv1b, w_si1, b_si1, g_si, be_si,
                                                w_si2, b_si2, gate_s);
    channel_gate_k<<<Bn, 192, 0, stream>>>(pooled2, w_ci1, b_ci1, g_ci, be_ci,
                                           w_ci2, b_ci2, gate_c);
    qkv_mfma<<<dim3(Mn / 128, 6), 256, 0, stream>>>(xb, w_qkv, b_qkv, Qp, Kp, Vp);
    attn_mfma<<<3072, 256, 0, stream>>>(Qp, Kp, Vp, gate_s, fu_b);
    dwconv2_k<<<Bn * Hn * 2, 256, 0, stream>>>(fu_b, gate_c,
                                               w_dw2, b_dw2, g_bn2, be_bn2, out2b);
    proj_mfma<<<dim3(Mn / 128, 2), 256, 0, stream>>>(out2b, w_proj, b_proj, (float*)d_out);
}

// Round 14
// 310.539 us; speedup vs baseline: 4.3053x; 1.0144x over previous
//
#include <hip/hip_runtime.h>

#define Bn 8
#define Hn 128
#define Wn 128
#define Cn 192
#define Ln (Hn*Wn)          // 16384
#define Mn (Bn*Ln)          // 131072
#define FUn ((size_t)Mn*Cn) // 25,165,824 floats
#define BANKn ((size_t)Mn*96) // shorts per branch-bank
#define BN_RSQ 0.9999950000374997f   // 1/sqrt(1+1e-5)

typedef unsigned short ushort_t;
typedef __attribute__((ext_vector_type(8))) short short8;
typedef __attribute__((ext_vector_type(4))) float f32x4;
typedef __attribute__((ext_vector_type(4))) unsigned int uint4v;

static __device__ __forceinline__ float gelu_f(float x) {
    return 0.5f * x * (1.0f + erff(x * 0.7071067811865475f));
}
static __device__ __forceinline__ float gate1p(float x) {  // 1 + sigmoid(x)
    return 1.0f + 1.0f / (1.0f + __expf(-x));
}
static __device__ __forceinline__ unsigned short f2bf(float f) {  // RNE
    unsigned u = __float_as_uint(f);
    return (unsigned short)((u + 0x7FFFu + ((u >> 16) & 1u)) >> 16);
}
static __device__ __forceinline__ unsigned int pk2(float lo, float hi) {
    return (unsigned int)f2bf(lo) | ((unsigned int)f2bf(hi) << 16);
}
static __device__ __forceinline__ float bf2f(ushort_t u) {
    return __uint_as_float((unsigned)u << 16);
}

// ========== qkv GEMM (bf16 A; all 576 cols) -> window-contiguous Q/K/V =====
// grid (6, Mn/128): x = column part (L2 reuse of A-tile), y = m-tile.
__global__ __launch_bounds__(256) void qkv_mfma(const ushort_t* __restrict__ Ab,
        const float* __restrict__ Bw, const float* __restrict__ bias,
        ushort_t* __restrict__ Qp, ushort_t* __restrict__ Kp,
        ushort_t* __restrict__ Vp)
{
    __shared__ __align__(16) ushort_t As[128 * 64];
    __shared__ __align__(16) ushort_t Bs[96 * 64];
    const int m0 = blockIdx.y * 128;
    const int n0g = blockIdx.x * 96;                  // 0..480
    const int part = n0g / 192;
    const int coln = n0g - part * 192;                // 0 or 96 (block-uniform)
    ushort_t* dst = part == 0 ? Qp : (part == 1 ? Kp : Vp);
    ushort_t* bptr = dst + (coln ? BANKn : 0);
    const int tid = threadIdx.x;
    const int lane = tid & 63;
    const int wrow = (tid >> 6) * 32;
    const int r0 = lane >> 4, cl = lane & 15;
    f32x4 acc[2][6] = {};

    for (int ks = 0; ks < 3; ++ks) {
        const int k0 = ks * 64;
        if (ks) __syncthreads();
        #pragma unroll
        for (int i = 0; i < 2; ++i) {
            int s = tid + i * 256;
            int row = s >> 2, q = s & 3;
            const ushort_t* src = Ab + (size_t)(m0 + row) * 192 + k0 + q * 16;
            uint4 u0 = *(const uint4*)(src);
            uint4 u1 = *(const uint4*)(src + 8);
            int r7 = row & 7;
            *(uint4*)&As[row * 64 + (((q * 2) ^ r7) * 8)] = u0;
            *(uint4*)&As[row * 64 + (((q * 2 + 1) ^ r7) * 8)] = u1;
        }
        #pragma unroll
        for (int i = 0; i < 3; ++i) {
            int f = tid + i * 256;                    // 0..767
            int col = f % 96, kslot = f / 96;
            uint4v wv;
            #pragma unroll
            for (int e2 = 0; e2 < 4; ++e2) {
                float lo = Bw[(size_t)(k0 + kslot * 8 + 2 * e2)     * 576 + n0g + col];
                float hi = Bw[(size_t)(k0 + kslot * 8 + 2 * e2 + 1) * 576 + n0g + col];
                wv[e2] = pk2(lo, hi);
            }
            *(uint4v*)&Bs[col * 64 + ((kslot ^ (col & 7)) * 8)] = wv;
        }
        __syncthreads();
        #pragma unroll
        for (int kk = 0; kk < 2; ++kk) {
            int kslot = kk * 4 + r0;
            int ra0 = wrow + cl, ra1 = wrow + 16 + cl;
            short8 a0 = *(const short8*)&As[ra0 * 64 + ((kslot ^ (ra0 & 7)) * 8)];
            short8 a1 = *(const short8*)&As[ra1 * 64 + ((kslot ^ (ra1 & 7)) * 8)];
            #pragma unroll
            for (int n = 0; n < 6; ++n) {
                int col = n * 16 + cl;
                short8 bn = *(const short8*)&Bs[col * 64 + ((kslot ^ (col & 7)) * 8)];
                acc[0][n] = __builtin_amdgcn_mfma_f32_16x16x32_bf16(a0, bn, acc[0][n], 0, 0, 0);
                acc[1][n] = __builtin_amdgcn_mfma_f32_16x16x32_bf16(a1, bn, acc[1][n], 0, 0, 0);
            }
        }
    }
    float bv[6];
    #pragma unroll
    for (int n = 0; n < 6; ++n) bv[n] = bias[n0g + n * 16 + cl];
    #pragma unroll
    for (int m = 0; m < 2; ++m) {
        #pragma unroll
        for (int j = 0; j < 4; ++j) {
            int row = m0 + wrow + m * 16 + r0 * 4 + j;
            int b = row >> 14, l = row & 16383;
            int h = l >> 7, w = l & 127;
            int win, t;
            if (coln == 0) { win = (h >> 3) * 8 + (w >> 4);  t = (h & 7) * 16 + (w & 15); }
            else           { win = (h >> 4) * 16 + (w >> 3); t = (h & 15) * 8 + (w & 7); }
            size_t rbase = ((size_t)((b * 128 + win) * 128 + t)) * 96;
            #pragma unroll
            for (int n = 0; n < 6; ++n)
                bptr[rbase + n * 16 + cl] = f2bf(acc[m][n][j] + bv[n]);
        }
    }
}

// =================== proj GEMM: bf16 A (row-major) x f32 Bw -> f32 out ======
__global__ __launch_bounds__(256) void proj_mfma(const ushort_t* __restrict__ Ab,
        const float* __restrict__ Bw, const float* __restrict__ bias,
        float* __restrict__ Cout)
{
    __shared__ __align__(16) ushort_t As[128 * 64];
    __shared__ __align__(16) ushort_t Bs[96 * 64];
    const int m0 = blockIdx.x * 128;
    const int n0 = blockIdx.y * 96;
    const int tid = threadIdx.x;
    const int lane = tid & 63;
    const int wrow = (tid >> 6) * 32;
    const int r0 = lane >> 4, cl = lane & 15;
    f32x4 acc[2][6] = {};

    for (int ks = 0; ks < 3; ++ks) {
        const int k0 = ks * 64;
        if (ks) __syncthreads();
        #pragma unroll
        for (int i = 0; i < 2; ++i) {
            int s = tid + i * 256;
            int row = s >> 2, q = s & 3;
            const ushort_t* src = Ab + (size_t)(m0 + row) * 192 + k0 + q * 16;
            uint4 u0 = *(const uint4*)(src);
            uint4 u1 = *(const uint4*)(src + 8);
            int r7 = row & 7;
            *(uint4*)&As[row * 64 + (((q * 2) ^ r7) * 8)] = u0;
            *(uint4*)&As[row * 64 + (((q * 2 + 1) ^ r7) * 8)] = u1;
        }
        #pragma unroll
        for (int i = 0; i < 3; ++i) {
            int f = tid + i * 256;
            int col = f % 96, kslot = f / 96;
            uint4v wv;
            #pragma unroll
            for (int e2 = 0; e2 < 4; ++e2) {
                float lo = Bw[(size_t)(k0 + kslot * 8 + 2 * e2)     * 192 + n0 + col];
                float hi = Bw[(size_t)(k0 + kslot * 8 + 2 * e2 + 1) * 192 + n0 + col];
                wv[e2] = pk2(lo, hi);
            }
            *(uint4v*)&Bs[col * 64 + ((kslot ^ (col & 7)) * 8)] = wv;
        }
        __syncthreads();
        #pragma unroll
        for (int kk = 0; kk < 2; ++kk) {
            int kslot = kk * 4 + r0;
            int ra0 = wrow + cl, ra1 = wrow + 16 + cl;
            short8 a0 = *(const short8*)&As[ra0 * 64 + ((kslot ^ (ra0 & 7)) * 8)];
            short8 a1 = *(const short8*)&As[ra1 * 64 + ((kslot ^ (ra1 & 7)) * 8)];
            #pragma unroll
            for (int n = 0; n < 6; ++n) {
                int col = n * 16 + cl;
                short8 bn = *(const short8*)&Bs[col * 64 + ((kslot ^ (col & 7)) * 8)];
                acc[0][n] = __builtin_amdgcn_mfma_f32_16x16x32_bf16(a0, bn, acc[0][n], 0, 0, 0);
                acc[1][n] = __builtin_amdgcn_mfma_f32_16x16x32_bf16(a1, bn, acc[1][n], 0, 0, 0);
            }
        }
    }
    #pragma unroll
    for (int m = 0; m < 2; ++m) {
        #pragma unroll
        for (int n = 0; n < 6; ++n) {
            int col = n0 + n * 16 + cl;
            float bv = bias[col];
            #pragma unroll
            for (int j = 0; j < 4; ++j) {
                int row = m0 + wrow + m * 16 + r0 * 4 + j;
                Cout[(size_t)row * 192 + col] = acc[m][n][j] + bv;
            }
        }
    }
}

// ===== MFMA window attention, j-split: wave = (win, head, query-half) ======
__global__ __launch_bounds__(256) void attn_mfma(const ushort_t* __restrict__ Qp,
        const ushort_t* __restrict__ Kp, const ushort_t* __restrict__ Vp,
        const float* __restrict__ gate_s, ushort_t* __restrict__ fu_b)
{
    const int widx = threadIdx.x >> 6;
    const int idx = blockIdx.x * 4 + widx;          // 0..12287
    const int jhalf = idx & 1;                      // sibling waves share a block
    const int sub0 = idx >> 1;                      // 0..6143
    const int branch = (sub0 >= 3072) ? 1 : 0;
    const int sub = sub0 - branch * 3072;
    const int head = sub >> 10;
    const int b = (sub >> 7) & 7;
    const int win = sub & 127;
    const int L = threadIdx.x & 63;
    const int g = L >> 4, q = L & 15;
    int hb, wb;
    if (branch == 0) { hb = (win >> 3) * 8;  wb = (win & 7) * 16; }
    else             { hb = (win >> 4) * 16; wb = (win & 15) * 8; }
    const int cf = branch * 96 + head * 32;         // fu channel base
    const int hch = head * 32;                      // in-bank channel base
    const int jbase = jhalf * 4;

    const size_t bank = branch ? BANKn : 0;
    const size_t wbase = ((size_t)((b * 128 + win) * 128)) * 96;
    const ushort_t* Qw = Qp + bank + wbase;
    const ushort_t* Kw = Kp + bank + wbase;
    const ushort_t* Vw = Vp + bank + wbase;

    short8 kf[8], qf[4];
    #pragma unroll
    for (int i = 0; i < 8; ++i)
        kf[i] = *(const short8*)(Kw + (size_t)(16 * i + q) * 96 + hch + 8 * g);
    #pragma unroll
    for (int jj = 0; jj < 4; ++jj)
        qf[jj] = *(const short8*)(Qw + (size_t)(16 * (jbase + jj) + q) * 96 + hch + 8 * g);
    short8 vf[2][4];
    {
        #pragma unroll
        for (int s = 0; s < 4; ++s) {
            #pragma unroll
            for (int dblk = 0; dblk < 2; ++dblk) {
                uint4v wv;
                #pragma unroll
                for (int e2 = 0; e2 < 4; ++e2) {
                    size_t base = (size_t)(32 * s + 8 * g + 2 * e2) * 96 + hch + 16 * dblk + q;
                    unsigned lo = Vw[base];
                    unsigned hi = Vw[base + 96];
                    wv[e2] = lo | (hi << 16);
                }
                vf[dblk][s] = *(short8*)&wv;
            }
        }
    }

    const float SC = 0.5303300858899106f;   // 3/sqrt(32)
    const int src0 = q + ((g & 1) << 5);
    const bool thi = (g >> 1) != 0;
    const bool glo = (g < 2);
    #pragma unroll
    for (int jj = 0; jj < 4; ++jj) {
        const int j = jbase + jj;
        unsigned wA[8], wB[8];
        float ss = 0.0f;
        #pragma unroll
        for (int i = 0; i < 8; ++i) {
            f32x4 z = {};
            f32x4 S = __builtin_amdgcn_mfma_f32_16x16x32_bf16(kf[i], qf[jj], z, 0, 0, 0);
            float p0 = __expf(S[0] * SC), p1 = __expf(S[1] * SC);
            float p2 = __expf(S[2] * SC), p3 = __expf(S[3] * SC);
            ss += (p0 + p1) + (p2 + p3);
            wA[i] = pk2(p0, p1);
            wB[i] = pk2(p2, p3);
        }
        ss += __shfl_xor(ss, 16);
        ss += __shfl_xor(ss, 32);
        int l_own;
        if (branch == 0) l_own = (hb + j) * Wn + wb + q;
        else             l_own = (hb + 2 * j + (q >> 3)) * Wn + wb + (q & 7);
        float s_own = 3.0f * gate_s[(size_t)b * Ln + l_own] / ss;

        f32x4 O0 = {}, O1 = {};
        #pragma unroll
        for (int s = 0; s < 4; ++s) {
            unsigned a0  = (unsigned)__shfl((int)wA[2*s],     src0);
            unsigned b0  = (unsigned)__shfl((int)wB[2*s],     src0);
            unsigned a0h = (unsigned)__shfl((int)wA[2*s],     src0 + 16);
            unsigned b0h = (unsigned)__shfl((int)wB[2*s],     src0 + 16);
            unsigned a1  = (unsigned)__shfl((int)wA[2*s+1],   src0);
            unsigned b1  = (unsigned)__shfl((int)wB[2*s+1],   src0);
            unsigned a1h = (unsigned)__shfl((int)wA[2*s+1],   src0 + 16);
            unsigned b1h = (unsigned)__shfl((int)wB[2*s+1],   src0 + 16);
            uint4v B2u;
            B2u[0] = thi ? a1  : a0;
            B2u[1] = thi ? b1  : b0;
            B2u[2] = thi ? a1h : a0h;
            B2u[3] = thi ? b1h : b0h;
            short8 B2 = *(short8*)&B2u;
            O0 = __builtin_amdgcn_mfma_f32_16x16x32_bf16(vf[0][s], B2, O0, 0, 0, 0);
            O1 = __builtin_amdgcn_mfma_f32_16x16x32_bf16(vf[1][s], B2, O1, 0, 0, 0);
        }
        unsigned w0 = pk2(O0[0] * s_own, O0[1] * s_own);
        unsigned w1 = pk2(O0[2] * s_own, O0[3] * s_own);
        unsigned w2 = pk2(O1[0] * s_own, O1[1] * s_own);
        unsigned w3 = pk2(O1[2] * s_own, O1[3] * s_own);
        unsigned a0 = (unsigned)__shfl((int)w0, src0);
        unsigned a1 = (unsigned)__shfl((int)w1, src0);
        unsigned b0 = (unsigned)__shfl((int)w0, src0 + 16);
        unsigned b1 = (unsigned)__shfl((int)w1, src0 + 16);
        unsigned c0 = (unsigned)__shfl((int)w2, src0);
        unsigned c1 = (unsigned)__shfl((int)w3, src0);
        unsigned d0 = (unsigned)__shfl((int)w2, src0 + 16);
        unsigned d1 = (unsigned)__shfl((int)w3, src0 + 16);
        uint4 o = make_uint4(glo ? a0 : c0, glo ? a1 : c1,
                             glo ? b0 : d0, glo ? b1 : d1);
        *(uint4*)(fu_b + (size_t)(b * Ln + l_own) * 192 + cf + 8 * g) = o;
    }
}

// ---- conv1: dwconv3x3+BN+GELU, half-plane blocks; halo edges via shuffle ---
__global__ __launch_bounds__(256) void conv1_k(const float* __restrict__ x,
        const float* __restrict__ wdw, const float* __restrict__ bdw,
        const float* __restrict__ g1, const float* __restrict__ be1,
        ushort_t* __restrict__ conv1b, ushort_t* __restrict__ xb,
        float* __restrict__ pooled2)
{
    int bc = blockIdx.x;                   // b*192 + c
    int half = blockIdx.y;                 // 0/1
    int c = bc % 192;
    const float* plane = x + (size_t)bc * Ln;
    ushort_t* oplane = conv1b + (size_t)bc * Ln;
    ushort_t* xplane = xb + (size_t)bc * Ln;
    int t = threadIdx.x;
    int sx = t & 31, sy = t >> 5;          // 32 strips x 8 bands
    int w0 = sx * 4, h0 = half * 64 + sy * 8;
    float wk[9];
    #pragma unroll
    for (int i = 0; i < 9; ++i) wk[i] = wdw[c * 9 + i];
    float gb = g1[c] * BN_RSQ, bb = be1[c], bd = bdw[c];

    // r[i]: {left, m.x, m.y, m.z, m.w, right}; edges from neighbor lanes.
    // lane = (sy&1)*32 + sx; sx +-1 == lane +-1 within the same sy row;
    // sx==0 / sx==31 boundaries masked to 0 (image border).
    float r[10][6];
    #pragma unroll
    for (int i = 0; i < 10; ++i) {
        int h = h0 - 1 + i;
        float4 m = make_float4(0.f, 0.f, 0.f, 0.f);
        if (h >= 0 && h < Hn)
            m = *(const float4*)(plane + h * Wn + w0);
        float lf = __shfl_up(m.w, 1);
        float rt = __shfl_down(m.x, 1);
        r[i][0] = sx ? lf : 0.0f;
        r[i][1] = m.x; r[i][2] = m.y; r[i][3] = m.z; r[i][4] = m.w;
        r[i][5] = (sx < 31) ? rt : 0.0f;
    }
    float psum = 0.0f;
    #pragma unroll
    for (int i = 0; i < 8; ++i) {
        int h = h0 + i;
        *(uint2*)(xplane + h * Wn + w0) =
            make_uint2(pk2(r[i+1][1], r[i+1][2]), pk2(r[i+1][3], r[i+1][4]));
        float o[4];
        #pragma unroll
        for (int p = 0; p < 4; ++p) {
            float s = wk[0] * r[i][p];
            s = fmaf(wk[1], r[i][p + 1], s);
            s = fmaf(wk[2], r[i][p + 2], s);
            s = fmaf(wk[3], r[i+1][p],     s);
            s = fmaf(wk[4], r[i+1][p + 1], s);
            s = fmaf(wk[5], r[i+1][p + 2], s);
            s = fmaf(wk[6], r[i+2][p],     s);
            s = fmaf(wk[7], r[i+2][p + 1], s);
            s = fmaf(wk[8], r[i+2][p + 2], s);
            float y = gelu_f((s + bd) * gb + bb);
            psum += y;
            o[p] = y;
        }
        *(uint2*)(oplane + h * Wn + w0) =
            make_uint2(pk2(o[0], o[1]), pk2(o[2], o[3]));
    }
    __shared__ float red[4];
    for (int off = 32; off; off >>= 1) psum += __shfl_down(psum, off);
    if ((t & 63) == 0) red[t >> 6] = psum;
    __syncthreads();
    if (t == 0)
        pooled2[bc * 2 + half] = red[0] + red[1] + red[2] + red[3];
}

// ------- spatial gate: per-pixel 192->24->1 MLP on bf16 conv1 ---------------
__global__ __launch_bounds__(128) void spatial_gate_k(const ushort_t* __restrict__ conv1b,
        const float* __restrict__ ws1g, const float* __restrict__ bs1,
        const float* __restrict__ gsi, const float* __restrict__ besi,
        const float* __restrict__ ws2, const float* __restrict__ bs2,
        float* __restrict__ gate_s)
{
    int bh = blockIdx.x;                   // b*128 + h
    int b = bh >> 7, h = bh & 127;
    int w = threadIdx.x;
    __shared__ float ws1T[192 * 24];       // [c][o]
    for (int i = w; i < 192 * 24; i += 128) {
        int c = i / 24, o = i - c * 24;
        ws1T[i] = ws1g[o * 192 + c];
    }
    __syncthreads();
    float acc24[24] = {};
    const ushort_t* base = conv1b + (size_t)b * 192 * Ln + h * Wn + w;
    #pragma unroll 4
    for (int c = 0; c < 192; ++c) {
        float v = bf2f(base[(size_t)c * Ln]);
        const float4* wp = (const float4*)&ws1T[c * 24];
        #pragma unroll
        for (int o4 = 0; o4 < 6; ++o4) {
            float4 wv = wp[o4];
            acc24[o4*4+0] = fmaf(v, wv.x, acc24[o4*4+0]);
            acc24[o4*4+1] = fmaf(v, wv.y, acc24[o4*4+1]);
            acc24[o4*4+2] = fmaf(v, wv.z, acc24[o4*4+2]);
            acc24[o4*4+3] = fmaf(v, wv.w, acc24[o4*4+3]);
        }
    }
    float s2 = bs2[0];
    #pragma unroll
    for (int o = 0; o < 24; ++o)
        s2 = fmaf(gelu_f((acc24[o] + bs1[o]) * (gsi[o] * BN_RSQ) + besi[o]), ws2[o], s2);
    gate_s[(size_t)bh * 128 + w] = gate1p(s2);
}

// ------ channel gate: combine pooled halves + 192->24->192, 1+sigmoid ------
__global__ __launch_bounds__(192) void channel_gate_k(const float* __restrict__ pooled2,
        const float* __restrict__ w1, const float* __restrict__ b1,
        const float* __restrict__ g, const float* __restrict__ be,
        const float* __restrict__ w2, const float* __restrict__ b2,
        float* __restrict__ gate_c)
{
    int b = blockIdx.x, t = threadIdx.x;
    __shared__ float pl[192];
    __shared__ float h1[24];
    int bc = b * 192 + t;
    pl[t] = (pooled2[bc * 2] + pooled2[bc * 2 + 1]) * (1.0f / Ln);
    __syncthreads();
    if (t < 24) {
        float a = b1[t];
        for (int c = 0; c < 192; ++c) a = fmaf(pl[c], w1[t * 192 + c], a);
        a = a * (g[t] * BN_RSQ) + be[t];
        h1[t] = gelu_f(a);
    }
    __syncthreads();
    float a = b2[t];
    #pragma unroll
    for (int o = 0; o < 24; ++o) a = fmaf(h1[o], w2[t * 24 + o], a);
    gate_c[b * 192 + t] = gate1p(a);
}

// ---- dwconv2: channels-last register 3x3 stencil, conflict-free LDS -------
__global__ __launch_bounds__(256) void dwconv2_k(const ushort_t* __restrict__ fu_b,
        const float* __restrict__ gate_c,
        const float* __restrict__ wdw, const float* __restrict__ bdw,
        const float* __restrict__ g2, const float* __restrict__ be2,
        ushort_t* __restrict__ out2b)
{
    int bh = blockIdx.x >> 1;              // b*128 + h
    int whalf = blockIdx.x & 1;
    int b = bh >> 7, h = bh & 127;
    int tid = threadIdx.x;
    __shared__ float cwp[24 * 105];        // [c8]{72 weights, 24 params}
    for (int idx = tid; idx < 24 * 96; idx += 256) {
        int c8 = idx / 96, r = idx - c8 * 96;
        float v;
        if (r < 72) {
            int i = r / 9, p = r - i * 9;
            v = wdw[(c8 * 8 + i) * 9 + p];
        } else {
            int r2 = r - 72;
            int i = r2 / 3, j = r2 - i * 3;
            int c = c8 * 8 + i;
            float A = g2[c] * BN_RSQ;
            v = (j == 0) ? A : (j == 1) ? fmaf(bdw[c], A, be2[c])
                                        : gate_c[b * 192 + c];
        }
        cwp[c8 * 105 + r] = v;
    }
    __syncthreads();
    const size_t outrow = (size_t)(b * Ln + h * Wn) * 192;
    for (int it = 0; it < 6; ++it) {
        int item = it * 256 + tid;          // 0..1535
        int w = whalf * 64 + item / 24;
        int c8 = item % 24;
        int co = c8 * 8;
        const float* wp = &cwp[c8 * 105];
        uint4 nb[3][3];
        #pragma unroll
        for (int r = 0; r < 3; ++r)
            #pragma unroll
            for (int d = 0; d < 3; ++d)
                nb[r][d] = make_uint4(0u, 0u, 0u, 0u);
        #pragma unroll
        for (int r = 0; r < 3; ++r) {
            int hh = h - 1 + r;
            if (hh < 0 || hh >= Hn) continue;
            const ushort_t* rp = fu_b + (size_t)(b * Ln + hh * Wn) * 192 + co;
            #pragma unroll
            for (int d = 0; d < 3; ++d) {
                int w2 = w - 1 + d;
                if (w2 < 0 || w2 >= Wn) continue;
                nb[r][d] = *(const uint4*)(rp + (size_t)w2 * 192);
            }
        }
        unsigned ou[4];
        #pragma unroll
        for (int i = 0; i < 8; ++i) {
            float s = 0.0f;
            #pragma unroll
            for (int r = 0; r < 3; ++r) {
                #pragma unroll
                for (int d = 0; d < 3; ++d) {
                    unsigned word = ((const unsigned*)&nb[r][d])[i >> 1];
                    float v = __uint_as_float((i & 1) ? (word & 0xffff0000u)
                                                      : (word << 16));
                    s = fmaf(wp[i * 9 + r * 3 + d], v, s);
                }
            }
            float A = wp[72 + i * 3];
            float Bc = wp[72 + i * 3 + 1];
            float G = wp[72 + i * 3 + 2];
            float y = gelu_f(fmaf(s, A, Bc)) * G;
            if (i & 1) ou[i >> 1] |= (unsigned)f2bf(y) << 16;
            else       ou[i >> 1] = (unsigned)f2bf(y);
        }
        *(uint4*)(out2b + outrow + (size_t)w * 192 + co) =
            make_uint4(ou[0], ou[1], ou[2], ou[3]);
    }
}

extern "C" void kernel_launch(void* const* d_in, const int* in_sizes, int n_in,
                              void* d_out, int out_size, void* d_ws, size_t ws_size,
                              hipStream_t stream) {
    (void)in_sizes; (void)n_in; (void)out_size; (void)ws_size;
    const float* x      = (const float*)d_in[0];
    const float* w_qkv  = (const float*)d_in[1];
    const float* b_qkv  = (const float*)d_in[2];
    const float* w_dw1  = (const float*)d_in[3];
    const float* b_dw1  = (const float*)d_in[4];
    const float* g_bn1  = (const float*)d_in[5];
    const float* be_bn1 = (const float*)d_in[6];
    const float* w_si1  = (const float*)d_in[7];
    const float* b_si1  = (const float*)d_in[8];
    const float* g_si   = (const float*)d_in[9];
    const float* be_si  = (const float*)d_in[10];
    const float* w_si2  = (const float*)d_in[11];
    const float* b_si2  = (const float*)d_in[12];
    const float* w_ci1  = (const float*)d_in[13];
    const float* b_ci1  = (const float*)d_in[14];
    const float* g_ci   = (const float*)d_in[15];
    const float* be_ci  = (const float*)d_in[16];
    const float* w_ci2  = (const float*)d_in[17];
    const float* b_ci2  = (const float*)d_in[18];
    const float* w_dw2  = (const float*)d_in[19];
    const float* b_dw2  = (const float*)d_in[20];
    const float* g_bn2  = (const float*)d_in[21];
    const float* be_bn2 = (const float*)d_in[22];
    const float* w_proj = (const float*)d_in[23];
    const float* b_proj = (const float*)d_in[24];

    float* ws = (float*)d_ws;
    ushort_t* conv1b = (ushort_t*)ws;
    ushort_t* Qp     = (ushort_t*)ws;
    ushort_t* Kp     = (ushort_t*)(ws + FUn / 2);
    ushort_t* out2b  = (ushort_t*)(ws + 8000000);
    float* gate_s    = ws + FUn;                       // B*L
    float* gate_c    = gate_s + (size_t)Bn * Ln;       // B*192
    float* pooled2   = gate_c + Bn * 192;              // B*192*2
    ushort_t* xb     = (ushort_t*)d_out;
    ushort_t* fu_b   = (ushort_t*)d_out;
    ushort_t* Vp     = (ushort_t*)d_out + FUn;

    conv1_k<<<dim3(Bn * 192, 2), 256, 0, stream>>>(x, w_dw1, b_dw1, g_bn1, be_bn1,
                                                   conv1b, xb, pooled2);
    spatial_gate_k<<<Bn * Hn, 128, 0, stream>>>(conv1b, w_si1, b_si1, g_si, be_si,
                                                w_si2, b_si2, gate_s);
    channel_gate_k<<<Bn, 192, 0, stream>>>(pooled2, w_ci1, b_ci1, g_ci, be_ci,
                                           w_ci2, b_ci2, gate_c);
    qkv_mfma<<<dim3(6, Mn / 128), 256, 0, stream>>>(xb, w_qkv, b_qkv, Qp, Kp, Vp);
    attn_mfma<<<3072, 256, 0, stream>>>(Qp, Kp, Vp, gate_s, fu_b);
    dwconv2_k<<<Bn * Hn * 2, 256, 0, stream>>>(fu_b, gate_c,
                                               w_dw2, b_dw2, g_bn2, be_bn2, out2b);
    proj_mfma<<<dim3(Mn / 128, 2), 256, 0, stream>>>(out2b, w_proj, b_proj, (float*)d_out);
}